// Round 1
// baseline (1329.924 us; speedup 1.0000x reference)
//
#include <hip/hip_runtime.h>
#include <math.h>

#define HIDDEN 128
#define NCLS 40

__device__ __forceinline__ float wave_reduce_sum(float v) {
    #pragma unroll
    for (int off = 32; off > 0; off >>= 1) v += __shfl_xor(v, off);
    return v;
}

// ---------------- CSR build ----------------

__global__ void k_count(const int* __restrict__ ei, int E, int* __restrict__ deg_i) {
    int e = blockIdx.x * 256 + threadIdx.x;
    if (e < E) atomicAdd(&deg_i[ei[E + e]], 1);  // dst = ei[E+e]
}

__global__ void k_scan(const int* __restrict__ deg_i, int N,
                       int* __restrict__ row_start, float* __restrict__ degf,
                       int* __restrict__ counter) {
    __shared__ int sd[256];
    __shared__ int sbase;
    int tid = threadIdx.x;
    int n = blockIdx.x * 256 + tid;
    int v = (n < N) ? deg_i[n] : 0;
    sd[tid] = v;
    __syncthreads();
    // Hillis-Steele inclusive scan
    #pragma unroll
    for (int off = 1; off < 256; off <<= 1) {
        int t = (tid >= off) ? sd[tid - off] : 0;
        __syncthreads();
        sd[tid] += t;
        __syncthreads();
    }
    int incl = sd[tid];
    if (tid == 255) sbase = atomicAdd(counter, incl);   // block total
    __syncthreads();
    if (n < N) {
        row_start[n] = sbase + incl - v;   // exclusive scan + block base
        degf[n] = fmaxf((float)v, 1.0f);
    }
}

__global__ void k_fill(const int* __restrict__ ei, int E,
                       const int* __restrict__ row_start, int* __restrict__ cursor,
                       int* __restrict__ csr_src) {
    int e = blockIdx.x * 256 + threadIdx.x;
    if (e < E) {
        int s = ei[e];
        int d = ei[E + e];
        int pos = row_start[d] + atomicAdd(&cursor[d], 1);
        csr_src[pos] = s;
    }
}

// ---------------- fp32 GEMM: C[M,128] = A[M,128] @ W[128,128] + bias (opt relu) ----------------
// block 256 threads -> 64 rows x 64 cols tile, 4x4 per thread, gridDim.y = 2 (col halves)

__launch_bounds__(256)
__global__ void k_gemm128(const float* __restrict__ A, const float* __restrict__ W,
                          const float* __restrict__ bias, float* __restrict__ C,
                          int M, int do_relu) {
    const int tid  = threadIdx.x;
    const int row0 = blockIdx.x * 64;
    const int col0 = blockIdx.y * 64;
    const int tc = (tid & 15) * 4;   // col offset in tile
    const int tr = (tid >> 4) * 4;   // row offset in tile
    __shared__ float Ws[16][64];     // [k][col]
    __shared__ float Xs[16][68];     // [k][row], padded for bank spread
    const int wkr = tid >> 4;        // W chunk row 0..15
    const int wcc = (tid & 15) * 4;  // W col offset
    const int xr  = tid >> 2;        // A row 0..63
    const int xkq = (tid & 3) * 4;   // A k offset in chunk

    float acc[4][4] = {{0.f}};
    for (int k0 = 0; k0 < 128; k0 += 16) {
        float4 w4 = *(const float4*)&W[(k0 + wkr) * HIDDEN + col0 + wcc];
        float4 a4 = make_float4(0.f, 0.f, 0.f, 0.f);
        int arow = row0 + xr;
        if (arow < M) a4 = *(const float4*)&A[(size_t)arow * HIDDEN + k0 + xkq];
        *(float4*)&Ws[wkr][wcc] = w4;
        Xs[xkq + 0][xr] = a4.x;
        Xs[xkq + 1][xr] = a4.y;
        Xs[xkq + 2][xr] = a4.z;
        Xs[xkq + 3][xr] = a4.w;
        __syncthreads();
        #pragma unroll
        for (int kk = 0; kk < 16; kk++) {
            float4 wv = *(const float4*)&Ws[kk][tc];
            float4 xv = *(const float4*)&Xs[kk][tr];
            float wa[4] = {wv.x, wv.y, wv.z, wv.w};
            float xa[4] = {xv.x, xv.y, xv.z, xv.w};
            #pragma unroll
            for (int i = 0; i < 4; i++)
                #pragma unroll
                for (int j = 0; j < 4; j++)
                    acc[i][j] += xa[i] * wa[j];
        }
        __syncthreads();
    }
    float4 b4 = *(const float4*)&bias[col0 + tc];
    float ba[4] = {b4.x, b4.y, b4.z, b4.w};
    for (int i = 0; i < 4; i++) {
        int r = row0 + tr + i;
        if (r < M) {
            float o[4];
            #pragma unroll
            for (int j = 0; j < 4; j++) {
                o[j] = acc[i][j] + ba[j];
                if (do_relu) o[j] = fmaxf(o[j], 0.f);
            }
            *(float4*)&C[(size_t)r * HIDDEN + col0 + tc] =
                make_float4(o[0], o[1], o[2], o[3]);
        }
    }
}

// ---------------- fused depth step: controllers + aggregate + mix + relu + selected/cp ----------------
// one wave (64 lanes) per node; 4 nodes per 256-thread block

__launch_bounds__(256)
__global__ void k_depth(float* __restrict__ h, const float* __restrict__ ht,
                        float* __restrict__ selected, float* __restrict__ cp,
                        const float* __restrict__ degf, const int* __restrict__ deg_i,
                        const int* __restrict__ row_start, const int* __restrict__ csr_src,
                        const float* __restrict__ Wd, const float* __restrict__ bd,
                        const float* __restrict__ Wa, const float* __restrict__ ba,
                        int N, int first) {
    int lane = threadIdx.x & 63;
    int wave = threadIdx.x >> 6;
    int node = blockIdx.x * 4 + wave;
    if (node >= N) return;

    float2 hv = *(const float2*)&h[(size_t)node * HIDDEN + lane * 2];
    int k0 = lane * 2, k1 = lane * 2 + 1;
    // controller partial dots (5 of them, length-128 each)
    float d0 = hv.x * Wd[k0 * 2 + 0] + hv.y * Wd[k1 * 2 + 0];
    float d1 = hv.x * Wd[k0 * 2 + 1] + hv.y * Wd[k1 * 2 + 1];
    float a0 = hv.x * Wa[k0 * 3 + 0] + hv.y * Wa[k1 * 3 + 0];
    float a1 = hv.x * Wa[k0 * 3 + 1] + hv.y * Wa[k1 * 3 + 1];
    float a2 = hv.x * Wa[k0 * 3 + 2] + hv.y * Wa[k1 * 3 + 2];
    d0 = wave_reduce_sum(d0); d1 = wave_reduce_sum(d1);
    a0 = wave_reduce_sum(a0); a1 = wave_reduce_sum(a1); a2 = wave_reduce_sum(a2);
    d0 += bd[0]; d1 += bd[1];
    a0 += ba[0]; a1 += ba[1]; a2 += ba[2];
    // softmax over 2 (stop) and 3 (aggr); INIT_TEMP = 1
    float m2 = fmaxf(d0, d1);
    float e0 = expf(d0 - m2), e1 = expf(d1 - m2);
    float inv2 = 1.f / (e0 + e1);
    float sp0 = e0 * inv2, sp1 = e1 * inv2;
    float m3 = fmaxf(fmaxf(a0, a1), a2);
    float f0 = expf(a0 - m3), f1 = expf(a1 - m3), f2 = expf(a2 - m3);
    float inv3 = 1.f / (f0 + f1 + f2);
    float ap0 = f0 * inv3, ap1 = f1 * inv3, ap2 = f2 * inv3;

    // aggregate incoming neighbors: sum + max over ht[src]
    int cnt = deg_i[node], start = row_start[node];
    float sx = 0.f, sy = 0.f, mxx = -3.4e38f, mxy = -3.4e38f;
    for (int eb = 0; eb < cnt; eb += 64) {
        int idx = eb + lane;
        int s = (idx < cnt) ? csr_src[start + idx] : 0;
        int lim = min(64, cnt - eb);
        for (int j = 0; j < lim; j++) {
            int sj = __shfl(s, j);
            float2 v = *(const float2*)&ht[(size_t)sj * HIDDEN + lane * 2];
            sx += v.x; sy += v.y;
            mxx = fmaxf(mxx, v.x); mxy = fmaxf(mxy, v.y);
        }
    }
    float invd = 1.0f / degf[node];
    float meanx = sx * invd, meany = sy * invd;
    if (cnt == 0) { mxx = 0.f; mxy = 0.f; }   // segment_max of empty -> -inf -> 0
    float2 self = *(const float2*)&ht[(size_t)node * HIDDEN + lane * 2];
    float hx = ap0 * meanx + ap1 * mxx + ap2 * self.x;
    float hy = ap0 * meany + ap1 * mxy + ap2 * self.y;
    hx = fmaxf(hx, 0.f); hy = fmaxf(hy, 0.f);

    float cpv = first ? 1.0f : cp[node];
    float w = cpv * sp1;
    float2* selp = (float2*)&selected[(size_t)node * HIDDEN + lane * 2];
    if (first) {
        *selp = make_float2(w * hx, w * hy);
    } else {
        float2 sv = *selp;
        sv.x += w * hx; sv.y += w * hy;
        *selp = sv;
    }
    *(float2*)&h[(size_t)node * HIDDEN + lane * 2] = make_float2(hx, hy);
    if (lane == 0) cp[node] = cpv * sp0;
}

// ---------------- post GEMM (128x40) + log_softmax ----------------
// one wave per node: lane c < 40 computes its logit, wave-reduce max/sum

__launch_bounds__(256)
__global__ void k_post(const float* __restrict__ selected, const float* __restrict__ Wp,
                       const float* __restrict__ bp, float* __restrict__ out, int N) {
    int lane = threadIdx.x & 63;
    int wave = threadIdx.x >> 6;
    int node = blockIdx.x * 4 + wave;
    if (node >= N) return;
    int c = (lane < NCLS) ? lane : 0;
    const float* srow = &selected[(size_t)node * HIDDEN];
    float z = bp[c];
    #pragma unroll 8
    for (int k = 0; k < HIDDEN; k++) {
        z += srow[k] * Wp[k * NCLS + c];
    }
    float zm = (lane < NCLS) ? z : -3.4e38f;
    float m = zm;
    #pragma unroll
    for (int off = 32; off > 0; off >>= 1) m = fmaxf(m, __shfl_xor(m, off));
    float ex = (lane < NCLS) ? expf(z - m) : 0.f;
    float s = wave_reduce_sum(ex);
    if (lane < NCLS) out[(size_t)node * NCLS + lane] = z - m - logf(s);
}

// ---------------- launch ----------------

extern "C" void kernel_launch(void* const* d_in, const int* in_sizes, int n_in,
                              void* d_out, int out_size, void* d_ws, size_t ws_size,
                              hipStream_t stream) {
    const float* x      = (const float*)d_in[0];
    const int*   ei     = (const int*)d_in[1];
    const float* W_pre  = (const float*)d_in[2];
    const float* b_pre  = (const float*)d_in[3];
    const float* W_dep  = (const float*)d_in[4];
    const float* b_dep  = (const float*)d_in[5];
    const float* W_aggr = (const float*)d_in[6];
    const float* b_aggr = (const float*)d_in[7];
    const float* W_conv = (const float*)d_in[8];
    const float* b_conv = (const float*)d_in[9];
    const float* W_post = (const float*)d_in[10];
    const float* b_post = (const float*)d_in[11];

    const int N = in_sizes[0] / HIDDEN;
    const int E = in_sizes[1] / 2;

    char* ws = (char*)d_ws;
    size_t off = 0;
    auto alloc = [&](size_t bytes) -> void* {
        void* p = ws + off;
        off += (bytes + 255) & ~(size_t)255;
        return p;
    };
    float* h        = (float*)alloc((size_t)N * HIDDEN * 4);
    float* ht       = (float*)alloc((size_t)N * HIDDEN * 4);
    float* selected = (float*)alloc((size_t)N * HIDDEN * 4);
    float* cp       = (float*)alloc((size_t)N * 4);
    float* degf     = (float*)alloc((size_t)N * 4);
    int*   ibuf     = (int*)alloc((size_t)(2 * N + 64) * 4); // deg_i | cursor | counter
    int*   deg_i    = ibuf;
    int*   cursor   = ibuf + N;
    int*   counter  = ibuf + 2 * N;
    int*   row_start= (int*)alloc((size_t)N * 4);
    int*   csr_src  = (int*)alloc((size_t)E * 4);

    hipMemsetAsync(ibuf, 0, (size_t)(2 * N + 1) * 4, stream);

    int eb = (E + 255) / 256;
    int nb = (N + 255) / 256;
    k_count<<<eb, 256, 0, stream>>>(ei, E, deg_i);
    k_scan<<<nb, 256, 0, stream>>>(deg_i, N, row_start, degf, counter);
    k_fill<<<eb, 256, 0, stream>>>(ei, E, row_start, cursor, csr_src);

    dim3 gg((N + 63) / 64, 2);
    // h = relu(x @ W_pre + b_pre)
    k_gemm128<<<gg, 256, 0, stream>>>(x, W_pre, b_pre, h, N, 1);

    int nb4 = (N + 3) / 4;
    for (int d = 0; d < 4; d++) {
        k_gemm128<<<gg, 256, 0, stream>>>(h, W_conv + (size_t)d * HIDDEN * HIDDEN,
                                          b_conv + (size_t)d * HIDDEN, ht, N, 0);
        k_depth<<<nb4, 256, 0, stream>>>(h, ht, selected, cp, degf, deg_i,
                                         row_start, csr_src,
                                         W_dep, b_dep, W_aggr, b_aggr,
                                         N, d == 0 ? 1 : 0);
    }
    k_post<<<nb4, 256, 0, stream>>>(selected, W_post, b_post, (float*)d_out, N);
}

// Round 2
// 1108.403 us; speedup vs baseline: 1.1999x; 1.1999x over previous
//
#include <hip/hip_runtime.h>
#include <math.h>

#define HIDDEN 128
#define NCLS 40

__device__ __forceinline__ float wave_reduce_sum(float v) {
    #pragma unroll
    for (int off = 32; off > 0; off >>= 1) v += __shfl_xor(v, off);
    return v;
}

// ---------------- CSR build ----------------

__global__ void k_count(const int* __restrict__ ei, int E, int* __restrict__ deg_i) {
    int e = blockIdx.x * 256 + threadIdx.x;
    if (e < E) atomicAdd(&deg_i[ei[E + e]], 1);  // dst = ei[E+e]
}

__global__ void k_scan(const int* __restrict__ deg_i, int N,
                       int* __restrict__ row_start, float* __restrict__ degf,
                       int* __restrict__ counter) {
    __shared__ int sd[256];
    __shared__ int sbase;
    int tid = threadIdx.x;
    int n = blockIdx.x * 256 + tid;
    int v = (n < N) ? deg_i[n] : 0;
    sd[tid] = v;
    __syncthreads();
    #pragma unroll
    for (int off = 1; off < 256; off <<= 1) {
        int t = (tid >= off) ? sd[tid - off] : 0;
        __syncthreads();
        sd[tid] += t;
        __syncthreads();
    }
    int incl = sd[tid];
    if (tid == 255) sbase = atomicAdd(counter, incl);   // block total
    __syncthreads();
    if (n < N) {
        row_start[n] = sbase + incl - v;   // exclusive scan + block base (unordered base ok)
        degf[n] = fmaxf((float)v, 1.0f);
    }
}

__global__ void k_fill(const int* __restrict__ ei, int E,
                       const int* __restrict__ row_start, int* __restrict__ cursor,
                       int* __restrict__ csr_src) {
    int e = blockIdx.x * 256 + threadIdx.x;
    if (e < E) {
        int s = ei[e];
        int d = ei[E + e];
        int pos = row_start[d] + atomicAdd(&cursor[d], 1);
        csr_src[pos] = s;
    }
}

// ---------------- fp32 GEMM: C[M,128] = A[M,128] @ W[128,128] + bias (opt relu) ----------------

__launch_bounds__(256)
__global__ void k_gemm128(const float* __restrict__ A, const float* __restrict__ W,
                          const float* __restrict__ bias, float* __restrict__ C,
                          int M, int do_relu) {
    const int tid  = threadIdx.x;
    const int row0 = blockIdx.x * 64;
    const int col0 = blockIdx.y * 64;
    const int tc = (tid & 15) * 4;
    const int tr = (tid >> 4) * 4;
    __shared__ float Ws[16][64];
    __shared__ float Xs[16][68];
    const int wkr = tid >> 4;
    const int wcc = (tid & 15) * 4;
    const int xr  = tid >> 2;
    const int xkq = (tid & 3) * 4;

    float acc[4][4] = {{0.f}};
    for (int k0 = 0; k0 < 128; k0 += 16) {
        float4 w4 = *(const float4*)&W[(k0 + wkr) * HIDDEN + col0 + wcc];
        float4 a4 = make_float4(0.f, 0.f, 0.f, 0.f);
        int arow = row0 + xr;
        if (arow < M) a4 = *(const float4*)&A[(size_t)arow * HIDDEN + k0 + xkq];
        *(float4*)&Ws[wkr][wcc] = w4;
        Xs[xkq + 0][xr] = a4.x;
        Xs[xkq + 1][xr] = a4.y;
        Xs[xkq + 2][xr] = a4.z;
        Xs[xkq + 3][xr] = a4.w;
        __syncthreads();
        #pragma unroll
        for (int kk = 0; kk < 16; kk++) {
            float4 wv = *(const float4*)&Ws[kk][tc];
            float4 xv = *(const float4*)&Xs[kk][tr];
            float wa[4] = {wv.x, wv.y, wv.z, wv.w};
            float xa[4] = {xv.x, xv.y, xv.z, xv.w};
            #pragma unroll
            for (int i = 0; i < 4; i++)
                #pragma unroll
                for (int j = 0; j < 4; j++)
                    acc[i][j] += xa[i] * wa[j];
        }
        __syncthreads();
    }
    float4 b4 = *(const float4*)&bias[col0 + tc];
    float ba[4] = {b4.x, b4.y, b4.z, b4.w};
    for (int i = 0; i < 4; i++) {
        int r = row0 + tr + i;
        if (r < M) {
            float o[4];
            #pragma unroll
            for (int j = 0; j < 4; j++) {
                o[j] = acc[i][j] + ba[j];
                if (do_relu) o[j] = fmaxf(o[j], 0.f);
            }
            *(float4*)&C[(size_t)r * HIDDEN + col0 + tc] =
                make_float4(o[0], o[1], o[2], o[3]);
        }
    }
}

// ---------------- fused depth step ----------------
// one wave (64 lanes) per node; 4 nodes per 256-thread block
// neighbor loop manually unrolled 4x -> 4 independent 512B gather streams in flight

__launch_bounds__(256)
__global__ void k_depth(float* __restrict__ h, const float* __restrict__ ht,
                        float* __restrict__ selected, float* __restrict__ cp,
                        const float* __restrict__ degf, const int* __restrict__ deg_i,
                        const int* __restrict__ row_start, const int* __restrict__ csr_src,
                        const float* __restrict__ Wd, const float* __restrict__ bd,
                        const float* __restrict__ Wa, const float* __restrict__ ba,
                        int N, int first) {
    int lane = threadIdx.x & 63;
    int wave = threadIdx.x >> 6;
    int node = blockIdx.x * 4 + wave;
    if (node >= N) return;

    float2 hv = *(const float2*)&h[(size_t)node * HIDDEN + lane * 2];
    int k0 = lane * 2, k1 = lane * 2 + 1;
    float d0 = hv.x * Wd[k0 * 2 + 0] + hv.y * Wd[k1 * 2 + 0];
    float d1 = hv.x * Wd[k0 * 2 + 1] + hv.y * Wd[k1 * 2 + 1];
    float a0 = hv.x * Wa[k0 * 3 + 0] + hv.y * Wa[k1 * 3 + 0];
    float a1 = hv.x * Wa[k0 * 3 + 1] + hv.y * Wa[k1 * 3 + 1];
    float a2 = hv.x * Wa[k0 * 3 + 2] + hv.y * Wa[k1 * 3 + 2];
    d0 = wave_reduce_sum(d0); d1 = wave_reduce_sum(d1);
    a0 = wave_reduce_sum(a0); a1 = wave_reduce_sum(a1); a2 = wave_reduce_sum(a2);
    d0 += bd[0]; d1 += bd[1];
    a0 += ba[0]; a1 += ba[1]; a2 += ba[2];
    float m2 = fmaxf(d0, d1);
    float e0 = expf(d0 - m2), e1 = expf(d1 - m2);
    float inv2 = 1.f / (e0 + e1);
    float sp0 = e0 * inv2, sp1 = e1 * inv2;
    float m3 = fmaxf(fmaxf(a0, a1), a2);
    float f0 = expf(a0 - m3), f1 = expf(a1 - m3), f2 = expf(a2 - m3);
    float inv3 = 1.f / (f0 + f1 + f2);
    float ap0 = f0 * inv3, ap1 = f1 * inv3, ap2 = f2 * inv3;

    // aggregate incoming neighbors: sum + max over ht[src]
    int cnt = deg_i[node], start = row_start[node];
    float sx = 0.f, sy = 0.f, mxx = -3.4e38f, mxy = -3.4e38f;
    const int lo2 = lane * 2;
    for (int eb = 0; eb < cnt; eb += 64) {
        int idx = eb + lane;
        int s = (idx < cnt) ? csr_src[start + idx] : 0;
        int lim = min(64, cnt - eb);
        int j = 0;
        for (; j + 4 <= lim; j += 4) {
            int s0 = __shfl(s, j + 0);
            int s1 = __shfl(s, j + 1);
            int s2 = __shfl(s, j + 2);
            int s3 = __shfl(s, j + 3);
            float2 v0 = *(const float2*)&ht[(size_t)s0 * HIDDEN + lo2];
            float2 v1 = *(const float2*)&ht[(size_t)s1 * HIDDEN + lo2];
            float2 v2 = *(const float2*)&ht[(size_t)s2 * HIDDEN + lo2];
            float2 v3 = *(const float2*)&ht[(size_t)s3 * HIDDEN + lo2];
            sx += (v0.x + v1.x) + (v2.x + v3.x);
            sy += (v0.y + v1.y) + (v2.y + v3.y);
            mxx = fmaxf(fmaxf(fmaxf(mxx, v0.x), fmaxf(v1.x, v2.x)), v3.x);
            mxy = fmaxf(fmaxf(fmaxf(mxy, v0.y), fmaxf(v1.y, v2.y)), v3.y);
        }
        for (; j < lim; j++) {
            int sj = __shfl(s, j);
            float2 v = *(const float2*)&ht[(size_t)sj * HIDDEN + lo2];
            sx += v.x; sy += v.y;
            mxx = fmaxf(mxx, v.x); mxy = fmaxf(mxy, v.y);
        }
    }
    float invd = 1.0f / degf[node];
    float meanx = sx * invd, meany = sy * invd;
    if (cnt == 0) { mxx = 0.f; mxy = 0.f; }
    float2 self = *(const float2*)&ht[(size_t)node * HIDDEN + lo2];
    float hx = ap0 * meanx + ap1 * mxx + ap2 * self.x;
    float hy = ap0 * meany + ap1 * mxy + ap2 * self.y;
    hx = fmaxf(hx, 0.f); hy = fmaxf(hy, 0.f);

    float cpv = first ? 1.0f : cp[node];
    float w = cpv * sp1;
    float2* selp = (float2*)&selected[(size_t)node * HIDDEN + lo2];
    if (first) {
        *selp = make_float2(w * hx, w * hy);
    } else {
        float2 sv = *selp;
        sv.x += w * hx; sv.y += w * hy;
        *selp = sv;
    }
    *(float2*)&h[(size_t)node * HIDDEN + lo2] = make_float2(hx, hy);
    if (lane == 0) cp[node] = cpv * sp0;
}

// ---------------- post GEMM (128x40) + log_softmax, block-tiled ----------------
// 32 nodes per 256-thread block; selected rows + W_post^T staged in LDS;
// 8 threads per node, 5 classes each; log-softmax via shfl_xor over the 8-group.

__launch_bounds__(256)
__global__ void k_post(const float* __restrict__ selected, const float* __restrict__ Wp,
                       const float* __restrict__ bp, float* __restrict__ out, int N) {
    __shared__ float Ss[32][132];    // padded: bank = (4*row + k) % 32
    __shared__ float Wt[NCLS][132];  // transposed W_post, padded
    __shared__ float bs[NCLS];
    const int tid = threadIdx.x;
    const int n0 = blockIdx.x * 32;

    // stage W_post (128x40) transposed
    for (int i = tid; i < (HIDDEN * NCLS) / 4; i += 256) {   // 1280 float4
        float4 v = *(const float4*)&Wp[i * 4];
        int f = i * 4;
        int k = f / NCLS, c = f % NCLS;
        // 4 consecutive flat elems; c may wrap to next k
        float e[4] = {v.x, v.y, v.z, v.w};
        #pragma unroll
        for (int j = 0; j < 4; j++) {
            int cc = c + j, kk = k;
            if (cc >= NCLS) { cc -= NCLS; kk++; }
            Wt[cc][kk] = e[j];
        }
    }
    if (tid < NCLS) bs[tid] = bp[tid];
    // stage 32 selected rows (coalesced float4)
    #pragma unroll
    for (int p = 0; p < 4; p++) {
        int fi = p * 256 + tid;          // float4 index 0..1023
        int row = fi >> 5;               // 32 float4 per row
        int col = (fi & 31) * 4;
        int rg = n0 + row;
        float4 v = make_float4(0.f, 0.f, 0.f, 0.f);
        if (rg < N) v = *(const float4*)&selected[(size_t)rg * HIDDEN + col];
        *(float4*)&Ss[row][col] = v;
    }
    __syncthreads();

    const int node_l = tid >> 3;         // 0..31
    const int c0 = (tid & 7) * 5;        // 0,5,...,35
    float z[5];
    #pragma unroll
    for (int i = 0; i < 5; i++) z[i] = bs[c0 + i];
    for (int k = 0; k < HIDDEN; k += 4) {
        float4 s4 = *(const float4*)&Ss[node_l][k];
        #pragma unroll
        for (int i = 0; i < 5; i++) {
            float4 w4 = *(const float4*)&Wt[c0 + i][k];
            z[i] += s4.x * w4.x + s4.y * w4.y + s4.z * w4.z + s4.w * w4.w;
        }
    }
    float m = z[0];
    #pragma unroll
    for (int i = 1; i < 5; i++) m = fmaxf(m, z[i]);
    #pragma unroll
    for (int off = 1; off < 8; off <<= 1) m = fmaxf(m, __shfl_xor(m, off));
    float s = 0.f;
    #pragma unroll
    for (int i = 0; i < 5; i++) s += expf(z[i] - m);
    #pragma unroll
    for (int off = 1; off < 8; off <<= 1) s += __shfl_xor(s, off);
    float lg = m + logf(s);
    int ng = n0 + node_l;
    if (ng < N) {
        #pragma unroll
        for (int i = 0; i < 5; i++)
            out[(size_t)ng * NCLS + c0 + i] = z[i] - lg;
    }
}

// ---------------- launch ----------------

extern "C" void kernel_launch(void* const* d_in, const int* in_sizes, int n_in,
                              void* d_out, int out_size, void* d_ws, size_t ws_size,
                              hipStream_t stream) {
    const float* x      = (const float*)d_in[0];
    const int*   ei     = (const int*)d_in[1];
    const float* W_pre  = (const float*)d_in[2];
    const float* b_pre  = (const float*)d_in[3];
    const float* W_dep  = (const float*)d_in[4];
    const float* b_dep  = (const float*)d_in[5];
    const float* W_aggr = (const float*)d_in[6];
    const float* b_aggr = (const float*)d_in[7];
    const float* W_conv = (const float*)d_in[8];
    const float* b_conv = (const float*)d_in[9];
    const float* W_post = (const float*)d_in[10];
    const float* b_post = (const float*)d_in[11];

    const int N = in_sizes[0] / HIDDEN;
    const int E = in_sizes[1] / 2;

    char* ws = (char*)d_ws;
    size_t off = 0;
    auto alloc = [&](size_t bytes) -> void* {
        void* p = ws + off;
        off += (bytes + 255) & ~(size_t)255;
        return p;
    };
    float* h        = (float*)alloc((size_t)N * HIDDEN * 4);
    float* ht       = (float*)alloc((size_t)N * HIDDEN * 4);
    float* selected = (float*)alloc((size_t)N * HIDDEN * 4);
    float* cp       = (float*)alloc((size_t)N * 4);
    float* degf     = (float*)alloc((size_t)N * 4);
    int*   ibuf     = (int*)alloc((size_t)(2 * N + 64) * 4); // deg_i | cursor | counter
    int*   deg_i    = ibuf;
    int*   cursor   = ibuf + N;
    int*   counter  = ibuf + 2 * N;
    int*   row_start= (int*)alloc((size_t)N * 4);
    int*   csr_src  = (int*)alloc((size_t)E * 4);

    hipMemsetAsync(ibuf, 0, (size_t)(2 * N + 1) * 4, stream);

    int eb = (E + 255) / 256;
    int nb = (N + 255) / 256;
    k_count<<<eb, 256, 0, stream>>>(ei, E, deg_i);
    k_scan<<<nb, 256, 0, stream>>>(deg_i, N, row_start, degf, counter);
    k_fill<<<eb, 256, 0, stream>>>(ei, E, row_start, cursor, csr_src);

    dim3 gg((N + 63) / 64, 2);
    k_gemm128<<<gg, 256, 0, stream>>>(x, W_pre, b_pre, h, N, 1);

    int nb4 = (N + 3) / 4;
    for (int d = 0; d < 4; d++) {
        k_gemm128<<<gg, 256, 0, stream>>>(h, W_conv + (size_t)d * HIDDEN * HIDDEN,
                                          b_conv + (size_t)d * HIDDEN, ht, N, 0);
        k_depth<<<nb4, 256, 0, stream>>>(h, ht, selected, cp, degf, deg_i,
                                         row_start, csr_src,
                                         W_dep, b_dep, W_aggr, b_aggr,
                                         N, d == 0 ? 1 : 0);
    }
    k_post<<<(N + 31) / 32, 256, 0, stream>>>(selected, W_post, b_post, (float*)d_out, N);
}

// Round 3
// 1004.936 us; speedup vs baseline: 1.3234x; 1.1030x over previous
//
#include <hip/hip_runtime.h>
#include <math.h>

#define HIDDEN 128
#define NCLS 40

typedef __attribute__((ext_vector_type(8))) short short8;
typedef __attribute__((ext_vector_type(4))) float f32x4;

__device__ __forceinline__ float wave_reduce_sum(float v) {
    #pragma unroll
    for (int off = 32; off > 0; off >>= 1) v += __shfl_xor(v, off);
    return v;
}

__device__ __forceinline__ unsigned short f2bf(float f) {
    unsigned u = __float_as_uint(f);
    unsigned r = u + 0x7FFFu + ((u >> 16) & 1u);   // RNE
    return (unsigned short)(r >> 16);
}
__device__ __forceinline__ float bf2f(unsigned short h) {
    return __uint_as_float((unsigned)h << 16);
}

// ---------------- dtype conversion / weight transpose ----------------

__global__ void k_f2bf4(const float* __restrict__ in, unsigned short* __restrict__ out, int n4) {
    int i = blockIdx.x * 256 + threadIdx.x;
    if (i < n4) {
        float4 v = *(const float4*)(in + (size_t)i * 4);
        ushort4 o;
        o.x = f2bf(v.x); o.y = f2bf(v.y); o.z = f2bf(v.z); o.w = f2bf(v.w);
        *(ushort4*)(out + (size_t)i * 4) = o;
    }
}

// Wt[m][n][k] = W[m][k][n], bf16
__global__ void k_wt(const float* __restrict__ W, unsigned short* __restrict__ Wt, int total) {
    int i = blockIdx.x * 256 + threadIdx.x;
    if (i < total) {
        int m = i >> 14;
        int rem = i & 16383;
        int n = rem >> 7, k = rem & 127;
        Wt[i] = f2bf(W[(m << 14) + k * 128 + n]);
    }
}

// ---------------- CSR build ----------------

__global__ void k_count(const int* __restrict__ ei, int E, int* __restrict__ deg_i) {
    int e = blockIdx.x * 256 + threadIdx.x;
    if (e < E) atomicAdd(&deg_i[ei[E + e]], 1);  // dst = ei[E+e]
}

__global__ void k_scan(const int* __restrict__ deg_i, int N,
                       int* __restrict__ row_start, float* __restrict__ degf,
                       int* __restrict__ counter) {
    __shared__ int sd[256];
    __shared__ int sbase;
    int tid = threadIdx.x;
    int n = blockIdx.x * 256 + tid;
    int v = (n < N) ? deg_i[n] : 0;
    sd[tid] = v;
    __syncthreads();
    #pragma unroll
    for (int off = 1; off < 256; off <<= 1) {
        int t = (tid >= off) ? sd[tid - off] : 0;
        __syncthreads();
        sd[tid] += t;
        __syncthreads();
    }
    int incl = sd[tid];
    if (tid == 255) sbase = atomicAdd(counter, incl);
    __syncthreads();
    if (n < N) {
        row_start[n] = sbase + incl - v;
        degf[n] = fmaxf((float)v, 1.0f);
    }
}

__global__ void k_fill(const int* __restrict__ ei, int E,
                       const int* __restrict__ row_start, int* __restrict__ cursor,
                       int* __restrict__ csr_src) {
    int e = blockIdx.x * 256 + threadIdx.x;
    if (e < E) {
        int s = ei[e];
        int d = ei[E + e];
        int pos = row_start[d] + atomicAdd(&cursor[d], 1);
        csr_src[pos] = s;
    }
}

// ---------------- bf16 MFMA GEMM: C[M,128] = A_bf[M,128] @ W[128,128] + bias ----------------
// Wt is W transposed [n][k] bf16. Block 256 = 4 waves; tile 128 rows x 128 cols.
// Wave w: 64x64 quadrant; 4x4 grid of 16x16x32 MFMAs. LDS rows padded to 40 bf16
// (80 B stride -> max 2-way bank aliasing, free per m136).

__launch_bounds__(256)
__global__ void k_gemm_mfma(const unsigned short* __restrict__ A,
                            const unsigned short* __restrict__ Wt,
                            const float* __restrict__ bias,
                            float* __restrict__ Cf, unsigned short* __restrict__ Cb,
                            int M, int do_relu) {
    __shared__ unsigned short As[128 * 40];
    __shared__ unsigned short Ws[128 * 40];
    const int tid = threadIdx.x;
    const int lane = tid & 63;
    const int wv = tid >> 6;
    const int row_blk = blockIdx.x * 128;
    const int rows0 = (wv >> 1) * 64;
    const int cols0 = (wv & 1) * 64;
    const int l15 = lane & 15;
    const int q = lane >> 4;

    f32x4 acc[4][4] = {};
    for (int k0 = 0; k0 < 128; k0 += 32) {
        // stage A tile (128x32) and Wt tile (128x32): 512 chunks of 16B each
        #pragma unroll
        for (int i = 0; i < 2; i++) {
            int c = tid + i * 256;
            int r = c >> 2;            // row 0..127
            int ch = c & 3;            // 16B chunk in row
            uint4 av = make_uint4(0u, 0u, 0u, 0u);
            int ar = row_blk + r;
            if (ar < M) av = *(const uint4*)(A + (size_t)ar * HIDDEN + k0 + ch * 8);
            *(uint4*)&As[r * 40 + ch * 8] = av;
            uint4 wvv = *(const uint4*)(Wt + (size_t)r * HIDDEN + k0 + ch * 8);
            *(uint4*)&Ws[r * 40 + ch * 8] = wvv;
        }
        __syncthreads();
        short8 af[4], bfr[4];
        #pragma unroll
        for (int mi = 0; mi < 4; mi++)
            af[mi] = *(const short8*)&As[(rows0 + mi * 16 + l15) * 40 + q * 8];
        #pragma unroll
        for (int ni = 0; ni < 4; ni++)
            bfr[ni] = *(const short8*)&Ws[(cols0 + ni * 16 + l15) * 40 + q * 8];
        #pragma unroll
        for (int mi = 0; mi < 4; mi++)
            #pragma unroll
            for (int ni = 0; ni < 4; ni++)
                acc[mi][ni] = __builtin_amdgcn_mfma_f32_16x16x32_bf16(
                    af[mi], bfr[ni], acc[mi][ni], 0, 0, 0);
        __syncthreads();
    }
    // epilogue: C/D layout col=lane&15, row=quad*4+reg
    #pragma unroll
    for (int ni = 0; ni < 4; ni++) {
        int col = cols0 + ni * 16 + l15;
        float bv = bias[col];
        #pragma unroll
        for (int mi = 0; mi < 4; mi++) {
            #pragma unroll
            for (int r = 0; r < 4; r++) {
                int row = row_blk + rows0 + mi * 16 + q * 4 + r;
                if (row < M) {
                    float o = acc[mi][ni][r] + bv;
                    if (do_relu) o = fmaxf(o, 0.f);
                    if (Cf) Cf[(size_t)row * HIDDEN + col] = o;
                    if (Cb) Cb[(size_t)row * HIDDEN + col] = f2bf(o);
                }
            }
        }
    }
}

// ---------------- fused depth step ----------------
// one wave per node; h stored bf16; ht fp32; 4x-unrolled gather

__launch_bounds__(256)
__global__ void k_depth(unsigned short* __restrict__ hb, const float* __restrict__ ht,
                        float* __restrict__ selected, float* __restrict__ cp,
                        const float* __restrict__ degf, const int* __restrict__ deg_i,
                        const int* __restrict__ row_start, const int* __restrict__ csr_src,
                        const float* __restrict__ Wd, const float* __restrict__ bd,
                        const float* __restrict__ Wa, const float* __restrict__ ba,
                        int N, int first) {
    int lane = threadIdx.x & 63;
    int wave = threadIdx.x >> 6;
    int node = blockIdx.x * 4 + wave;
    if (node >= N) return;

    ushort2 hu = *(const ushort2*)&hb[(size_t)node * HIDDEN + lane * 2];
    float hvx = bf2f(hu.x), hvy = bf2f(hu.y);
    int k0 = lane * 2, k1 = lane * 2 + 1;
    float d0 = hvx * Wd[k0 * 2 + 0] + hvy * Wd[k1 * 2 + 0];
    float d1 = hvx * Wd[k0 * 2 + 1] + hvy * Wd[k1 * 2 + 1];
    float a0 = hvx * Wa[k0 * 3 + 0] + hvy * Wa[k1 * 3 + 0];
    float a1 = hvx * Wa[k0 * 3 + 1] + hvy * Wa[k1 * 3 + 1];
    float a2 = hvx * Wa[k0 * 3 + 2] + hvy * Wa[k1 * 3 + 2];
    d0 = wave_reduce_sum(d0); d1 = wave_reduce_sum(d1);
    a0 = wave_reduce_sum(a0); a1 = wave_reduce_sum(a1); a2 = wave_reduce_sum(a2);
    d0 += bd[0]; d1 += bd[1];
    a0 += ba[0]; a1 += ba[1]; a2 += ba[2];
    float m2 = fmaxf(d0, d1);
    float e0 = expf(d0 - m2), e1 = expf(d1 - m2);
    float inv2 = 1.f / (e0 + e1);
    float sp0 = e0 * inv2, sp1 = e1 * inv2;
    float m3 = fmaxf(fmaxf(a0, a1), a2);
    float f0 = expf(a0 - m3), f1 = expf(a1 - m3), f2 = expf(a2 - m3);
    float inv3 = 1.f / (f0 + f1 + f2);
    float ap0 = f0 * inv3, ap1 = f1 * inv3, ap2 = f2 * inv3;

    int cnt = deg_i[node], start = row_start[node];
    float sx = 0.f, sy = 0.f, mxx = -3.4e38f, mxy = -3.4e38f;
    const int lo2 = lane * 2;
    for (int eb = 0; eb < cnt; eb += 64) {
        int idx = eb + lane;
        int s = (idx < cnt) ? csr_src[start + idx] : 0;
        int lim = min(64, cnt - eb);
        int j = 0;
        for (; j + 4 <= lim; j += 4) {
            int s0 = __shfl(s, j + 0);
            int s1 = __shfl(s, j + 1);
            int s2 = __shfl(s, j + 2);
            int s3 = __shfl(s, j + 3);
            float2 v0 = *(const float2*)&ht[(size_t)s0 * HIDDEN + lo2];
            float2 v1 = *(const float2*)&ht[(size_t)s1 * HIDDEN + lo2];
            float2 v2 = *(const float2*)&ht[(size_t)s2 * HIDDEN + lo2];
            float2 v3 = *(const float2*)&ht[(size_t)s3 * HIDDEN + lo2];
            sx += (v0.x + v1.x) + (v2.x + v3.x);
            sy += (v0.y + v1.y) + (v2.y + v3.y);
            mxx = fmaxf(fmaxf(fmaxf(mxx, v0.x), fmaxf(v1.x, v2.x)), v3.x);
            mxy = fmaxf(fmaxf(fmaxf(mxy, v0.y), fmaxf(v1.y, v2.y)), v3.y);
        }
        for (; j < lim; j++) {
            int sj = __shfl(s, j);
            float2 v = *(const float2*)&ht[(size_t)sj * HIDDEN + lo2];
            sx += v.x; sy += v.y;
            mxx = fmaxf(mxx, v.x); mxy = fmaxf(mxy, v.y);
        }
    }
    float invd = 1.0f / degf[node];
    float meanx = sx * invd, meany = sy * invd;
    if (cnt == 0) { mxx = 0.f; mxy = 0.f; }
    float2 self = *(const float2*)&ht[(size_t)node * HIDDEN + lo2];
    float hx = ap0 * meanx + ap1 * mxx + ap2 * self.x;
    float hy = ap0 * meany + ap1 * mxy + ap2 * self.y;
    hx = fmaxf(hx, 0.f); hy = fmaxf(hy, 0.f);

    float cpv = first ? 1.0f : cp[node];
    float w = cpv * sp1;
    float2* selp = (float2*)&selected[(size_t)node * HIDDEN + lo2];
    if (first) {
        *selp = make_float2(w * hx, w * hy);
    } else {
        float2 sv = *selp;
        sv.x += w * hx; sv.y += w * hy;
        *selp = sv;
    }
    ushort2 ho; ho.x = f2bf(hx); ho.y = f2bf(hy);
    *(ushort2*)&hb[(size_t)node * HIDDEN + lo2] = ho;
    if (lane == 0) cp[node] = cpv * sp0;
}

// ---------------- post GEMM (128x40) + log_softmax, block-tiled ----------------

__launch_bounds__(256)
__global__ void k_post(const float* __restrict__ selected, const float* __restrict__ Wp,
                       const float* __restrict__ bp, float* __restrict__ out, int N) {
    __shared__ float Ss[32][132];
    __shared__ float Wt[NCLS][132];
    __shared__ float bs[NCLS];
    const int tid = threadIdx.x;
    const int n0 = blockIdx.x * 32;

    for (int i = tid; i < (HIDDEN * NCLS) / 4; i += 256) {
        float4 v = *(const float4*)&Wp[i * 4];
        int f = i * 4;
        int k = f / NCLS, c = f % NCLS;
        float e[4] = {v.x, v.y, v.z, v.w};
        #pragma unroll
        for (int j = 0; j < 4; j++) {
            int cc = c + j, kk = k;
            if (cc >= NCLS) { cc -= NCLS; kk++; }
            Wt[cc][kk] = e[j];
        }
    }
    if (tid < NCLS) bs[tid] = bp[tid];
    #pragma unroll
    for (int p = 0; p < 4; p++) {
        int fi = p * 256 + tid;
        int row = fi >> 5;
        int col = (fi & 31) * 4;
        int rg = n0 + row;
        float4 v = make_float4(0.f, 0.f, 0.f, 0.f);
        if (rg < N) v = *(const float4*)&selected[(size_t)rg * HIDDEN + col];
        *(float4*)&Ss[row][col] = v;
    }
    __syncthreads();

    const int node_l = tid >> 3;
    const int c0 = (tid & 7) * 5;
    float z[5];
    #pragma unroll
    for (int i = 0; i < 5; i++) z[i] = bs[c0 + i];
    for (int k = 0; k < HIDDEN; k += 4) {
        float4 s4 = *(const float4*)&Ss[node_l][k];
        #pragma unroll
        for (int i = 0; i < 5; i++) {
            float4 w4 = *(const float4*)&Wt[c0 + i][k];
            z[i] += s4.x * w4.x + s4.y * w4.y + s4.z * w4.z + s4.w * w4.w;
        }
    }
    float m = z[0];
    #pragma unroll
    for (int i = 1; i < 5; i++) m = fmaxf(m, z[i]);
    #pragma unroll
    for (int off = 1; off < 8; off <<= 1) m = fmaxf(m, __shfl_xor(m, off));
    float s = 0.f;
    #pragma unroll
    for (int i = 0; i < 5; i++) s += expf(z[i] - m);
    #pragma unroll
    for (int off = 1; off < 8; off <<= 1) s += __shfl_xor(s, off);
    float lg = m + logf(s);
    int ng = n0 + node_l;
    if (ng < N) {
        #pragma unroll
        for (int i = 0; i < 5; i++)
            out[(size_t)ng * NCLS + c0 + i] = z[i] - lg;
    }
}

// ---------------- launch ----------------

extern "C" void kernel_launch(void* const* d_in, const int* in_sizes, int n_in,
                              void* d_out, int out_size, void* d_ws, size_t ws_size,
                              hipStream_t stream) {
    const float* x      = (const float*)d_in[0];
    const int*   ei     = (const int*)d_in[1];
    const float* W_pre  = (const float*)d_in[2];
    const float* b_pre  = (const float*)d_in[3];
    const float* W_dep  = (const float*)d_in[4];
    const float* b_dep  = (const float*)d_in[5];
    const float* W_aggr = (const float*)d_in[6];
    const float* b_aggr = (const float*)d_in[7];
    const float* W_conv = (const float*)d_in[8];
    const float* b_conv = (const float*)d_in[9];
    const float* W_post = (const float*)d_in[10];
    const float* b_post = (const float*)d_in[11];

    const int N = in_sizes[0] / HIDDEN;
    const int E = in_sizes[1] / 2;

    char* ws = (char*)d_ws;
    size_t off = 0;
    auto alloc = [&](size_t bytes) -> void* {
        void* p = ws + off;
        off += (bytes + 255) & ~(size_t)255;
        return p;
    };
    unsigned short* x_bf   = (unsigned short*)alloc((size_t)N * HIDDEN * 2);
    unsigned short* h_bf   = (unsigned short*)alloc((size_t)N * HIDDEN * 2);
    float* ht       = (float*)alloc((size_t)N * HIDDEN * 4);
    float* selected = (float*)alloc((size_t)N * HIDDEN * 4);
    float* cp       = (float*)alloc((size_t)N * 4);
    float* degf     = (float*)alloc((size_t)N * 4);
    unsigned short* WpreT  = (unsigned short*)alloc(128 * 128 * 2);
    unsigned short* WconvT = (unsigned short*)alloc(4 * 128 * 128 * 2);
    int*   ibuf     = (int*)alloc((size_t)(2 * N + 64) * 4);
    int*   deg_i    = ibuf;
    int*   cursor   = ibuf + N;
    int*   counter  = ibuf + 2 * N;
    int*   row_start= (int*)alloc((size_t)N * 4);
    int*   csr_src  = (int*)alloc((size_t)E * 4);

    hipMemsetAsync(ibuf, 0, (size_t)(2 * N + 1) * 4, stream);

    int eb = (E + 255) / 256;
    int nb = (N + 255) / 256;
    k_count<<<eb, 256, 0, stream>>>(ei, E, deg_i);
    k_scan<<<nb, 256, 0, stream>>>(deg_i, N, row_start, degf, counter);
    k_fill<<<eb, 256, 0, stream>>>(ei, E, row_start, cursor, csr_src);

    // conversions
    int n4 = N * HIDDEN / 4;
    k_f2bf4<<<(n4 + 255) / 256, 256, 0, stream>>>(x, x_bf, n4);
    k_wt<<<(16384 + 255) / 256, 256, 0, stream>>>(W_pre, WpreT, 16384);
    k_wt<<<(4 * 16384 + 255) / 256, 256, 0, stream>>>(W_conv, WconvT, 4 * 16384);

    int gblk = (N + 127) / 128;
    // h = relu(x @ W_pre + b_pre) -> bf16
    k_gemm_mfma<<<gblk, 256, 0, stream>>>(x_bf, WpreT, b_pre, nullptr, h_bf, N, 1);

    int nb4 = (N + 3) / 4;
    for (int d = 0; d < 4; d++) {
        k_gemm_mfma<<<gblk, 256, 0, stream>>>(h_bf, WconvT + (size_t)d * 16384,
                                              b_conv + (size_t)d * HIDDEN, ht, nullptr, N, 0);
        k_depth<<<nb4, 256, 0, stream>>>(h_bf, ht, selected, cp, degf, deg_i,
                                         row_start, csr_src,
                                         W_dep, b_dep, W_aggr, b_aggr,
                                         N, d == 0 ? 1 : 0);
    }
    k_post<<<(N + 31) / 32, 256, 0, stream>>>(selected, W_post, b_post, (float*)d_out, N);
}

// Round 4
// 784.624 us; speedup vs baseline: 1.6950x; 1.2808x over previous
//
#include <hip/hip_runtime.h>
#include <math.h>

#define HIDDEN 128
#define NCLS 40

typedef __attribute__((ext_vector_type(8))) short short8;
typedef __attribute__((ext_vector_type(4))) float f32x4;

__device__ __forceinline__ float wave_reduce_sum(float v) {
    #pragma unroll
    for (int off = 32; off > 0; off >>= 1) v += __shfl_xor(v, off);
    return v;
}

__device__ __forceinline__ unsigned short f2bf(float f) {
    unsigned u = __float_as_uint(f);
    unsigned r = u + 0x7FFFu + ((u >> 16) & 1u);   // RNE
    return (unsigned short)(r >> 16);
}
__device__ __forceinline__ float bf_lo(unsigned u) { return __uint_as_float(u << 16); }
__device__ __forceinline__ float bf_hi(unsigned u) { return __uint_as_float(u & 0xFFFF0000u); }

// ---------------- weight transpose: Wt[m][n][k] = W[m][k][n], bf16 ----------------

__global__ void k_wt(const float* __restrict__ W, unsigned short* __restrict__ Wt, int total) {
    int i = blockIdx.x * 256 + threadIdx.x;
    if (i < total) {
        int m = i >> 14;
        int rem = i & 16383;
        int n = rem >> 7, k = rem & 127;
        Wt[i] = f2bf(W[(m << 14) + k * 128 + n]);
    }
}

// ---------------- CSR build ----------------

__global__ void k_count(const int* __restrict__ ei, int E, int* __restrict__ deg_i) {
    int e = blockIdx.x * 256 + threadIdx.x;
    if (e < E) atomicAdd(&deg_i[ei[E + e]], 1);
}

__global__ void k_scan(const int* __restrict__ deg_i, int N,
                       int* __restrict__ row_start, float* __restrict__ degf,
                       int* __restrict__ counter) {
    __shared__ int sd[256];
    __shared__ int sbase;
    int tid = threadIdx.x;
    int n = blockIdx.x * 256 + tid;
    int v = (n < N) ? deg_i[n] : 0;
    sd[tid] = v;
    __syncthreads();
    #pragma unroll
    for (int off = 1; off < 256; off <<= 1) {
        int t = (tid >= off) ? sd[tid - off] : 0;
        __syncthreads();
        sd[tid] += t;
        __syncthreads();
    }
    int incl = sd[tid];
    if (tid == 255) sbase = atomicAdd(counter, incl);
    __syncthreads();
    if (n < N) {
        row_start[n] = sbase + incl - v;
        degf[n] = fmaxf((float)v, 1.0f);
    }
}

__global__ void k_fill(const int* __restrict__ ei, int E,
                       const int* __restrict__ row_start, int* __restrict__ cursor,
                       int* __restrict__ csr_src) {
    int e = blockIdx.x * 256 + threadIdx.x;
    if (e < E) {
        int s = ei[e];
        int d = ei[E + e];
        int pos = row_start[d] + atomicAdd(&cursor[d], 1);
        csr_src[pos] = s;
    }
}

// ---------------- bf16 MFMA GEMM: Cb[M,128] = A[M,128] @ W[128,128] + bias (bf16 out) ----
// AF32: A is fp32 (converted during LDS staging). Wt is W^T [n][k] bf16.
// 128x128 tile, 4 waves, 4x4 grid of 16x16x32 MFMAs per wave.
// LDS rows padded to 40 shorts (80 B stride).

template <bool AF32>
__launch_bounds__(256)
__global__ void k_gemm_mfma(const void* __restrict__ Ain,
                            const unsigned short* __restrict__ Wt,
                            const float* __restrict__ bias,
                            unsigned short* __restrict__ Cb,
                            int M, int do_relu) {
    __shared__ unsigned short As[128 * 40];
    __shared__ unsigned short Ws[128 * 40];
    const int tid = threadIdx.x;
    const int lane = tid & 63;
    const int wv = tid >> 6;
    const int row_blk = blockIdx.x * 128;
    const int rows0 = (wv >> 1) * 64;
    const int cols0 = (wv & 1) * 64;
    const int l15 = lane & 15;
    const int q = lane >> 4;

    f32x4 acc[4][4] = {};
    for (int k0 = 0; k0 < 128; k0 += 32) {
        // stage Wt tile (128 n-rows x 32 k) : 512 x 16B
        #pragma unroll
        for (int i = 0; i < 2; i++) {
            int c = tid + i * 256;
            int r = c >> 2, ch = c & 3;
            uint4 wvv = *(const uint4*)(Wt + (size_t)r * HIDDEN + k0 + ch * 8);
            *(uint4*)&Ws[r * 40 + ch * 8] = wvv;
        }
        if (AF32) {
            const float* A = (const float*)Ain;
            #pragma unroll
            for (int i = 0; i < 4; i++) {
                int c = tid + i * 256;
                int r = c >> 3, ch = c & 7;        // 8 float4 per row of 32 floats
                int ar = row_blk + r;
                float4 v = make_float4(0.f, 0.f, 0.f, 0.f);
                if (ar < M) v = *(const float4*)(A + (size_t)ar * HIDDEN + k0 + ch * 4);
                ushort4 o;
                o.x = f2bf(v.x); o.y = f2bf(v.y); o.z = f2bf(v.z); o.w = f2bf(v.w);
                *(ushort4*)&As[r * 40 + ch * 4] = o;
            }
        } else {
            const unsigned short* A = (const unsigned short*)Ain;
            #pragma unroll
            for (int i = 0; i < 2; i++) {
                int c = tid + i * 256;
                int r = c >> 2, ch = c & 3;
                uint4 av = make_uint4(0u, 0u, 0u, 0u);
                int ar = row_blk + r;
                if (ar < M) av = *(const uint4*)(A + (size_t)ar * HIDDEN + k0 + ch * 8);
                *(uint4*)&As[r * 40 + ch * 8] = av;
            }
        }
        __syncthreads();
        short8 af[4], bfr[4];
        #pragma unroll
        for (int mi = 0; mi < 4; mi++)
            af[mi] = *(const short8*)&As[(rows0 + mi * 16 + l15) * 40 + q * 8];
        #pragma unroll
        for (int ni = 0; ni < 4; ni++)
            bfr[ni] = *(const short8*)&Ws[(cols0 + ni * 16 + l15) * 40 + q * 8];
        #pragma unroll
        for (int mi = 0; mi < 4; mi++)
            #pragma unroll
            for (int ni = 0; ni < 4; ni++)
                acc[mi][ni] = __builtin_amdgcn_mfma_f32_16x16x32_bf16(
                    af[mi], bfr[ni], acc[mi][ni], 0, 0, 0);
        __syncthreads();
    }
    // epilogue: C/D layout col=lane&15, row=quad*4+reg
    #pragma unroll
    for (int ni = 0; ni < 4; ni++) {
        int col = cols0 + ni * 16 + l15;
        float bv = bias[col];
        #pragma unroll
        for (int mi = 0; mi < 4; mi++) {
            #pragma unroll
            for (int r = 0; r < 4; r++) {
                int row = row_blk + rows0 + mi * 16 + q * 4 + r;
                if (row < M) {
                    float o = acc[mi][ni][r] + bv;
                    if (do_relu) o = fmaxf(o, 0.f);
                    Cb[(size_t)row * HIDDEN + col] = f2bf(o);
                }
            }
        }
    }
}

// ---------------- fused depth step ----------------
// one wave per node. h_in/ht/h_out all bf16. Stores per-depth select weight w_d;
// `selected` is never materialized (k_post reconstructs it).

__launch_bounds__(256)
__global__ void k_depth(const unsigned short* __restrict__ h_in,
                        const unsigned short* __restrict__ ht,
                        unsigned short* __restrict__ h_out,
                        float* __restrict__ cp, float* __restrict__ wsel,
                        const float* __restrict__ degf, const int* __restrict__ deg_i,
                        const int* __restrict__ row_start, const int* __restrict__ csr_src,
                        const float* __restrict__ Wd, const float* __restrict__ bd,
                        const float* __restrict__ Wa, const float* __restrict__ ba,
                        int N, int first) {
    int lane = threadIdx.x & 63;
    int wave = threadIdx.x >> 6;
    int node = blockIdx.x * 4 + wave;
    if (node >= N) return;
    const int lo2 = lane * 2;

    unsigned hu = *(const unsigned*)&h_in[(size_t)node * HIDDEN + lo2];
    float hvx = bf_lo(hu), hvy = bf_hi(hu);
    int k0 = lo2, k1 = lo2 + 1;
    float d0 = hvx * Wd[k0 * 2 + 0] + hvy * Wd[k1 * 2 + 0];
    float d1 = hvx * Wd[k0 * 2 + 1] + hvy * Wd[k1 * 2 + 1];
    float a0 = hvx * Wa[k0 * 3 + 0] + hvy * Wa[k1 * 3 + 0];
    float a1 = hvx * Wa[k0 * 3 + 1] + hvy * Wa[k1 * 3 + 1];
    float a2 = hvx * Wa[k0 * 3 + 2] + hvy * Wa[k1 * 3 + 2];
    d0 = wave_reduce_sum(d0); d1 = wave_reduce_sum(d1);
    a0 = wave_reduce_sum(a0); a1 = wave_reduce_sum(a1); a2 = wave_reduce_sum(a2);
    d0 += bd[0]; d1 += bd[1];
    a0 += ba[0]; a1 += ba[1]; a2 += ba[2];
    float m2 = fmaxf(d0, d1);
    float e0 = expf(d0 - m2), e1 = expf(d1 - m2);
    float inv2 = 1.f / (e0 + e1);
    float sp0 = e0 * inv2, sp1 = e1 * inv2;
    float m3 = fmaxf(fmaxf(a0, a1), a2);
    float f0 = expf(a0 - m3), f1 = expf(a1 - m3), f2 = expf(a2 - m3);
    float inv3 = 1.f / (f0 + f1 + f2);
    float ap0 = f0 * inv3, ap1 = f1 * inv3, ap2 = f2 * inv3;

    // aggregate: sum + max over bf16 rows of ht[src]
    int cnt = deg_i[node], start = row_start[node];
    float sx = 0.f, sy = 0.f, mxx = -3.4e38f, mxy = -3.4e38f;
    for (int eb = 0; eb < cnt; eb += 64) {
        int idx = eb + lane;
        int s = (idx < cnt) ? csr_src[start + idx] : 0;
        int lim = min(64, cnt - eb);
        int j = 0;
        for (; j + 4 <= lim; j += 4) {
            int s0 = __shfl(s, j + 0);
            int s1 = __shfl(s, j + 1);
            int s2 = __shfl(s, j + 2);
            int s3 = __shfl(s, j + 3);
            unsigned u0 = *(const unsigned*)&ht[(size_t)s0 * HIDDEN + lo2];
            unsigned u1 = *(const unsigned*)&ht[(size_t)s1 * HIDDEN + lo2];
            unsigned u2 = *(const unsigned*)&ht[(size_t)s2 * HIDDEN + lo2];
            unsigned u3 = *(const unsigned*)&ht[(size_t)s3 * HIDDEN + lo2];
            float x0 = bf_lo(u0), y0 = bf_hi(u0);
            float x1 = bf_lo(u1), y1 = bf_hi(u1);
            float x2 = bf_lo(u2), y2 = bf_hi(u2);
            float x3 = bf_lo(u3), y3 = bf_hi(u3);
            sx += (x0 + x1) + (x2 + x3);
            sy += (y0 + y1) + (y2 + y3);
            mxx = fmaxf(fmaxf(fmaxf(mxx, x0), fmaxf(x1, x2)), x3);
            mxy = fmaxf(fmaxf(fmaxf(mxy, y0), fmaxf(y1, y2)), y3);
        }
        for (; j < lim; j++) {
            int sj = __shfl(s, j);
            unsigned u = *(const unsigned*)&ht[(size_t)sj * HIDDEN + lo2];
            float x = bf_lo(u), y = bf_hi(u);
            sx += x; sy += y;
            mxx = fmaxf(mxx, x); mxy = fmaxf(mxy, y);
        }
    }
    float invd = 1.0f / degf[node];
    float meanx = sx * invd, meany = sy * invd;
    if (cnt == 0) { mxx = 0.f; mxy = 0.f; }
    unsigned su = *(const unsigned*)&ht[(size_t)node * HIDDEN + lo2];
    float hx = ap0 * meanx + ap1 * mxx + ap2 * bf_lo(su);
    float hy = ap0 * meany + ap1 * mxy + ap2 * bf_hi(su);
    hx = fmaxf(hx, 0.f); hy = fmaxf(hy, 0.f);

    ushort2 ho; ho.x = f2bf(hx); ho.y = f2bf(hy);
    *(ushort2*)&h_out[(size_t)node * HIDDEN + lo2] = ho;

    if (lane == 0) {
        float cpv = first ? 1.0f : cp[node];
        wsel[node] = cpv * sp1;
        cp[node] = cpv * sp0;
    }
}

// ---------------- post: sel = sum_d w_d * h_{d+1}; logits = sel @ W_post + b; log_softmax ----
// 32 nodes / 256-thread block. Phase 1: 8 threads/node each build 16 sel values into LDS.
// Phase 2: 8 threads/node x 5 classes each, LDS dot products, shfl log-softmax.

__launch_bounds__(256)
__global__ void k_post(const unsigned short* __restrict__ h_all, size_t hstride,
                       const float* __restrict__ wsel, int N,
                       const float* __restrict__ Wp, const float* __restrict__ bp,
                       float* __restrict__ out) {
    __shared__ float Ss[32][132];
    __shared__ float Wt[NCLS][132];
    __shared__ float bs[NCLS];
    const int tid = threadIdx.x;
    const int n0 = blockIdx.x * 32;

    // stage W_post transposed
    for (int i = tid; i < (HIDDEN * NCLS) / 4; i += 256) {
        float4 v = *(const float4*)&Wp[i * 4];
        int f = i * 4;
        int k = f / NCLS, c = f % NCLS;
        float e[4] = {v.x, v.y, v.z, v.w};
        #pragma unroll
        for (int j = 0; j < 4; j++) {
            int cc = c + j, kk = k;
            if (cc >= NCLS) { cc -= NCLS; kk++; }
            Wt[cc][kk] = e[j];
        }
    }
    if (tid < NCLS) bs[tid] = bp[tid];

    // phase 1: reconstruct sel rows
    const int node_l = tid >> 3;          // 0..31
    const int kc = (tid & 7) * 16;        // k chunk
    const int ng = n0 + node_l;
    float sel[16];
    #pragma unroll
    for (int i = 0; i < 16; i++) sel[i] = 0.f;
    if (ng < N) {
        #pragma unroll
        for (int d = 0; d < 4; d++) {
            float w = wsel[(size_t)d * N + ng];
            const unsigned short* hrow = h_all + (size_t)(d + 1) * hstride + (size_t)ng * HIDDEN;
            #pragma unroll
            for (int u = 0; u < 2; u++) {
                uint4 p = *(const uint4*)(hrow + kc + u * 8);
                unsigned vs[4] = {p.x, p.y, p.z, p.w};
                #pragma unroll
                for (int j = 0; j < 4; j++) {
                    sel[u * 8 + j * 2 + 0] += w * bf_lo(vs[j]);
                    sel[u * 8 + j * 2 + 1] += w * bf_hi(vs[j]);
                }
            }
        }
    }
    #pragma unroll
    for (int u = 0; u < 4; u++)
        *(float4*)&Ss[node_l][kc + u * 4] =
            make_float4(sel[u * 4], sel[u * 4 + 1], sel[u * 4 + 2], sel[u * 4 + 3]);
    __syncthreads();

    // phase 2: 5 classes per thread
    const int c0 = (tid & 7) * 5;
    float z[5];
    #pragma unroll
    for (int i = 0; i < 5; i++) z[i] = bs[c0 + i];
    for (int k = 0; k < HIDDEN; k += 4) {
        float4 s4 = *(const float4*)&Ss[node_l][k];
        #pragma unroll
        for (int i = 0; i < 5; i++) {
            float4 w4 = *(const float4*)&Wt[c0 + i][k];
            z[i] += s4.x * w4.x + s4.y * w4.y + s4.z * w4.z + s4.w * w4.w;
        }
    }
    float m = z[0];
    #pragma unroll
    for (int i = 1; i < 5; i++) m = fmaxf(m, z[i]);
    #pragma unroll
    for (int off = 1; off < 8; off <<= 1) m = fmaxf(m, __shfl_xor(m, off));
    float s = 0.f;
    #pragma unroll
    for (int i = 0; i < 5; i++) s += expf(z[i] - m);
    #pragma unroll
    for (int off = 1; off < 8; off <<= 1) s += __shfl_xor(s, off);
    float lg = m + logf(s);
    if (ng < N) {
        #pragma unroll
        for (int i = 0; i < 5; i++)
            out[(size_t)ng * NCLS + c0 + i] = z[i] - lg;
    }
}

// ---------------- launch ----------------

extern "C" void kernel_launch(void* const* d_in, const int* in_sizes, int n_in,
                              void* d_out, int out_size, void* d_ws, size_t ws_size,
                              hipStream_t stream) {
    const float* x      = (const float*)d_in[0];
    const int*   ei     = (const int*)d_in[1];
    const float* W_pre  = (const float*)d_in[2];
    const float* b_pre  = (const float*)d_in[3];
    const float* W_dep  = (const float*)d_in[4];
    const float* b_dep  = (const float*)d_in[5];
    const float* W_aggr = (const float*)d_in[6];
    const float* b_aggr = (const float*)d_in[7];
    const float* W_conv = (const float*)d_in[8];
    const float* b_conv = (const float*)d_in[9];
    const float* W_post = (const float*)d_in[10];
    const float* b_post = (const float*)d_in[11];

    const int N = in_sizes[0] / HIDDEN;
    const int E = in_sizes[1] / 2;

    char* ws = (char*)d_ws;
    size_t off = 0;
    auto alloc = [&](size_t bytes) -> void* {
        void* p = ws + off;
        off += (bytes + 255) & ~(size_t)255;
        return p;
    };
    const size_t hstride = (size_t)N * HIDDEN;           // elements per depth buffer
    unsigned short* h_all  = (unsigned short*)alloc(5 * hstride * 2);  // h_0..h_4
    unsigned short* ht     = (unsigned short*)alloc(hstride * 2);
    float* cp       = (float*)alloc((size_t)N * 4);
    float* wsel     = (float*)alloc((size_t)4 * N * 4);
    float* degf     = (float*)alloc((size_t)N * 4);
    unsigned short* WpreT  = (unsigned short*)alloc(128 * 128 * 2);
    unsigned short* WconvT = (unsigned short*)alloc(4 * 128 * 128 * 2);
    int*   ibuf     = (int*)alloc((size_t)(2 * N + 64) * 4);
    int*   deg_i    = ibuf;
    int*   cursor   = ibuf + N;
    int*   counter  = ibuf + 2 * N;
    int*   row_start= (int*)alloc((size_t)N * 4);
    int*   csr_src  = (int*)alloc((size_t)E * 4);

    hipMemsetAsync(ibuf, 0, (size_t)(2 * N + 1) * 4, stream);

    int eb = (E + 255) / 256;
    int nb = (N + 255) / 256;
    k_count<<<eb, 256, 0, stream>>>(ei, E, deg_i);
    k_scan<<<nb, 256, 0, stream>>>(deg_i, N, row_start, degf, counter);
    k_fill<<<eb, 256, 0, stream>>>(ei, E, row_start, cursor, csr_src);

    k_wt<<<(16384 + 255) / 256, 256, 0, stream>>>(W_pre, WpreT, 16384);
    k_wt<<<(4 * 16384 + 255) / 256, 256, 0, stream>>>(W_conv, WconvT, 4 * 16384);

    int gblk = (N + 127) / 128;
    // h0 = relu(x @ W_pre + b_pre), fp32 A converted in-staging
    k_gemm_mfma<true><<<gblk, 256, 0, stream>>>(x, WpreT, b_pre, h_all, N, 1);

    int nb4 = (N + 3) / 4;
    for (int d = 0; d < 4; d++) {
        unsigned short* h_d  = h_all + (size_t)d * hstride;
        unsigned short* h_n  = h_all + (size_t)(d + 1) * hstride;
        k_gemm_mfma<false><<<gblk, 256, 0, stream>>>(h_d, WconvT + (size_t)d * 16384,
                                                     b_conv + (size_t)d * HIDDEN, ht, N, 0);
        k_depth<<<nb4, 256, 0, stream>>>(h_d, ht, h_n, cp, wsel + (size_t)d * N,
                                         degf, deg_i, row_start, csr_src,
                                         W_dep, b_dep, W_aggr, b_aggr,
                                         N, d == 0 ? 1 : 0);
    }
    k_post<<<(N + 31) / 32, 256, 0, stream>>>(h_all, hstride, wsel, N,
                                              W_post, b_post, (float*)d_out);
}

// Round 5
// 735.779 us; speedup vs baseline: 1.8075x; 1.0664x over previous
//
#include <hip/hip_runtime.h>
#include <math.h>

#define HIDDEN 128
#define NCLS 40
#define BMAX 1024   // max buckets (256 nodes/bucket -> supports N <= 262144)

typedef __attribute__((ext_vector_type(8))) short short8;
typedef __attribute__((ext_vector_type(4))) float f32x4;

__device__ __forceinline__ float wave_reduce_sum(float v) {
    #pragma unroll
    for (int off = 32; off > 0; off >>= 1) v += __shfl_xor(v, off);
    return v;
}

__device__ __forceinline__ unsigned short f2bf(float f) {
    unsigned u = __float_as_uint(f);
    unsigned r = u + 0x7FFFu + ((u >> 16) & 1u);   // RNE
    return (unsigned short)(r >> 16);
}
__device__ __forceinline__ float bf_lo(unsigned u) { return __uint_as_float(u << 16); }
__device__ __forceinline__ float bf_hi(unsigned u) { return __uint_as_float(u & 0xFFFF0000u); }

// ---------------- weight transpose: Wt[m][n][k] = W[m][k][n], bf16 ----------------

__global__ void k_wt(const float* __restrict__ W, unsigned short* __restrict__ Wt, int total) {
    int i = blockIdx.x * 256 + threadIdx.x;
    if (i < total) {
        int m = i >> 14;
        int rem = i & 16383;
        int n = rem >> 7, k = rem & 127;
        Wt[i] = f2bf(W[(m << 14) + k * 128 + n]);
    }
}

// ---------------- CSR build (two-level binned counting sort) ----------------
// bucket b = nodes [b*256, b*256+256); bucket's CSR region is contiguous because
// k_scan assigns each 256-node block one atomic base.

__global__ void k_count(const int* __restrict__ ei, int E, int* __restrict__ deg_i) {
    int e = blockIdx.x * 256 + threadIdx.x;
    if (e < E) atomicAdd(&deg_i[ei[E + e]], 1);
}

__global__ void k_scan(const int* __restrict__ deg_i, int N,
                       int* __restrict__ row_start, float* __restrict__ degf,
                       int* __restrict__ counter,
                       int* __restrict__ bucket_base, int* __restrict__ bucket_cursor,
                       int* __restrict__ bucket_cnt) {
    __shared__ int sd[256];
    __shared__ int sbase;
    int tid = threadIdx.x;
    int n = blockIdx.x * 256 + tid;
    int v = (n < N) ? deg_i[n] : 0;
    sd[tid] = v;
    __syncthreads();
    #pragma unroll
    for (int off = 1; off < 256; off <<= 1) {
        int t = (tid >= off) ? sd[tid - off] : 0;
        __syncthreads();
        sd[tid] += t;
        __syncthreads();
    }
    int incl = sd[tid];
    if (tid == 255) {
        int base = atomicAdd(counter, incl);   // block total -> contiguous region
        sbase = base;
        bucket_base[blockIdx.x] = base;
        bucket_cursor[blockIdx.x] = base;
        bucket_cnt[blockIdx.x] = incl;
    }
    __syncthreads();
    if (n < N) {
        row_start[n] = sbase + incl - v;
        degf[n] = fmaxf((float)v, 1.0f);
    }
}

// bin 4096 edges/block into bucket-grouped runs of packed (dstlocal<<24 | src).
// NOTE: packing requires N < 2^24 (N=100000 here).
__launch_bounds__(256)
__global__ void k_bin(const int* __restrict__ ei, int E,
                      int* __restrict__ bucket_cursor, unsigned* __restrict__ binned) {
    __shared__ int hist[BMAX];
    __shared__ int rankc[BMAX];
    __shared__ int lbase[BMAX];
    const int tid = threadIdx.x;
    const int e0 = blockIdx.x * 4096;
    for (int i = tid; i < BMAX; i += 256) { hist[i] = 0; rankc[i] = 0; }
    __syncthreads();
    int bkt[16];
    unsigned pk[16];
    #pragma unroll
    for (int i = 0; i < 16; i++) {
        int e = e0 + i * 256 + tid;
        if (e < E) {
            int s = ei[e];
            int d = ei[E + e];
            bkt[i] = d >> 8;
            pk[i] = ((unsigned)(d & 255) << 24) | (unsigned)s;
            atomicAdd(&hist[bkt[i]], 1);
        } else bkt[i] = -1;
    }
    __syncthreads();
    for (int i = tid; i < BMAX; i += 256)
        if (hist[i] > 0) lbase[i] = atomicAdd(&bucket_cursor[i], hist[i]);
    __syncthreads();
    #pragma unroll
    for (int i = 0; i < 16; i++) {
        if (bkt[i] >= 0) {
            int r = atomicAdd(&rankc[bkt[i]], 1);
            binned[lbase[bkt[i]] + r] = pk[i];
        }
    }
}

// one block per bucket: scatter binned edges into the bucket's private CSR region.
// LDS cursors -> zero global atomics; writes confined to ~16KB region.
__launch_bounds__(256)
__global__ void k_scatter(const unsigned* __restrict__ binned,
                          const int* __restrict__ bucket_base,
                          const int* __restrict__ bucket_cnt,
                          const int* __restrict__ row_start,
                          int* __restrict__ csr_src, int N) {
    __shared__ int rs[256];
    __shared__ int cur[256];
    const int tid = threadIdx.x;
    const int node0 = blockIdx.x << 8;
    int n = node0 + tid;
    rs[tid] = (n < N) ? row_start[n] : 0;
    cur[tid] = 0;
    __syncthreads();
    const int base = bucket_base[blockIdx.x];
    const int cnt = bucket_cnt[blockIdx.x];
    for (int i = tid; i < cnt; i += 256) {
        unsigned p = binned[base + i];
        int src = (int)(p & 0xFFFFFFu);
        int dl = (int)(p >> 24);
        int r = atomicAdd(&cur[dl], 1);
        csr_src[rs[dl] + r] = src;
    }
}

// ---------------- bf16 MFMA GEMM: Cb[M,128] = A[M,128] @ W[128,128] + bias (bf16 out) ----

template <bool AF32>
__launch_bounds__(256)
__global__ void k_gemm_mfma(const void* __restrict__ Ain,
                            const unsigned short* __restrict__ Wt,
                            const float* __restrict__ bias,
                            unsigned short* __restrict__ Cb,
                            int M, int do_relu) {
    __shared__ unsigned short As[128 * 40];
    __shared__ unsigned short Ws[128 * 40];
    const int tid = threadIdx.x;
    const int lane = tid & 63;
    const int wv = tid >> 6;
    const int row_blk = blockIdx.x * 128;
    const int rows0 = (wv >> 1) * 64;
    const int cols0 = (wv & 1) * 64;
    const int l15 = lane & 15;
    const int q = lane >> 4;

    f32x4 acc[4][4] = {};
    for (int k0 = 0; k0 < 128; k0 += 32) {
        #pragma unroll
        for (int i = 0; i < 2; i++) {
            int c = tid + i * 256;
            int r = c >> 2, ch = c & 3;
            uint4 wvv = *(const uint4*)(Wt + (size_t)r * HIDDEN + k0 + ch * 8);
            *(uint4*)&Ws[r * 40 + ch * 8] = wvv;
        }
        if (AF32) {
            const float* A = (const float*)Ain;
            #pragma unroll
            for (int i = 0; i < 4; i++) {
                int c = tid + i * 256;
                int r = c >> 3, ch = c & 7;
                int ar = row_blk + r;
                float4 v = make_float4(0.f, 0.f, 0.f, 0.f);
                if (ar < M) v = *(const float4*)(A + (size_t)ar * HIDDEN + k0 + ch * 4);
                ushort4 o;
                o.x = f2bf(v.x); o.y = f2bf(v.y); o.z = f2bf(v.z); o.w = f2bf(v.w);
                *(ushort4*)&As[r * 40 + ch * 4] = o;
            }
        } else {
            const unsigned short* A = (const unsigned short*)Ain;
            #pragma unroll
            for (int i = 0; i < 2; i++) {
                int c = tid + i * 256;
                int r = c >> 2, ch = c & 3;
                uint4 av = make_uint4(0u, 0u, 0u, 0u);
                int ar = row_blk + r;
                if (ar < M) av = *(const uint4*)(A + (size_t)ar * HIDDEN + k0 + ch * 8);
                *(uint4*)&As[r * 40 + ch * 8] = av;
            }
        }
        __syncthreads();
        short8 af[4], bfr[4];
        #pragma unroll
        for (int mi = 0; mi < 4; mi++)
            af[mi] = *(const short8*)&As[(rows0 + mi * 16 + l15) * 40 + q * 8];
        #pragma unroll
        for (int ni = 0; ni < 4; ni++)
            bfr[ni] = *(const short8*)&Ws[(cols0 + ni * 16 + l15) * 40 + q * 8];
        #pragma unroll
        for (int mi = 0; mi < 4; mi++)
            #pragma unroll
            for (int ni = 0; ni < 4; ni++)
                acc[mi][ni] = __builtin_amdgcn_mfma_f32_16x16x32_bf16(
                    af[mi], bfr[ni], acc[mi][ni], 0, 0, 0);
        __syncthreads();
    }
    #pragma unroll
    for (int ni = 0; ni < 4; ni++) {
        int col = cols0 + ni * 16 + l15;
        float bv = bias[col];
        #pragma unroll
        for (int mi = 0; mi < 4; mi++) {
            #pragma unroll
            for (int r = 0; r < 4; r++) {
                int row = row_blk + rows0 + mi * 16 + q * 4 + r;
                if (row < M) {
                    float o = acc[mi][ni][r] + bv;
                    if (do_relu) o = fmaxf(o, 0.f);
                    Cb[(size_t)row * HIDDEN + col] = f2bf(o);
                }
            }
        }
    }
}

// ---------------- fused depth step ----------------

__launch_bounds__(256)
__global__ void k_depth(const unsigned short* __restrict__ h_in,
                        const unsigned short* __restrict__ ht,
                        unsigned short* __restrict__ h_out,
                        float* __restrict__ cp, float* __restrict__ wsel,
                        const float* __restrict__ degf, const int* __restrict__ deg_i,
                        const int* __restrict__ row_start, const int* __restrict__ csr_src,
                        const float* __restrict__ Wd, const float* __restrict__ bd,
                        const float* __restrict__ Wa, const float* __restrict__ ba,
                        int N, int first) {
    int lane = threadIdx.x & 63;
    int wave = threadIdx.x >> 6;
    int node = blockIdx.x * 4 + wave;
    if (node >= N) return;
    const int lo2 = lane * 2;

    unsigned hu = *(const unsigned*)&h_in[(size_t)node * HIDDEN + lo2];
    float hvx = bf_lo(hu), hvy = bf_hi(hu);
    int k0 = lo2, k1 = lo2 + 1;
    float d0 = hvx * Wd[k0 * 2 + 0] + hvy * Wd[k1 * 2 + 0];
    float d1 = hvx * Wd[k0 * 2 + 1] + hvy * Wd[k1 * 2 + 1];
    float a0 = hvx * Wa[k0 * 3 + 0] + hvy * Wa[k1 * 3 + 0];
    float a1 = hvx * Wa[k0 * 3 + 1] + hvy * Wa[k1 * 3 + 1];
    float a2 = hvx * Wa[k0 * 3 + 2] + hvy * Wa[k1 * 3 + 2];
    d0 = wave_reduce_sum(d0); d1 = wave_reduce_sum(d1);
    a0 = wave_reduce_sum(a0); a1 = wave_reduce_sum(a1); a2 = wave_reduce_sum(a2);
    d0 += bd[0]; d1 += bd[1];
    a0 += ba[0]; a1 += ba[1]; a2 += ba[2];
    float m2 = fmaxf(d0, d1);
    float e0 = expf(d0 - m2), e1 = expf(d1 - m2);
    float inv2 = 1.f / (e0 + e1);
    float sp0 = e0 * inv2, sp1 = e1 * inv2;
    float m3 = fmaxf(fmaxf(a0, a1), a2);
    float f0 = expf(a0 - m3), f1 = expf(a1 - m3), f2 = expf(a2 - m3);
    float inv3 = 1.f / (f0 + f1 + f2);
    float ap0 = f0 * inv3, ap1 = f1 * inv3, ap2 = f2 * inv3;

    int cnt = deg_i[node], start = row_start[node];
    float sx = 0.f, sy = 0.f, mxx = -3.4e38f, mxy = -3.4e38f;
    for (int eb = 0; eb < cnt; eb += 64) {
        int idx = eb + lane;
        int s = (idx < cnt) ? csr_src[start + idx] : 0;
        int lim = min(64, cnt - eb);
        int j = 0;
        for (; j + 4 <= lim; j += 4) {
            int s0 = __shfl(s, j + 0);
            int s1 = __shfl(s, j + 1);
            int s2 = __shfl(s, j + 2);
            int s3 = __shfl(s, j + 3);
            unsigned u0 = *(const unsigned*)&ht[(size_t)s0 * HIDDEN + lo2];
            unsigned u1 = *(const unsigned*)&ht[(size_t)s1 * HIDDEN + lo2];
            unsigned u2 = *(const unsigned*)&ht[(size_t)s2 * HIDDEN + lo2];
            unsigned u3 = *(const unsigned*)&ht[(size_t)s3 * HIDDEN + lo2];
            float x0 = bf_lo(u0), y0 = bf_hi(u0);
            float x1 = bf_lo(u1), y1 = bf_hi(u1);
            float x2 = bf_lo(u2), y2 = bf_hi(u2);
            float x3 = bf_lo(u3), y3 = bf_hi(u3);
            sx += (x0 + x1) + (x2 + x3);
            sy += (y0 + y1) + (y2 + y3);
            mxx = fmaxf(fmaxf(fmaxf(mxx, x0), fmaxf(x1, x2)), x3);
            mxy = fmaxf(fmaxf(fmaxf(mxy, y0), fmaxf(y1, y2)), y3);
        }
        for (; j < lim; j++) {
            int sj = __shfl(s, j);
            unsigned u = *(const unsigned*)&ht[(size_t)sj * HIDDEN + lo2];
            float x = bf_lo(u), y = bf_hi(u);
            sx += x; sy += y;
            mxx = fmaxf(mxx, x); mxy = fmaxf(mxy, y);
        }
    }
    float invd = 1.0f / degf[node];
    float meanx = sx * invd, meany = sy * invd;
    if (cnt == 0) { mxx = 0.f; mxy = 0.f; }
    unsigned su = *(const unsigned*)&ht[(size_t)node * HIDDEN + lo2];
    float hx = ap0 * meanx + ap1 * mxx + ap2 * bf_lo(su);
    float hy = ap0 * meany + ap1 * mxy + ap2 * bf_hi(su);
    hx = fmaxf(hx, 0.f); hy = fmaxf(hy, 0.f);

    ushort2 ho; ho.x = f2bf(hx); ho.y = f2bf(hy);
    *(ushort2*)&h_out[(size_t)node * HIDDEN + lo2] = ho;

    if (lane == 0) {
        float cpv = first ? 1.0f : cp[node];
        wsel[node] = cpv * sp1;
        cp[node] = cpv * sp0;
    }
}

// ---------------- post: sel = sum_d w_d * h_{d+1}; logits; log_softmax ----------------

__launch_bounds__(256)
__global__ void k_post(const unsigned short* __restrict__ h_all, size_t hstride,
                       const float* __restrict__ wsel, int N,
                       const float* __restrict__ Wp, const float* __restrict__ bp,
                       float* __restrict__ out) {
    __shared__ float Ss[32][132];
    __shared__ float Wt[NCLS][132];
    __shared__ float bs[NCLS];
    const int tid = threadIdx.x;
    const int n0 = blockIdx.x * 32;

    for (int i = tid; i < (HIDDEN * NCLS) / 4; i += 256) {
        float4 v = *(const float4*)&Wp[i * 4];
        int f = i * 4;
        int k = f / NCLS, c = f % NCLS;
        float e[4] = {v.x, v.y, v.z, v.w};
        #pragma unroll
        for (int j = 0; j < 4; j++) {
            int cc = c + j, kk = k;
            if (cc >= NCLS) { cc -= NCLS; kk++; }
            Wt[cc][kk] = e[j];
        }
    }
    if (tid < NCLS) bs[tid] = bp[tid];

    const int node_l = tid >> 3;
    const int kc = (tid & 7) * 16;
    const int ng = n0 + node_l;
    float sel[16];
    #pragma unroll
    for (int i = 0; i < 16; i++) sel[i] = 0.f;
    if (ng < N) {
        #pragma unroll
        for (int d = 0; d < 4; d++) {
            float w = wsel[(size_t)d * N + ng];
            const unsigned short* hrow = h_all + (size_t)(d + 1) * hstride + (size_t)ng * HIDDEN;
            #pragma unroll
            for (int u = 0; u < 2; u++) {
                uint4 p = *(const uint4*)(hrow + kc + u * 8);
                unsigned vs[4] = {p.x, p.y, p.z, p.w};
                #pragma unroll
                for (int j = 0; j < 4; j++) {
                    sel[u * 8 + j * 2 + 0] += w * bf_lo(vs[j]);
                    sel[u * 8 + j * 2 + 1] += w * bf_hi(vs[j]);
                }
            }
        }
    }
    #pragma unroll
    for (int u = 0; u < 4; u++)
        *(float4*)&Ss[node_l][kc + u * 4] =
            make_float4(sel[u * 4], sel[u * 4 + 1], sel[u * 4 + 2], sel[u * 4 + 3]);
    __syncthreads();

    const int c0 = (tid & 7) * 5;
    float z[5];
    #pragma unroll
    for (int i = 0; i < 5; i++) z[i] = bs[c0 + i];
    for (int k = 0; k < HIDDEN; k += 4) {
        float4 s4 = *(const float4*)&Ss[node_l][k];
        #pragma unroll
        for (int i = 0; i < 5; i++) {
            float4 w4 = *(const float4*)&Wt[c0 + i][k];
            z[i] += s4.x * w4.x + s4.y * w4.y + s4.z * w4.z + s4.w * w4.w;
        }
    }
    float m = z[0];
    #pragma unroll
    for (int i = 1; i < 5; i++) m = fmaxf(m, z[i]);
    #pragma unroll
    for (int off = 1; off < 8; off <<= 1) m = fmaxf(m, __shfl_xor(m, off));
    float s = 0.f;
    #pragma unroll
    for (int i = 0; i < 5; i++) s += expf(z[i] - m);
    #pragma unroll
    for (int off = 1; off < 8; off <<= 1) s += __shfl_xor(s, off);
    float lg = m + logf(s);
    if (ng < N) {
        #pragma unroll
        for (int i = 0; i < 5; i++)
            out[(size_t)ng * NCLS + c0 + i] = z[i] - lg;
    }
}

// ---------------- launch ----------------

extern "C" void kernel_launch(void* const* d_in, const int* in_sizes, int n_in,
                              void* d_out, int out_size, void* d_ws, size_t ws_size,
                              hipStream_t stream) {
    const float* x      = (const float*)d_in[0];
    const int*   ei     = (const int*)d_in[1];
    const float* W_pre  = (const float*)d_in[2];
    const float* b_pre  = (const float*)d_in[3];
    const float* W_dep  = (const float*)d_in[4];
    const float* b_dep  = (const float*)d_in[5];
    const float* W_aggr = (const float*)d_in[6];
    const float* b_aggr = (const float*)d_in[7];
    const float* W_conv = (const float*)d_in[8];
    const float* b_conv = (const float*)d_in[9];
    const float* W_post = (const float*)d_in[10];
    const float* b_post = (const float*)d_in[11];

    const int N = in_sizes[0] / HIDDEN;
    const int E = in_sizes[1] / 2;
    const int nbuckets = (N + 255) >> 8;

    char* ws = (char*)d_ws;
    size_t off = 0;
    auto alloc = [&](size_t bytes) -> void* {
        void* p = ws + off;
        off += (bytes + 255) & ~(size_t)255;
        return p;
    };
    const size_t hstride = (size_t)N * HIDDEN;
    unsigned short* h_all  = (unsigned short*)alloc(5 * hstride * 2);  // h_0..h_4
    unsigned short* ht     = (unsigned short*)alloc(hstride * 2);
    float* cp       = (float*)alloc((size_t)N * 4);
    float* wsel     = (float*)alloc((size_t)4 * N * 4);
    float* degf     = (float*)alloc((size_t)N * 4);
    unsigned short* WpreT  = (unsigned short*)alloc(128 * 128 * 2);
    unsigned short* WconvT = (unsigned short*)alloc(4 * 128 * 128 * 2);
    int*   ibuf     = (int*)alloc((size_t)(N + 64) * 4);   // deg_i | counter
    int*   deg_i    = ibuf;
    int*   counter  = ibuf + N;
    int*   row_start= (int*)alloc((size_t)N * 4);
    int*   bucket_base   = (int*)alloc(BMAX * 4);
    int*   bucket_cursor = (int*)alloc(BMAX * 4);
    int*   bucket_cnt    = (int*)alloc(BMAX * 4);
    int*   csr_src  = (int*)alloc((size_t)E * 4);
    unsigned* binned = (unsigned*)alloc((size_t)E * 4);

    hipMemsetAsync(ibuf, 0, (size_t)(N + 1) * 4, stream);

    int eb = (E + 255) / 256;
    k_count<<<eb, 256, 0, stream>>>(ei, E, deg_i);
    k_scan<<<nbuckets, 256, 0, stream>>>(deg_i, N, row_start, degf, counter,
                                         bucket_base, bucket_cursor, bucket_cnt);
    k_bin<<<(E + 4095) / 4096, 256, 0, stream>>>(ei, E, bucket_cursor, binned);
    k_scatter<<<nbuckets, 256, 0, stream>>>(binned, bucket_base, bucket_cnt,
                                            row_start, csr_src, N);

    k_wt<<<(16384 + 255) / 256, 256, 0, stream>>>(W_pre, WpreT, 16384);
    k_wt<<<(4 * 16384 + 255) / 256, 256, 0, stream>>>(W_conv, WconvT, 4 * 16384);

    int gblk = (N + 127) / 128;
    k_gemm_mfma<true><<<gblk, 256, 0, stream>>>(x, WpreT, b_pre, h_all, N, 1);

    int nb4 = (N + 3) / 4;
    for (int d = 0; d < 4; d++) {
        unsigned short* h_d  = h_all + (size_t)d * hstride;
        unsigned short* h_n  = h_all + (size_t)(d + 1) * hstride;
        k_gemm_mfma<false><<<gblk, 256, 0, stream>>>(h_d, WconvT + (size_t)d * 16384,
                                                     b_conv + (size_t)d * HIDDEN, ht, N, 0);
        k_depth<<<nb4, 256, 0, stream>>>(h_d, ht, h_n, cp, wsel + (size_t)d * N,
                                         degf, deg_i, row_start, csr_src,
                                         W_dep, b_dep, W_aggr, b_aggr,
                                         N, d == 0 ? 1 : 0);
    }
    k_post<<<(N + 31) / 32, 256, 0, stream>>>(h_all, hstride, wsel, N,
                                              W_post, b_post, (float*)d_out);
}

// Round 6
// 707.897 us; speedup vs baseline: 1.8787x; 1.0394x over previous
//
#include <hip/hip_runtime.h>
#include <math.h>

#define HIDDEN 128
#define NCLS 40
#define BMAX 1024   // max buckets (256 nodes/bucket -> supports N <= 262144)

typedef __attribute__((ext_vector_type(8))) short short8;
typedef __attribute__((ext_vector_type(4))) float f32x4;

__device__ __forceinline__ unsigned short f2bf(float f) {
    unsigned u = __float_as_uint(f);
    unsigned r = u + 0x7FFFu + ((u >> 16) & 1u);   // RNE
    return (unsigned short)(r >> 16);
}
__device__ __forceinline__ float bf_lo(unsigned u) { return __uint_as_float(u << 16); }
__device__ __forceinline__ float bf_hi(unsigned u) { return __uint_as_float(u & 0xFFFF0000u); }

// ---------------- weight prep ----------------
// WpreT[n][k] = W_pre[k][n], bf16 (128x128)
__global__ void k_wt(const float* __restrict__ W, unsigned short* __restrict__ Wt, int total) {
    int i = blockIdx.x * 256 + threadIdx.x;
    if (i < total) {
        int n = (i >> 7) & 127, k = i & 127;
        Wt[i] = f2bf(W[k * 128 + n]);
    }
}

// WT[d][n][k], n in [0,144): 0-127 = W_conv[d][k][n]; 128-129 = W_depth[k][n-128];
// 130-132 = W_aggr[k][n-130]; 133-143 = 0.
__global__ void k_wtc(const float* __restrict__ Wc, const float* __restrict__ Wd,
                      const float* __restrict__ Wa, unsigned short* __restrict__ WT,
                      int total) {
    int i = blockIdx.x * 256 + threadIdx.x;
    if (i < total) {
        int d = i / 18432;
        int rem = i % 18432;
        int n = rem >> 7, k = rem & 127;
        float v = 0.f;
        if (n < 128)      v = Wc[d * 16384 + k * 128 + n];
        else if (n < 130) v = Wd[k * 2 + (n - 128)];
        else if (n < 133) v = Wa[k * 3 + (n - 130)];
        WT[i] = f2bf(v);
    }
}

// ---------------- CSR build (two-level binned counting sort) ----------------

__global__ void k_count(const int* __restrict__ ei, int E, int* __restrict__ deg_i) {
    int e = blockIdx.x * 256 + threadIdx.x;
    if (e < E) atomicAdd(&deg_i[ei[E + e]], 1);
}

__global__ void k_scan(const int* __restrict__ deg_i, int N,
                       int* __restrict__ row_start, float* __restrict__ degf,
                       int* __restrict__ counter,
                       int* __restrict__ bucket_base, int* __restrict__ bucket_cursor,
                       int* __restrict__ bucket_cnt) {
    __shared__ int sd[256];
    __shared__ int sbase;
    int tid = threadIdx.x;
    int n = blockIdx.x * 256 + tid;
    int v = (n < N) ? deg_i[n] : 0;
    sd[tid] = v;
    __syncthreads();
    #pragma unroll
    for (int off = 1; off < 256; off <<= 1) {
        int t = (tid >= off) ? sd[tid - off] : 0;
        __syncthreads();
        sd[tid] += t;
        __syncthreads();
    }
    int incl = sd[tid];
    if (tid == 255) {
        int base = atomicAdd(counter, incl);
        sbase = base;
        bucket_base[blockIdx.x] = base;
        bucket_cursor[blockIdx.x] = base;
        bucket_cnt[blockIdx.x] = incl;
    }
    __syncthreads();
    if (n < N) {
        row_start[n] = sbase + incl - v;
        degf[n] = fmaxf((float)v, 1.0f);
    }
}

__launch_bounds__(256)
__global__ void k_bin(const int* __restrict__ ei, int E,
                      int* __restrict__ bucket_cursor, unsigned* __restrict__ binned) {
    __shared__ int hist[BMAX];
    __shared__ int rankc[BMAX];
    __shared__ int lbase[BMAX];
    const int tid = threadIdx.x;
    const int e0 = blockIdx.x * 4096;
    for (int i = tid; i < BMAX; i += 256) { hist[i] = 0; rankc[i] = 0; }
    __syncthreads();
    int bkt[16];
    unsigned pk[16];
    #pragma unroll
    for (int i = 0; i < 16; i++) {
        int e = e0 + i * 256 + tid;
        if (e < E) {
            int s = ei[e];
            int d = ei[E + e];
            bkt[i] = d >> 8;
            pk[i] = ((unsigned)(d & 255) << 24) | (unsigned)s;
            atomicAdd(&hist[bkt[i]], 1);
        } else bkt[i] = -1;
    }
    __syncthreads();
    for (int i = tid; i < BMAX; i += 256)
        if (hist[i] > 0) lbase[i] = atomicAdd(&bucket_cursor[i], hist[i]);
    __syncthreads();
    #pragma unroll
    for (int i = 0; i < 16; i++) {
        if (bkt[i] >= 0) {
            int r = atomicAdd(&rankc[bkt[i]], 1);
            binned[lbase[bkt[i]] + r] = pk[i];
        }
    }
}

__launch_bounds__(256)
__global__ void k_scatter(const unsigned* __restrict__ binned,
                          const int* __restrict__ bucket_base,
                          const int* __restrict__ bucket_cnt,
                          const int* __restrict__ row_start,
                          int* __restrict__ csr_src, int N) {
    __shared__ int rs[256];
    __shared__ int cur[256];
    const int tid = threadIdx.x;
    const int node0 = blockIdx.x << 8;
    int n = node0 + tid;
    rs[tid] = (n < N) ? row_start[n] : 0;
    cur[tid] = 0;
    __syncthreads();
    const int base = bucket_base[blockIdx.x];
    const int cnt = bucket_cnt[blockIdx.x];
    for (int i = tid; i < cnt; i += 256) {
        unsigned p = binned[base + i];
        int src = (int)(p & 0xFFFFFFu);
        int dl = (int)(p >> 24);
        int r = atomicAdd(&cur[dl], 1);
        csr_src[rs[dl] + r] = src;
    }
}

// ---------------- bf16 MFMA GEMM (+ optional fused controller logits) ----------------
// Cb[M,128] = A[M,128] @ W + bias (bf16 out). CTRL: B extended with rows 128-143
// (W_depth|W_aggr|0); waves with col-half 0 compute 5 controller logits per row
// into ctrl[row*8 + 0..4] (raw dots, bias added downstream).

template <bool AF32, bool CTRL>
__launch_bounds__(256)
__global__ void k_gemm_mfma(const void* __restrict__ Ain,
                            const unsigned short* __restrict__ Wt,
                            const float* __restrict__ bias,
                            unsigned short* __restrict__ Cb,
                            float* __restrict__ ctrl,
                            int M, int do_relu) {
    __shared__ unsigned short As[128 * 40];
    __shared__ unsigned short Ws[144 * 40];
    const int tid = threadIdx.x;
    const int lane = tid & 63;
    const int wv = tid >> 6;
    const int row_blk = blockIdx.x * 128;
    const int rows0 = (wv >> 1) * 64;
    const int cols0 = (wv & 1) * 64;
    const int l15 = lane & 15;
    const int q = lane >> 4;
    const int RWS = CTRL ? 144 : 128;

    f32x4 acc[4][4] = {};
    f32x4 acc5[4] = {};
    for (int k0 = 0; k0 < 128; k0 += 32) {
        for (int c = tid; c < RWS * 4; c += 256) {
            int r = c >> 2, ch = c & 3;
            uint4 wvv = *(const uint4*)(Wt + (size_t)r * HIDDEN + k0 + ch * 8);
            *(uint4*)&Ws[r * 40 + ch * 8] = wvv;
        }
        if (AF32) {
            const float* A = (const float*)Ain;
            #pragma unroll
            for (int i = 0; i < 4; i++) {
                int c = tid + i * 256;
                int r = c >> 3, ch = c & 7;
                int ar = row_blk + r;
                float4 v = make_float4(0.f, 0.f, 0.f, 0.f);
                if (ar < M) v = *(const float4*)(A + (size_t)ar * HIDDEN + k0 + ch * 4);
                ushort4 o;
                o.x = f2bf(v.x); o.y = f2bf(v.y); o.z = f2bf(v.z); o.w = f2bf(v.w);
                *(ushort4*)&As[r * 40 + ch * 4] = o;
            }
        } else {
            const unsigned short* A = (const unsigned short*)Ain;
            #pragma unroll
            for (int i = 0; i < 2; i++) {
                int c = tid + i * 256;
                int r = c >> 2, ch = c & 3;
                uint4 av = make_uint4(0u, 0u, 0u, 0u);
                int ar = row_blk + r;
                if (ar < M) av = *(const uint4*)(A + (size_t)ar * HIDDEN + k0 + ch * 8);
                *(uint4*)&As[r * 40 + ch * 8] = av;
            }
        }
        __syncthreads();
        short8 af[4], bfr[4];
        #pragma unroll
        for (int mi = 0; mi < 4; mi++)
            af[mi] = *(const short8*)&As[(rows0 + mi * 16 + l15) * 40 + q * 8];
        #pragma unroll
        for (int ni = 0; ni < 4; ni++)
            bfr[ni] = *(const short8*)&Ws[(cols0 + ni * 16 + l15) * 40 + q * 8];
        #pragma unroll
        for (int mi = 0; mi < 4; mi++)
            #pragma unroll
            for (int ni = 0; ni < 4; ni++)
                acc[mi][ni] = __builtin_amdgcn_mfma_f32_16x16x32_bf16(
                    af[mi], bfr[ni], acc[mi][ni], 0, 0, 0);
        if (CTRL && (wv & 1) == 0) {
            short8 b4 = *(const short8*)&Ws[(128 + l15) * 40 + q * 8];
            #pragma unroll
            for (int mi = 0; mi < 4; mi++)
                acc5[mi] = __builtin_amdgcn_mfma_f32_16x16x32_bf16(
                    af[mi], b4, acc5[mi], 0, 0, 0);
        }
        __syncthreads();
    }
    #pragma unroll
    for (int ni = 0; ni < 4; ni++) {
        int col = cols0 + ni * 16 + l15;
        float bv = bias[col];
        #pragma unroll
        for (int mi = 0; mi < 4; mi++) {
            #pragma unroll
            for (int r = 0; r < 4; r++) {
                int row = row_blk + rows0 + mi * 16 + q * 4 + r;
                if (row < M) {
                    float o = acc[mi][ni][r] + bv;
                    if (do_relu) o = fmaxf(o, 0.f);
                    Cb[(size_t)row * HIDDEN + col] = f2bf(o);
                }
            }
        }
    }
    if (CTRL && (wv & 1) == 0 && l15 < 5) {
        #pragma unroll
        for (int mi = 0; mi < 4; mi++)
            #pragma unroll
            for (int r = 0; r < 4; r++) {
                int row = row_blk + rows0 + mi * 16 + q * 4 + r;
                if (row < M) ctrl[(size_t)row * 8 + l15] = acc5[mi][r];
            }
    }
}

// ---------------- fused depth step (controllers precomputed) ----------------
// one wave per node; reads ctrl logits (scalarized), gathers ht rows, mixes, relu.

__launch_bounds__(256)
__global__ void k_depth(const unsigned short* __restrict__ ht,
                        unsigned short* __restrict__ h_out,
                        float* __restrict__ cp, float* __restrict__ wsel,
                        const float* __restrict__ ctrl,
                        const float* __restrict__ degf, const int* __restrict__ deg_i,
                        const int* __restrict__ row_start, const int* __restrict__ csr_src,
                        const float* __restrict__ bd, const float* __restrict__ ba,
                        int N, int first) {
    int lane = threadIdx.x & 63;
    int wave = threadIdx.x >> 6;
    int node = blockIdx.x * 4 + wave;
    if (node >= N) return;
    const int nodeu = __builtin_amdgcn_readfirstlane(node);   // wave-uniform -> s_loads
    const int lo2 = lane * 2;

    // controller softmaxes from precomputed logits
    float4 c4 = *(const float4*)(ctrl + (size_t)nodeu * 8);
    float cl4 = ctrl[(size_t)nodeu * 8 + 4];
    float d0 = c4.x + bd[0], d1 = c4.y + bd[1];
    float a0 = c4.z + ba[0], a1 = c4.w + ba[1], a2 = cl4 + ba[2];
    float m2 = fmaxf(d0, d1);
    float e0 = __expf(d0 - m2), e1 = __expf(d1 - m2);
    float inv2 = 1.f / (e0 + e1);
    float sp0 = e0 * inv2, sp1 = e1 * inv2;
    float m3 = fmaxf(fmaxf(a0, a1), a2);
    float f0 = __expf(a0 - m3), f1 = __expf(a1 - m3), f2 = __expf(a2 - m3);
    float inv3 = 1.f / (f0 + f1 + f2);
    float ap0 = f0 * inv3, ap1 = f1 * inv3, ap2 = f2 * inv3;

    int cnt = deg_i[nodeu], start = row_start[nodeu];
    float invd = 1.0f / degf[nodeu];

    float sx = 0.f, sy = 0.f, mxx = -3.4e38f, mxy = -3.4e38f;
    for (int eb = 0; eb < cnt; eb += 64) {
        int idx = eb + lane;
        int s = (idx < cnt) ? csr_src[start + idx] : 0;
        int lim = min(64, cnt - eb);
        int j = 0;
        for (; j + 4 <= lim; j += 4) {
            int s0 = __shfl(s, j + 0);
            int s1 = __shfl(s, j + 1);
            int s2 = __shfl(s, j + 2);
            int s3 = __shfl(s, j + 3);
            unsigned u0 = *(const unsigned*)(ht + (unsigned)((s0 << 7) + lo2));
            unsigned u1 = *(const unsigned*)(ht + (unsigned)((s1 << 7) + lo2));
            unsigned u2 = *(const unsigned*)(ht + (unsigned)((s2 << 7) + lo2));
            unsigned u3 = *(const unsigned*)(ht + (unsigned)((s3 << 7) + lo2));
            float x0 = bf_lo(u0), y0 = bf_hi(u0);
            float x1 = bf_lo(u1), y1 = bf_hi(u1);
            float x2 = bf_lo(u2), y2 = bf_hi(u2);
            float x3 = bf_lo(u3), y3 = bf_hi(u3);
            sx += (x0 + x1) + (x2 + x3);
            sy += (y0 + y1) + (y2 + y3);
            mxx = fmaxf(fmaxf(fmaxf(mxx, x0), fmaxf(x1, x2)), x3);
            mxy = fmaxf(fmaxf(fmaxf(mxy, y0), fmaxf(y1, y2)), y3);
        }
        for (; j < lim; j++) {
            int sj = __shfl(s, j);
            unsigned u = *(const unsigned*)(ht + (unsigned)((sj << 7) + lo2));
            float x = bf_lo(u), y = bf_hi(u);
            sx += x; sy += y;
            mxx = fmaxf(mxx, x); mxy = fmaxf(mxy, y);
        }
    }
    float meanx = sx * invd, meany = sy * invd;
    if (cnt == 0) { mxx = 0.f; mxy = 0.f; }
    unsigned su = *(const unsigned*)(ht + (unsigned)((nodeu << 7) + lo2));
    float hx = ap0 * meanx + ap1 * mxx + ap2 * bf_lo(su);
    float hy = ap0 * meany + ap1 * mxy + ap2 * bf_hi(su);
    hx = fmaxf(hx, 0.f); hy = fmaxf(hy, 0.f);

    ushort2 ho; ho.x = f2bf(hx); ho.y = f2bf(hy);
    *(ushort2*)(h_out + (unsigned)((nodeu << 7) + lo2)) = ho;

    if (lane == 0) {
        float cpv = first ? 1.0f : cp[nodeu];
        wsel[nodeu] = cpv * sp1;
        cp[nodeu] = cpv * sp0;
    }
}

// ---------------- post: sel = sum_d w_d * h_{d+1}; logits; log_softmax ----------------

__launch_bounds__(256)
__global__ void k_post(const unsigned short* __restrict__ h_all, size_t hstride,
                       const float* __restrict__ wsel, int N,
                       const float* __restrict__ Wp, const float* __restrict__ bp,
                       float* __restrict__ out) {
    __shared__ float Ss[32][132];
    __shared__ float Wt[NCLS][132];
    __shared__ float bs[NCLS];
    const int tid = threadIdx.x;
    const int n0 = blockIdx.x * 32;

    for (int i = tid; i < (HIDDEN * NCLS) / 4; i += 256) {
        float4 v = *(const float4*)&Wp[i * 4];
        int f = i * 4;
        int k = f / NCLS, c = f % NCLS;
        float e[4] = {v.x, v.y, v.z, v.w};
        #pragma unroll
        for (int j = 0; j < 4; j++) {
            int cc = c + j, kk = k;
            if (cc >= NCLS) { cc -= NCLS; kk++; }
            Wt[cc][kk] = e[j];
        }
    }
    if (tid < NCLS) bs[tid] = bp[tid];

    const int node_l = tid >> 3;
    const int kc = (tid & 7) * 16;
    const int ng = n0 + node_l;
    float sel[16];
    #pragma unroll
    for (int i = 0; i < 16; i++) sel[i] = 0.f;
    if (ng < N) {
        #pragma unroll
        for (int d = 0; d < 4; d++) {
            float w = wsel[(size_t)d * N + ng];
            const unsigned short* hrow = h_all + (size_t)(d + 1) * hstride + (size_t)ng * HIDDEN;
            #pragma unroll
            for (int u = 0; u < 2; u++) {
                uint4 p = *(const uint4*)(hrow + kc + u * 8);
                unsigned vs[4] = {p.x, p.y, p.z, p.w};
                #pragma unroll
                for (int j = 0; j < 4; j++) {
                    sel[u * 8 + j * 2 + 0] += w * bf_lo(vs[j]);
                    sel[u * 8 + j * 2 + 1] += w * bf_hi(vs[j]);
                }
            }
        }
    }
    #pragma unroll
    for (int u = 0; u < 4; u++)
        *(float4*)&Ss[node_l][kc + u * 4] =
            make_float4(sel[u * 4], sel[u * 4 + 1], sel[u * 4 + 2], sel[u * 4 + 3]);
    __syncthreads();

    const int c0 = (tid & 7) * 5;
    float z[5];
    #pragma unroll
    for (int i = 0; i < 5; i++) z[i] = bs[c0 + i];
    for (int k = 0; k < HIDDEN; k += 4) {
        float4 s4 = *(const float4*)&Ss[node_l][k];
        #pragma unroll
        for (int i = 0; i < 5; i++) {
            float4 w4 = *(const float4*)&Wt[c0 + i][k];
            z[i] += s4.x * w4.x + s4.y * w4.y + s4.z * w4.z + s4.w * w4.w;
        }
    }
    float m = z[0];
    #pragma unroll
    for (int i = 1; i < 5; i++) m = fmaxf(m, z[i]);
    #pragma unroll
    for (int off = 1; off < 8; off <<= 1) m = fmaxf(m, __shfl_xor(m, off));
    float s = 0.f;
    #pragma unroll
    for (int i = 0; i < 5; i++) s += expf(z[i] - m);
    #pragma unroll
    for (int off = 1; off < 8; off <<= 1) s += __shfl_xor(s, off);
    float lg = m + logf(s);
    if (ng < N) {
        #pragma unroll
        for (int i = 0; i < 5; i++)
            out[(size_t)ng * NCLS + c0 + i] = z[i] - lg;
    }
}

// ---------------- launch ----------------

extern "C" void kernel_launch(void* const* d_in, const int* in_sizes, int n_in,
                              void* d_out, int out_size, void* d_ws, size_t ws_size,
                              hipStream_t stream) {
    const float* x      = (const float*)d_in[0];
    const int*   ei     = (const int*)d_in[1];
    const float* W_pre  = (const float*)d_in[2];
    const float* b_pre  = (const float*)d_in[3];
    const float* W_dep  = (const float*)d_in[4];
    const float* b_dep  = (const float*)d_in[5];
    const float* W_aggr = (const float*)d_in[6];
    const float* b_aggr = (const float*)d_in[7];
    const float* W_conv = (const float*)d_in[8];
    const float* b_conv = (const float*)d_in[9];
    const float* W_post = (const float*)d_in[10];
    const float* b_post = (const float*)d_in[11];

    const int N = in_sizes[0] / HIDDEN;
    const int E = in_sizes[1] / 2;
    const int nbuckets = (N + 255) >> 8;

    char* ws = (char*)d_ws;
    size_t off = 0;
    auto alloc = [&](size_t bytes) -> void* {
        void* p = ws + off;
        off += (bytes + 255) & ~(size_t)255;
        return p;
    };
    const size_t hstride = (size_t)N * HIDDEN;
    unsigned short* h_all  = (unsigned short*)alloc(5 * hstride * 2);  // h_0..h_4
    unsigned short* ht     = (unsigned short*)alloc(hstride * 2);
    float* cp       = (float*)alloc((size_t)N * 4);
    float* wsel     = (float*)alloc((size_t)4 * N * 4);
    float* degf     = (float*)alloc((size_t)N * 4);
    float* ctrl     = (float*)alloc((size_t)N * 8 * 4);
    unsigned short* WpreT = (unsigned short*)alloc(128 * 128 * 2);
    unsigned short* WT    = (unsigned short*)alloc(4 * 144 * 128 * 2);
    int*   ibuf     = (int*)alloc((size_t)(N + 64) * 4);   // deg_i | counter
    int*   deg_i    = ibuf;
    int*   counter  = ibuf + N;
    int*   row_start= (int*)alloc((size_t)N * 4);
    int*   bucket_base   = (int*)alloc(BMAX * 4);
    int*   bucket_cursor = (int*)alloc(BMAX * 4);
    int*   bucket_cnt    = (int*)alloc(BMAX * 4);
    int*   csr_src  = (int*)alloc((size_t)E * 4);
    unsigned* binned = (unsigned*)alloc((size_t)E * 4);

    hipMemsetAsync(ibuf, 0, (size_t)(N + 1) * 4, stream);

    int eb = (E + 255) / 256;
    k_count<<<eb, 256, 0, stream>>>(ei, E, deg_i);
    k_scan<<<nbuckets, 256, 0, stream>>>(deg_i, N, row_start, degf, counter,
                                         bucket_base, bucket_cursor, bucket_cnt);
    k_bin<<<(E + 4095) / 4096, 256, 0, stream>>>(ei, E, bucket_cursor, binned);
    k_scatter<<<nbuckets, 256, 0, stream>>>(binned, bucket_base, bucket_cnt,
                                            row_start, csr_src, N);

    k_wt<<<(16384 + 255) / 256, 256, 0, stream>>>(W_pre, WpreT, 16384);
    k_wtc<<<(4 * 18432 + 255) / 256, 256, 0, stream>>>(W_conv, W_dep, W_aggr, WT, 4 * 18432);

    int gblk = (N + 127) / 128;
    k_gemm_mfma<true, false><<<gblk, 256, 0, stream>>>(x, WpreT, b_pre, h_all,
                                                       nullptr, N, 1);

    int nb4 = (N + 3) / 4;
    for (int d = 0; d < 4; d++) {
        unsigned short* h_d  = h_all + (size_t)d * hstride;
        unsigned short* h_n  = h_all + (size_t)(d + 1) * hstride;
        k_gemm_mfma<false, true><<<gblk, 256, 0, stream>>>(h_d, WT + (size_t)d * 18432,
                                                           b_conv + (size_t)d * HIDDEN,
                                                           ht, ctrl, N, 0);
        k_depth<<<nb4, 256, 0, stream>>>(ht, h_n, cp, wsel + (size_t)d * N, ctrl,
                                         degf, deg_i, row_start, csr_src,
                                         b_dep, b_aggr, N, d == 0 ? 1 : 0);
    }
    k_post<<<(N + 31) / 32, 256, 0, stream>>>(h_all, hstride, wsel, N,
                                              W_post, b_post, (float*)d_out);
}

// Round 7
// 653.306 us; speedup vs baseline: 2.0357x; 1.0836x over previous
//
#include <hip/hip_runtime.h>
#include <math.h>

#define HIDDEN 128
#define NCLS 40
#define BMAX 1024   // max buckets (256 nodes/bucket -> supports N <= 262144)

typedef __attribute__((ext_vector_type(8))) short short8;
typedef __attribute__((ext_vector_type(4))) float f32x4;

__device__ __forceinline__ unsigned short f2bf(float f) {
    unsigned u = __float_as_uint(f);
    unsigned r = u + 0x7FFFu + ((u >> 16) & 1u);   // RNE
    return (unsigned short)(r >> 16);
}
__device__ __forceinline__ float bf_lo(unsigned u) { return __uint_as_float(u << 16); }
__device__ __forceinline__ float bf_hi(unsigned u) { return __uint_as_float(u & 0xFFFF0000u); }

// ---------------- weight prep ----------------
__global__ void k_wt(const float* __restrict__ W, unsigned short* __restrict__ Wt, int total) {
    int i = blockIdx.x * 256 + threadIdx.x;
    if (i < total) {
        int n = (i >> 7) & 127, k = i & 127;
        Wt[i] = f2bf(W[k * 128 + n]);
    }
}

// WT[d][n][k], n in [0,144): 0-127 = W_conv[d][k][n]; 128-129 = W_depth; 130-132 = W_aggr.
__global__ void k_wtc(const float* __restrict__ Wc, const float* __restrict__ Wd,
                      const float* __restrict__ Wa, unsigned short* __restrict__ WT,
                      int total) {
    int i = blockIdx.x * 256 + threadIdx.x;
    if (i < total) {
        int d = i / 18432;
        int rem = i % 18432;
        int n = rem >> 7, k = rem & 127;
        float v = 0.f;
        if (n < 128)      v = Wc[d * 16384 + k * 128 + n];
        else if (n < 130) v = Wd[k * 2 + (n - 128)];
        else if (n < 133) v = Wa[k * 3 + (n - 130)];
        WT[i] = f2bf(v);
    }
}

// ---------------- CSR build (histogram-free: bucket counts -> bin -> scatter) ----------

// per-block LDS histogram over buckets; one global atomic per nonzero (block,bucket)
__launch_bounds__(256)
__global__ void k_bcount(const int* __restrict__ ei, int E, int* __restrict__ bucket_cnt) {
    __shared__ int hist[BMAX];
    const int tid = threadIdx.x;
    for (int i = tid; i < BMAX; i += 256) hist[i] = 0;
    __syncthreads();
    const int e0 = blockIdx.x * 4096;
    #pragma unroll
    for (int i = 0; i < 16; i++) {
        int e = e0 + i * 256 + tid;
        if (e < E) atomicAdd(&hist[ei[E + e] >> 8], 1);
    }
    __syncthreads();
    for (int i = tid; i < BMAX; i += 256) {
        int v = hist[i];
        if (v > 0) atomicAdd(&bucket_cnt[i], v);
    }
}

// single block: exclusive scan of bucket counts -> base/cursor
__global__ void k_bscan(const int* __restrict__ bucket_cnt, int nb,
                        int* __restrict__ bucket_base, int* __restrict__ bucket_cursor) {
    __shared__ int sd[256];
    const int tid = threadIdx.x;
    int v[4];
    int sum = 0;
    #pragma unroll
    for (int j = 0; j < 4; j++) {
        int b = tid * 4 + j;
        v[j] = (b < nb) ? bucket_cnt[b] : 0;
        sum += v[j];
    }
    sd[tid] = sum;
    __syncthreads();
    #pragma unroll
    for (int off = 1; off < 256; off <<= 1) {
        int t = (tid >= off) ? sd[tid - off] : 0;
        __syncthreads();
        sd[tid] += t;
        __syncthreads();
    }
    int base = sd[tid] - sum;   // exclusive
    #pragma unroll
    for (int j = 0; j < 4; j++) {
        int b = tid * 4 + j;
        if (b < nb) {
            bucket_base[b] = base;
            bucket_cursor[b] = base;
            base += v[j];
        }
    }
}

// bin edges into bucket-grouped runs of packed (dstlocal<<24 | src). Needs N < 2^24.
__launch_bounds__(256)
__global__ void k_bin(const int* __restrict__ ei, int E,
                      int* __restrict__ bucket_cursor, unsigned* __restrict__ binned) {
    __shared__ int hist[BMAX];
    __shared__ int rankc[BMAX];
    __shared__ int lbase[BMAX];
    const int tid = threadIdx.x;
    const int e0 = blockIdx.x * 4096;
    for (int i = tid; i < BMAX; i += 256) { hist[i] = 0; rankc[i] = 0; }
    __syncthreads();
    int bkt[16];
    unsigned pk[16];
    #pragma unroll
    for (int i = 0; i < 16; i++) {
        int e = e0 + i * 256 + tid;
        if (e < E) {
            int s = ei[e];
            int d = ei[E + e];
            bkt[i] = d >> 8;
            pk[i] = ((unsigned)(d & 255) << 24) | (unsigned)s;
            atomicAdd(&hist[bkt[i]], 1);
        } else bkt[i] = -1;
    }
    __syncthreads();
    for (int i = tid; i < BMAX; i += 256)
        if (hist[i] > 0) lbase[i] = atomicAdd(&bucket_cursor[i], hist[i]);
    __syncthreads();
    #pragma unroll
    for (int i = 0; i < 16; i++) {
        if (bkt[i] >= 0) {
            int r = atomicAdd(&rankc[bkt[i]], 1);
            binned[lbase[bkt[i]] + r] = pk[i];
        }
    }
}

// one block per bucket: derive per-node degree from binned edges (LDS hist + scan),
// write row_start/deg_i/degf coalesced, scatter csr_src with LDS cursors.
__launch_bounds__(256)
__global__ void k_scatter(const unsigned* __restrict__ binned,
                          const int* __restrict__ bucket_base,
                          const int* __restrict__ bucket_cnt,
                          int* __restrict__ row_start, int* __restrict__ deg_i,
                          float* __restrict__ degf,
                          int* __restrict__ csr_src, int N) {
    __shared__ int hist[256];
    __shared__ int rs[256];
    __shared__ int cur[256];
    const int tid = threadIdx.x;
    hist[tid] = 0;
    __syncthreads();
    const int base = bucket_base[blockIdx.x];
    const int cnt = bucket_cnt[blockIdx.x];
    for (int i = tid; i < cnt; i += 256)
        atomicAdd(&hist[binned[base + i] >> 24], 1);
    __syncthreads();
    int v = hist[tid];
    rs[tid] = v;
    __syncthreads();
    #pragma unroll
    for (int off = 1; off < 256; off <<= 1) {
        int t = (tid >= off) ? rs[tid - off] : 0;
        __syncthreads();
        rs[tid] += t;
        __syncthreads();
    }
    int gstart = base + rs[tid] - v;   // exclusive scan + bucket base
    int n = (blockIdx.x << 8) + tid;
    if (n < N) {
        row_start[n] = gstart;
        deg_i[n] = v;
        degf[n] = fmaxf((float)v, 1.0f);
    }
    __syncthreads();
    rs[tid] = gstart;
    cur[tid] = 0;
    __syncthreads();
    for (int i = tid; i < cnt; i += 256) {
        unsigned p = binned[base + i];
        int dl = (int)(p >> 24);
        int r = atomicAdd(&cur[dl], 1);
        csr_src[rs[dl] + r] = (int)(p & 0xFFFFFFu);
    }
}

// ---------------- bf16 MFMA GEMM (+ optional fused controller logits) ----------------

template <bool AF32, bool CTRL>
__launch_bounds__(256)
__global__ void k_gemm_mfma(const void* __restrict__ Ain,
                            const unsigned short* __restrict__ Wt,
                            const float* __restrict__ bias,
                            unsigned short* __restrict__ Cb,
                            float* __restrict__ ctrl,
                            int M, int do_relu) {
    __shared__ unsigned short As[128 * 40];
    __shared__ unsigned short Ws[144 * 40];
    const int tid = threadIdx.x;
    const int lane = tid & 63;
    const int wv = tid >> 6;
    const int row_blk = blockIdx.x * 128;
    const int rows0 = (wv >> 1) * 64;
    const int cols0 = (wv & 1) * 64;
    const int l15 = lane & 15;
    const int q = lane >> 4;
    const int RWS = CTRL ? 144 : 128;

    f32x4 acc[4][4] = {};
    f32x4 acc5[4] = {};
    for (int k0 = 0; k0 < 128; k0 += 32) {
        for (int c = tid; c < RWS * 4; c += 256) {
            int r = c >> 2, ch = c & 3;
            uint4 wvv = *(const uint4*)(Wt + (size_t)r * HIDDEN + k0 + ch * 8);
            *(uint4*)&Ws[r * 40 + ch * 8] = wvv;
        }
        if (AF32) {
            const float* A = (const float*)Ain;
            #pragma unroll
            for (int i = 0; i < 4; i++) {
                int c = tid + i * 256;
                int r = c >> 3, ch = c & 7;
                int ar = row_blk + r;
                float4 v = make_float4(0.f, 0.f, 0.f, 0.f);
                if (ar < M) v = *(const float4*)(A + (size_t)ar * HIDDEN + k0 + ch * 4);
                ushort4 o;
                o.x = f2bf(v.x); o.y = f2bf(v.y); o.z = f2bf(v.z); o.w = f2bf(v.w);
                *(ushort4*)&As[r * 40 + ch * 4] = o;
            }
        } else {
            const unsigned short* A = (const unsigned short*)Ain;
            #pragma unroll
            for (int i = 0; i < 2; i++) {
                int c = tid + i * 256;
                int r = c >> 2, ch = c & 3;
                uint4 av = make_uint4(0u, 0u, 0u, 0u);
                int ar = row_blk + r;
                if (ar < M) av = *(const uint4*)(A + (size_t)ar * HIDDEN + k0 + ch * 8);
                *(uint4*)&As[r * 40 + ch * 8] = av;
            }
        }
        __syncthreads();
        short8 af[4], bfr[4];
        #pragma unroll
        for (int mi = 0; mi < 4; mi++)
            af[mi] = *(const short8*)&As[(rows0 + mi * 16 + l15) * 40 + q * 8];
        #pragma unroll
        for (int ni = 0; ni < 4; ni++)
            bfr[ni] = *(const short8*)&Ws[(cols0 + ni * 16 + l15) * 40 + q * 8];
        #pragma unroll
        for (int mi = 0; mi < 4; mi++)
            #pragma unroll
            for (int ni = 0; ni < 4; ni++)
                acc[mi][ni] = __builtin_amdgcn_mfma_f32_16x16x32_bf16(
                    af[mi], bfr[ni], acc[mi][ni], 0, 0, 0);
        if (CTRL && (wv & 1) == 0) {
            short8 b4 = *(const short8*)&Ws[(128 + l15) * 40 + q * 8];
            #pragma unroll
            for (int mi = 0; mi < 4; mi++)
                acc5[mi] = __builtin_amdgcn_mfma_f32_16x16x32_bf16(
                    af[mi], b4, acc5[mi], 0, 0, 0);
        }
        __syncthreads();
    }
    #pragma unroll
    for (int ni = 0; ni < 4; ni++) {
        int col = cols0 + ni * 16 + l15;
        float bv = bias[col];
        #pragma unroll
        for (int mi = 0; mi < 4; mi++) {
            #pragma unroll
            for (int r = 0; r < 4; r++) {
                int row = row_blk + rows0 + mi * 16 + q * 4 + r;
                if (row < M) {
                    float o = acc[mi][ni][r] + bv;
                    if (do_relu) o = fmaxf(o, 0.f);
                    Cb[(size_t)row * HIDDEN + col] = f2bf(o);
                }
            }
        }
    }
    if (CTRL && (wv & 1) == 0 && l15 < 5) {
        #pragma unroll
        for (int mi = 0; mi < 4; mi++)
            #pragma unroll
            for (int r = 0; r < 4; r++) {
                int row = row_blk + rows0 + mi * 16 + q * 4 + r;
                if (row < M) ctrl[(size_t)row * 8 + l15] = acc5[mi][r];
            }
    }
}

// ---------------- fused depth step (controllers precomputed) ----------------

__launch_bounds__(256)
__global__ void k_depth(const unsigned short* __restrict__ ht,
                        unsigned short* __restrict__ h_out,
                        float* __restrict__ cp, float* __restrict__ wsel,
                        const float* __restrict__ ctrl,
                        const float* __restrict__ degf, const int* __restrict__ deg_i,
                        const int* __restrict__ row_start, const int* __restrict__ csr_src,
                        const float* __restrict__ bd, const float* __restrict__ ba,
                        int N, int first) {
    int lane = threadIdx.x & 63;
    int wave = threadIdx.x >> 6;
    int node = blockIdx.x * 4 + wave;
    if (node >= N) return;
    const int nodeu = __builtin_amdgcn_readfirstlane(node);
    const int lo2 = lane * 2;

    float4 c4 = *(const float4*)(ctrl + (size_t)nodeu * 8);
    float cl4 = ctrl[(size_t)nodeu * 8 + 4];
    float d0 = c4.x + bd[0], d1 = c4.y + bd[1];
    float a0 = c4.z + ba[0], a1 = c4.w + ba[1], a2 = cl4 + ba[2];
    float m2 = fmaxf(d0, d1);
    float e0 = __expf(d0 - m2), e1 = __expf(d1 - m2);
    float inv2 = 1.f / (e0 + e1);
    float sp0 = e0 * inv2, sp1 = e1 * inv2;
    float m3 = fmaxf(fmaxf(a0, a1), a2);
    float f0 = __expf(a0 - m3), f1 = __expf(a1 - m3), f2 = __expf(a2 - m3);
    float inv3 = 1.f / (f0 + f1 + f2);
    float ap0 = f0 * inv3, ap1 = f1 * inv3, ap2 = f2 * inv3;

    int cnt = deg_i[nodeu], start = row_start[nodeu];
    float invd = 1.0f / degf[nodeu];

    float sx = 0.f, sy = 0.f, mxx = -3.4e38f, mxy = -3.4e38f;
    for (int eb = 0; eb < cnt; eb += 64) {
        int idx = eb + lane;
        int s = (idx < cnt) ? csr_src[start + idx] : 0;
        int lim = min(64, cnt - eb);
        int j = 0;
        for (; j + 4 <= lim; j += 4) {
            int s0 = __shfl(s, j + 0);
            int s1 = __shfl(s, j + 1);
            int s2 = __shfl(s, j + 2);
            int s3 = __shfl(s, j + 3);
            unsigned u0 = *(const unsigned*)(ht + (unsigned)((s0 << 7) + lo2));
            unsigned u1 = *(const unsigned*)(ht + (unsigned)((s1 << 7) + lo2));
            unsigned u2 = *(const unsigned*)(ht + (unsigned)((s2 << 7) + lo2));
            unsigned u3 = *(const unsigned*)(ht + (unsigned)((s3 << 7) + lo2));
            float x0 = bf_lo(u0), y0 = bf_hi(u0);
            float x1 = bf_lo(u1), y1 = bf_hi(u1);
            float x2 = bf_lo(u2), y2 = bf_hi(u2);
            float x3 = bf_lo(u3), y3 = bf_hi(u3);
            sx += (x0 + x1) + (x2 + x3);
            sy += (y0 + y1) + (y2 + y3);
            mxx = fmaxf(fmaxf(fmaxf(mxx, x0), fmaxf(x1, x2)), x3);
            mxy = fmaxf(fmaxf(fmaxf(mxy, y0), fmaxf(y1, y2)), y3);
        }
        for (; j < lim; j++) {
            int sj = __shfl(s, j);
            unsigned u = *(const unsigned*)(ht + (unsigned)((sj << 7) + lo2));
            float x = bf_lo(u), y = bf_hi(u);
            sx += x; sy += y;
            mxx = fmaxf(mxx, x); mxy = fmaxf(mxy, y);
        }
    }
    float meanx = sx * invd, meany = sy * invd;
    if (cnt == 0) { mxx = 0.f; mxy = 0.f; }
    unsigned su = *(const unsigned*)(ht + (unsigned)((nodeu << 7) + lo2));
    float hx = ap0 * meanx + ap1 * mxx + ap2 * bf_lo(su);
    float hy = ap0 * meany + ap1 * mxy + ap2 * bf_hi(su);
    hx = fmaxf(hx, 0.f); hy = fmaxf(hy, 0.f);

    ushort2 ho; ho.x = f2bf(hx); ho.y = f2bf(hy);
    *(ushort2*)(h_out + (unsigned)((nodeu << 7) + lo2)) = ho;

    if (lane == 0) {
        float cpv = first ? 1.0f : cp[nodeu];
        wsel[nodeu] = cpv * sp1;
        cp[nodeu] = cpv * sp0;
    }
}

// ---------------- post: sel = sum_d w_d * h_{d+1}; logits; log_softmax ----------------

__launch_bounds__(256)
__global__ void k_post(const unsigned short* __restrict__ h_all, size_t hstride,
                       const float* __restrict__ wsel, int N,
                       const float* __restrict__ Wp, const float* __restrict__ bp,
                       float* __restrict__ out) {
    __shared__ float Ss[32][132];
    __shared__ float Wt[NCLS][132];
    __shared__ float bs[NCLS];
    const int tid = threadIdx.x;
    const int n0 = blockIdx.x * 32;

    for (int i = tid; i < (HIDDEN * NCLS) / 4; i += 256) {
        float4 v = *(const float4*)&Wp[i * 4];
        int f = i * 4;
        int k = f / NCLS, c = f % NCLS;
        float e[4] = {v.x, v.y, v.z, v.w};
        #pragma unroll
        for (int j = 0; j < 4; j++) {
            int cc = c + j, kk = k;
            if (cc >= NCLS) { cc -= NCLS; kk++; }
            Wt[cc][kk] = e[j];
        }
    }
    if (tid < NCLS) bs[tid] = bp[tid];

    const int node_l = tid >> 3;
    const int kc = (tid & 7) * 16;
    const int ng = n0 + node_l;
    float sel[16];
    #pragma unroll
    for (int i = 0; i < 16; i++) sel[i] = 0.f;
    if (ng < N) {
        #pragma unroll
        for (int d = 0; d < 4; d++) {
            float w = wsel[(size_t)d * N + ng];
            const unsigned short* hrow = h_all + (size_t)(d + 1) * hstride + (size_t)ng * HIDDEN;
            #pragma unroll
            for (int u = 0; u < 2; u++) {
                uint4 p = *(const uint4*)(hrow + kc + u * 8);
                unsigned vs[4] = {p.x, p.y, p.z, p.w};
                #pragma unroll
                for (int j = 0; j < 4; j++) {
                    sel[u * 8 + j * 2 + 0] += w * bf_lo(vs[j]);
                    sel[u * 8 + j * 2 + 1] += w * bf_hi(vs[j]);
                }
            }
        }
    }
    #pragma unroll
    for (int u = 0; u < 4; u++)
        *(float4*)&Ss[node_l][kc + u * 4] =
            make_float4(sel[u * 4], sel[u * 4 + 1], sel[u * 4 + 2], sel[u * 4 + 3]);
    __syncthreads();

    const int c0 = (tid & 7) * 5;
    float z[5];
    #pragma unroll
    for (int i = 0; i < 5; i++) z[i] = bs[c0 + i];
    for (int k = 0; k < HIDDEN; k += 4) {
        float4 s4 = *(const float4*)&Ss[node_l][k];
        #pragma unroll
        for (int i = 0; i < 5; i++) {
            float4 w4 = *(const float4*)&Wt[c0 + i][k];
            z[i] += s4.x * w4.x + s4.y * w4.y + s4.z * w4.z + s4.w * w4.w;
        }
    }
    float m = z[0];
    #pragma unroll
    for (int i = 1; i < 5; i++) m = fmaxf(m, z[i]);
    #pragma unroll
    for (int off = 1; off < 8; off <<= 1) m = fmaxf(m, __shfl_xor(m, off));
    float s = 0.f;
    #pragma unroll
    for (int i = 0; i < 5; i++) s += expf(z[i] - m);
    #pragma unroll
    for (int off = 1; off < 8; off <<= 1) s += __shfl_xor(s, off);
    float lg = m + logf(s);
    if (ng < N) {
        #pragma unroll
        for (int i = 0; i < 5; i++)
            out[(size_t)ng * NCLS + c0 + i] = z[i] - lg;
    }
}

// ---------------- launch ----------------

extern "C" void kernel_launch(void* const* d_in, const int* in_sizes, int n_in,
                              void* d_out, int out_size, void* d_ws, size_t ws_size,
                              hipStream_t stream) {
    const float* x      = (const float*)d_in[0];
    const int*   ei     = (const int*)d_in[1];
    const float* W_pre  = (const float*)d_in[2];
    const float* b_pre  = (const float*)d_in[3];
    const float* W_dep  = (const float*)d_in[4];
    const float* b_dep  = (const float*)d_in[5];
    const float* W_aggr = (const float*)d_in[6];
    const float* b_aggr = (const float*)d_in[7];
    const float* W_conv = (const float*)d_in[8];
    const float* b_conv = (const float*)d_in[9];
    const float* W_post = (const float*)d_in[10];
    const float* b_post = (const float*)d_in[11];

    const int N = in_sizes[0] / HIDDEN;
    const int E = in_sizes[1] / 2;
    const int nbuckets = (N + 255) >> 8;

    char* ws = (char*)d_ws;
    size_t off = 0;
    auto alloc = [&](size_t bytes) -> void* {
        void* p = ws + off;
        off += (bytes + 255) & ~(size_t)255;
        return p;
    };
    const size_t hstride = (size_t)N * HIDDEN;
    unsigned short* h_all  = (unsigned short*)alloc(5 * hstride * 2);  // h_0..h_4
    unsigned short* ht     = (unsigned short*)alloc(hstride * 2);
    float* cp       = (float*)alloc((size_t)N * 4);
    float* wsel     = (float*)alloc((size_t)4 * N * 4);
    float* degf     = (float*)alloc((size_t)N * 4);
    float* ctrl     = (float*)alloc((size_t)N * 8 * 4);
    unsigned short* WpreT = (unsigned short*)alloc(128 * 128 * 2);
    unsigned short* WT    = (unsigned short*)alloc(4 * 144 * 128 * 2);
    int*   deg_i    = (int*)alloc((size_t)N * 4);
    int*   row_start= (int*)alloc((size_t)N * 4);
    int*   bucket_cnt    = (int*)alloc(BMAX * 4);
    int*   bucket_base   = (int*)alloc(BMAX * 4);
    int*   bucket_cursor = (int*)alloc(BMAX * 4);
    int*   csr_src  = (int*)alloc((size_t)E * 4);
    unsigned* binned = (unsigned*)alloc((size_t)E * 4);

    hipMemsetAsync(bucket_cnt, 0, BMAX * 4, stream);

    int ebb = (E + 4095) / 4096;
    k_bcount<<<ebb, 256, 0, stream>>>(ei, E, bucket_cnt);
    k_bscan<<<1, 256, 0, stream>>>(bucket_cnt, nbuckets, bucket_base, bucket_cursor);
    k_bin<<<ebb, 256, 0, stream>>>(ei, E, bucket_cursor, binned);
    k_scatter<<<nbuckets, 256, 0, stream>>>(binned, bucket_base, bucket_cnt,
                                            row_start, deg_i, degf, csr_src, N);

    k_wt<<<(16384 + 255) / 256, 256, 0, stream>>>(W_pre, WpreT, 16384);
    k_wtc<<<(4 * 18432 + 255) / 256, 256, 0, stream>>>(W_conv, W_dep, W_aggr, WT, 4 * 18432);

    int gblk = (N + 127) / 128;
    k_gemm_mfma<true, false><<<gblk, 256, 0, stream>>>(x, WpreT, b_pre, h_all,
                                                       nullptr, N, 1);

    int nb4 = (N + 3) / 4;
    for (int d = 0; d < 4; d++) {
        unsigned short* h_d  = h_all + (size_t)d * hstride;
        unsigned short* h_n  = h_all + (size_t)(d + 1) * hstride;
        k_gemm_mfma<false, true><<<gblk, 256, 0, stream>>>(h_d, WT + (size_t)d * 18432,
                                                           b_conv + (size_t)d * HIDDEN,
                                                           ht, ctrl, N, 0);
        k_depth<<<nb4, 256, 0, stream>>>(ht, h_n, cp, wsel + (size_t)d * N, ctrl,
                                         degf, deg_i, row_start, csr_src,
                                         b_dep, b_aggr, N, d == 0 ? 1 : 0);
    }
    k_post<<<(N + 31) / 32, 256, 0, stream>>>(h_all, hstride, wsel, N,
                                              W_post, b_post, (float*)d_out);
}

// Round 9
// 594.671 us; speedup vs baseline: 2.2364x; 1.0986x over previous
//
#include <hip/hip_runtime.h>
#include <math.h>

#define HIDDEN 128
#define NCLS 40
#define BMAX 1024   // max buckets (256 nodes/bucket -> supports N <= 262144)

typedef __attribute__((ext_vector_type(8))) short short8;
typedef __attribute__((ext_vector_type(4))) float f32x4;

__device__ __forceinline__ unsigned short f2bf(float f) {
    unsigned u = __float_as_uint(f);
    unsigned r = u + 0x7FFFu + ((u >> 16) & 1u);   // RNE
    return (unsigned short)(r >> 16);
}
__device__ __forceinline__ float bf_lo(unsigned u) { return __uint_as_float(u << 16); }
__device__ __forceinline__ float bf_hi(unsigned u) { return __uint_as_float(u & 0xFFFF0000u); }

// ---------------- weight prep ----------------
__global__ void k_wt(const float* __restrict__ W, unsigned short* __restrict__ Wt, int total) {
    int i = blockIdx.x * 256 + threadIdx.x;
    if (i < total) {
        int n = (i >> 7) & 127, k = i & 127;
        Wt[i] = f2bf(W[k * 128 + n]);
    }
}

// WT[d][n][k], n in [0,144): 0-127 = W_conv[d][k][n]; 128-129 = W_depth; 130-132 = W_aggr.
__global__ void k_wtc(const float* __restrict__ Wc, const float* __restrict__ Wd,
                      const float* __restrict__ Wa, unsigned short* __restrict__ WT,
                      int total) {
    int i = blockIdx.x * 256 + threadIdx.x;
    if (i < total) {
        int d = i / 18432;
        int rem = i % 18432;
        int n = rem >> 7, k = rem & 127;
        float v = 0.f;
        if (n < 128)      v = Wc[d * 16384 + k * 128 + n];
        else if (n < 130) v = Wd[k * 2 + (n - 128)];
        else if (n < 133) v = Wa[k * 3 + (n - 130)];
        WT[i] = f2bf(v);
    }
}

// ---------------- CSR build (histogram-free: bucket counts -> bin -> scatter) ----------

__launch_bounds__(256)
__global__ void k_bcount(const int* __restrict__ ei, int E, int* __restrict__ bucket_cnt) {
    __shared__ int hist[BMAX];
    const int tid = threadIdx.x;
    for (int i = tid; i < BMAX; i += 256) hist[i] = 0;
    __syncthreads();
    const int e0 = blockIdx.x * 4096;
    #pragma unroll
    for (int i = 0; i < 16; i++) {
        int e = e0 + i * 256 + tid;
        if (e < E) atomicAdd(&hist[ei[E + e] >> 8], 1);
    }
    __syncthreads();
    for (int i = tid; i < BMAX; i += 256) {
        int v = hist[i];
        if (v > 0) atomicAdd(&bucket_cnt[i], v);
    }
}

__global__ void k_bscan(const int* __restrict__ bucket_cnt, int nb,
                        int* __restrict__ bucket_base, int* __restrict__ bucket_cursor) {
    __shared__ int sd[256];
    const int tid = threadIdx.x;
    int v[4];
    int sum = 0;
    #pragma unroll
    for (int j = 0; j < 4; j++) {
        int b = tid * 4 + j;
        v[j] = (b < nb) ? bucket_cnt[b] : 0;
        sum += v[j];
    }
    sd[tid] = sum;
    __syncthreads();
    #pragma unroll
    for (int off = 1; off < 256; off <<= 1) {
        int t = (tid >= off) ? sd[tid - off] : 0;
        __syncthreads();
        sd[tid] += t;
        __syncthreads();
    }
    int base = sd[tid] - sum;   // exclusive
    #pragma unroll
    for (int j = 0; j < 4; j++) {
        int b = tid * 4 + j;
        if (b < nb) {
            bucket_base[b] = base;
            bucket_cursor[b] = base;
            base += v[j];
        }
    }
}

// bin edges into bucket-grouped runs of packed (dstlocal<<24 | src). Needs N < 2^24.
__launch_bounds__(256)
__global__ void k_bin(const int* __restrict__ ei, int E,
                      int* __restrict__ bucket_cursor, unsigned* __restrict__ binned) {
    __shared__ int hist[BMAX];
    __shared__ int rankc[BMAX];
    __shared__ int lbase[BMAX];
    const int tid = threadIdx.x;
    const int e0 = blockIdx.x * 4096;
    for (int i = tid; i < BMAX; i += 256) { hist[i] = 0; rankc[i] = 0; }
    __syncthreads();
    int bkt[16];
    unsigned pk[16];
    #pragma unroll
    for (int i = 0; i < 16; i++) {
        int e = e0 + i * 256 + tid;
        if (e < E) {
            int s = ei[e];
            int d = ei[E + e];
            bkt[i] = d >> 8;
            pk[i] = ((unsigned)(d & 255) << 24) | (unsigned)s;
            atomicAdd(&hist[bkt[i]], 1);
        } else bkt[i] = -1;
    }
    __syncthreads();
    for (int i = tid; i < BMAX; i += 256)
        if (hist[i] > 0) lbase[i] = atomicAdd(&bucket_cursor[i], hist[i]);
    __syncthreads();
    #pragma unroll
    for (int i = 0; i < 16; i++) {
        if (bkt[i] >= 0) {
            int r = atomicAdd(&rankc[bkt[i]], 1);
            binned[lbase[bkt[i]] + r] = pk[i];
        }
    }
}

// one block per bucket: derive degrees, write row_start/deg/degf coalesced, scatter
// csr as BYTE row offsets (src*256) for cheap gather addressing in k_depth.
__launch_bounds__(256)
__global__ void k_scatter(const unsigned* __restrict__ binned,
                          const int* __restrict__ bucket_base,
                          const int* __restrict__ bucket_cnt,
                          int* __restrict__ row_start, int* __restrict__ deg_i,
                          float* __restrict__ degf,
                          int* __restrict__ csr_off, int N) {
    __shared__ int hist[256];
    __shared__ int rs[256];
    __shared__ int cur[256];
    const int tid = threadIdx.x;
    hist[tid] = 0;
    __syncthreads();
    const int base = bucket_base[blockIdx.x];
    const int cnt = bucket_cnt[blockIdx.x];
    for (int i = tid; i < cnt; i += 256)
        atomicAdd(&hist[binned[base + i] >> 24], 1);
    __syncthreads();
    int v = hist[tid];
    rs[tid] = v;
    __syncthreads();
    #pragma unroll
    for (int off = 1; off < 256; off <<= 1) {
        int t = (tid >= off) ? rs[tid - off] : 0;
        __syncthreads();
        rs[tid] += t;
        __syncthreads();
    }
    int gstart = base + rs[tid] - v;
    int n = (blockIdx.x << 8) + tid;
    if (n < N) {
        row_start[n] = gstart;
        deg_i[n] = v;
        degf[n] = fmaxf((float)v, 1.0f);
    }
    __syncthreads();
    rs[tid] = gstart;
    cur[tid] = 0;
    __syncthreads();
    for (int i = tid; i < cnt; i += 256) {
        unsigned p = binned[base + i];
        int dl = (int)(p >> 24);
        int r = atomicAdd(&cur[dl], 1);
        csr_off[rs[dl] + r] = (int)((p & 0xFFFFFFu) << 8);   // src * 256 bytes
    }
}

// ---------------- bf16 MFMA GEMM, A streamed from global (no A-LDS, no k-loop barriers) ----
// Full 144x128 W staged ONCE in LDS (row stride 132 shorts = 264B -> conflict-free
// 16-lane b128 fragment reads). MFMA operands SWAPPED (W first, A second): D row =
// feature (q*4+reg), D col = node (lane&15) -> each lane's 4 acc regs = 4 consecutive
// features of one node -> packed ushort4 stores.

template <bool AF32, bool CTRL>
__launch_bounds__(256)
__global__ void k_gemm_mfma(const void* __restrict__ Ain,
                            const unsigned short* __restrict__ Wt,
                            const float* __restrict__ bias,
                            unsigned short* __restrict__ Cb,
                            float* __restrict__ ctrl,
                            int M, int do_relu) {
    __shared__ unsigned short Ws[144 * 132];
    const int tid = threadIdx.x;
    const int lane = tid & 63;
    const int wv = tid >> 6;
    const int row_blk = blockIdx.x * 128;
    const int rows0 = (wv >> 1) * 64;
    const int cols0 = (wv & 1) * 64;
    const int l15 = lane & 15;
    const int q = lane >> 4;
    const int RWS = CTRL ? 144 : 128;

    // stage all K=128 of W once: 16 x 16B chunks per row
    for (int c = tid; c < RWS * 16; c += 256) {
        int r = c >> 4, ch = c & 15;
        *(uint4*)&Ws[r * 132 + ch * 8] = *(const uint4*)(Wt + (size_t)r * HIDDEN + ch * 8);
    }
    __syncthreads();

    f32x4 acc[4][4] = {};
    f32x4 acc5[4] = {};
    for (int k0 = 0; k0 < 128; k0 += 32) {
        short8 af[4];
        #pragma unroll
        for (int mi = 0; mi < 4; mi++) {
            int ar = row_blk + rows0 + mi * 16 + l15;
            if (AF32) {
                const float* A = (const float*)Ain;
                float4 v0 = make_float4(0.f, 0.f, 0.f, 0.f);
                float4 v1 = make_float4(0.f, 0.f, 0.f, 0.f);
                if (ar < M) {
                    v0 = *(const float4*)(A + (size_t)ar * HIDDEN + k0 + q * 8);
                    v1 = *(const float4*)(A + (size_t)ar * HIDDEN + k0 + q * 8 + 4);
                }
                short8 t;
                t[0] = (short)f2bf(v0.x); t[1] = (short)f2bf(v0.y);
                t[2] = (short)f2bf(v0.z); t[3] = (short)f2bf(v0.w);
                t[4] = (short)f2bf(v1.x); t[5] = (short)f2bf(v1.y);
                t[6] = (short)f2bf(v1.z); t[7] = (short)f2bf(v1.w);
                af[mi] = t;
            } else {
                const unsigned short* A = (const unsigned short*)Ain;
                short8 t = {};
                if (ar < M) t = *(const short8*)(A + (size_t)ar * HIDDEN + k0 + q * 8);
                af[mi] = t;
            }
        }
        #pragma unroll
        for (int ni = 0; ni < 4; ni++) {
            short8 bw = *(const short8*)&Ws[(cols0 + ni * 16 + l15) * 132 + k0 + q * 8];
            #pragma unroll
            for (int mi = 0; mi < 4; mi++)
                acc[mi][ni] = __builtin_amdgcn_mfma_f32_16x16x32_bf16(
                    bw, af[mi], acc[mi][ni], 0, 0, 0);   // swapped: W first, A second
        }
        if (CTRL && (wv & 1) == 0) {
            short8 bc = *(const short8*)&Ws[(128 + l15) * 132 + k0 + q * 8];
            #pragma unroll
            for (int mi = 0; mi < 4; mi++)
                acc5[mi] = __builtin_amdgcn_mfma_f32_16x16x32_bf16(
                    bc, af[mi], acc5[mi], 0, 0, 0);
        }
    }
    // epilogue: acc[mi][ni] reg r -> feature cols0+ni*16+q*4+r of node rows0+mi*16+l15
    #pragma unroll
    for (int mi = 0; mi < 4; mi++) {
        int node = row_blk + rows0 + mi * 16 + l15;
        if (node < M) {
            #pragma unroll
            for (int ni = 0; ni < 4; ni++) {
                int fb = cols0 + ni * 16 + q * 4;
                float4 bv = *(const float4*)&bias[fb];
                float o0 = acc[mi][ni][0] + bv.x;
                float o1 = acc[mi][ni][1] + bv.y;
                float o2 = acc[mi][ni][2] + bv.z;
                float o3 = acc[mi][ni][3] + bv.w;
                if (do_relu) {
                    o0 = fmaxf(o0, 0.f); o1 = fmaxf(o1, 0.f);
                    o2 = fmaxf(o2, 0.f); o3 = fmaxf(o3, 0.f);
                }
                ushort4 ov;
                ov.x = f2bf(o0); ov.y = f2bf(o1); ov.z = f2bf(o2); ov.w = f2bf(o3);
                *(ushort4*)(Cb + (size_t)node * HIDDEN + fb) = ov;
            }
            if (CTRL && (wv & 1) == 0) {
                if (q == 0) {
                    *(float4*)(ctrl + (size_t)node * 8) =
                        make_float4(acc5[mi][0], acc5[mi][1], acc5[mi][2], acc5[mi][3]);
                } else if (q == 1) {
                    ctrl[(size_t)node * 8 + 4] = acc5[mi][0];
                }
            }
        }
    }
}

// ---------------- fused depth step ----------------
// one wave per node; each lane owns 4 features (8B uint2 gather), wave processes
// 2 edges/iteration via half-waves; cross-half shfl_xor combine; half0 stores ushort4.

__launch_bounds__(256)
__global__ void k_depth(const unsigned short* __restrict__ ht,
                        unsigned short* __restrict__ h_out,
                        float* __restrict__ cp, float* __restrict__ wsel,
                        const float* __restrict__ ctrl,
                        const float* __restrict__ degf, const int* __restrict__ deg_i,
                        const int* __restrict__ row_start, const int* __restrict__ csr_off,
                        const float* __restrict__ bd, const float* __restrict__ ba,
                        int N, int first) {
    const int lane = threadIdx.x & 63;
    const int wave = threadIdx.x >> 6;
    const int node = blockIdx.x * 4 + wave;
    if (node >= N) return;
    const int nodeu = __builtin_amdgcn_readfirstlane(node);
    const int half = lane >> 5;
    const int fb = (lane & 31) * 4;      // feature base (4 features/lane)
    const int fob = fb * 2;              // byte offset within row
    const char* htb = (const char*)ht;

    // controller softmaxes from precomputed logits
    float4 c4 = *(const float4*)(ctrl + (size_t)nodeu * 8);
    float cl4 = ctrl[(size_t)nodeu * 8 + 4];
    float d0 = c4.x + bd[0], d1 = c4.y + bd[1];
    float a0 = c4.z + ba[0], a1 = c4.w + ba[1], a2 = cl4 + ba[2];
    float m2 = fmaxf(d0, d1);
    float e0 = __expf(d0 - m2), e1 = __expf(d1 - m2);
    float inv2 = 1.f / (e0 + e1);
    float sp0 = e0 * inv2, sp1 = e1 * inv2;
    float m3 = fmaxf(fmaxf(a0, a1), a2);
    float f0 = __expf(a0 - m3), f1 = __expf(a1 - m3), f2 = __expf(a2 - m3);
    float inv3 = 1.f / (f0 + f1 + f2);
    float ap0 = f0 * inv3, ap1 = f1 * inv3, ap2 = f2 * inv3;

    const int cnt = deg_i[nodeu];
    const int start = row_start[nodeu];
    const float invd = 1.0f / degf[nodeu];

    float s0 = 0.f, s1 = 0.f, s2 = 0.f, s3 = 0.f;
    float x0m = -3.4e38f, x1m = -3.4e38f, x2m = -3.4e38f, x3m = -3.4e38f;

    for (int eb = 0; eb < cnt; eb += 64) {
        int idx = eb + lane;
        int soff = (idx < cnt) ? csr_off[start + idx] : 0;
        int lim = min(64, cnt - eb);
        int lim2 = lim & ~1;
        int j = 0;
        #define GPAIR(JJ)                                                     \
        {                                                                     \
            int o = __shfl(soff, (JJ) + half);                                \
            uint2 u = *(const uint2*)(htb + (unsigned)(o + fob));             \
            float px0 = bf_lo(u.x), px1 = bf_hi(u.x);                         \
            float px2 = bf_lo(u.y), px3 = bf_hi(u.y);                         \
            s0 += px0; s1 += px1; s2 += px2; s3 += px3;                       \
            x0m = fmaxf(x0m, px0); x1m = fmaxf(x1m, px1);                     \
            x2m = fmaxf(x2m, px2); x3m = fmaxf(x3m, px3);                     \
        }
        for (; j + 8 <= lim2; j += 8) { GPAIR(j) GPAIR(j + 2) GPAIR(j + 4) GPAIR(j + 6) }
        for (; j < lim2; j += 2) GPAIR(j)
        #undef GPAIR
        if (lim & 1) {
            int o = __shfl(soff, lim - 1);
            if (half == 0) {
                uint2 u = *(const uint2*)(htb + (unsigned)(o + fob));
                float px0 = bf_lo(u.x), px1 = bf_hi(u.x);
                float px2 = bf_lo(u.y), px3 = bf_hi(u.y);
                s0 += px0; s1 += px1; s2 += px2; s3 += px3;
                x0m = fmaxf(x0m, px0); x1m = fmaxf(x1m, px1);
                x2m = fmaxf(x2m, px2); x3m = fmaxf(x3m, px3);
            }
        }
    }
    // combine halves
    s0 += __shfl_xor(s0, 32); s1 += __shfl_xor(s1, 32);
    s2 += __shfl_xor(s2, 32); s3 += __shfl_xor(s3, 32);
    x0m = fmaxf(x0m, __shfl_xor(x0m, 32)); x1m = fmaxf(x1m, __shfl_xor(x1m, 32));
    x2m = fmaxf(x2m, __shfl_xor(x2m, 32)); x3m = fmaxf(x3m, __shfl_xor(x3m, 32));

    if (cnt == 0) { x0m = 0.f; x1m = 0.f; x2m = 0.f; x3m = 0.f; }

    if (half == 0) {
        uint2 su = *(const uint2*)(htb + (unsigned)(nodeu * 256 + fob));
        float h0 = ap0 * (s0 * invd) + ap1 * x0m + ap2 * bf_lo(su.x);
        float h1 = ap0 * (s1 * invd) + ap1 * x1m + ap2 * bf_hi(su.x);
        float h2 = ap0 * (s2 * invd) + ap1 * x2m + ap2 * bf_lo(su.y);
        float h3 = ap0 * (s3 * invd) + ap1 * x3m + ap2 * bf_hi(su.y);
        h0 = fmaxf(h0, 0.f); h1 = fmaxf(h1, 0.f);
        h2 = fmaxf(h2, 0.f); h3 = fmaxf(h3, 0.f);
        ushort4 ho;
        ho.x = f2bf(h0); ho.y = f2bf(h1); ho.z = f2bf(h2); ho.w = f2bf(h3);
        *(ushort4*)(h_out + (size_t)nodeu * HIDDEN + fb) = ho;
    }
    if (lane == 0) {
        float cpv = first ? 1.0f : cp[nodeu];
        wsel[nodeu] = cpv * sp1;
        cp[nodeu] = cpv * sp0;
    }
}

// ---------------- post: sel = sum_d w_d * h_{d+1}; logits; log_softmax ----------------

__launch_bounds__(256)
__global__ void k_post(const unsigned short* __restrict__ h_all, size_t hstride,
                       const float* __restrict__ wsel, int N,
                       const float* __restrict__ Wp, const float* __restrict__ bp,
                       float* __restrict__ out) {
    __shared__ float Ss[32][132];
    __shared__ float Wt[NCLS][132];
    __shared__ float bs[NCLS];
    const int tid = threadIdx.x;
    const int n0 = blockIdx.x * 32;

    for (int i = tid; i < (HIDDEN * NCLS) / 4; i += 256) {
        float4 v = *(const float4*)&Wp[i * 4];
        int f = i * 4;
        int k = f / NCLS, c = f % NCLS;
        float e[4] = {v.x, v.y, v.z, v.w};
        #pragma unroll
        for (int j = 0; j < 4; j++) {
            int cc = c + j, kk = k;
            if (cc >= NCLS) { cc -= NCLS; kk++; }
            Wt[cc][kk] = e[j];
        }
    }
    if (tid < NCLS) bs[tid] = bp[tid];

    const int node_l = tid >> 3;
    const int kc = (tid & 7) * 16;
    const int ng = n0 + node_l;
    float sel[16];
    #pragma unroll
    for (int i = 0; i < 16; i++) sel[i] = 0.f;
    if (ng < N) {
        #pragma unroll
        for (int d = 0; d < 4; d++) {
            float w = wsel[(size_t)d * N + ng];
            const unsigned short* hrow = h_all + (size_t)(d + 1) * hstride + (size_t)ng * HIDDEN;
            #pragma unroll
            for (int u = 0; u < 2; u++) {
                uint4 p = *(const uint4*)(hrow + kc + u * 8);
                unsigned vs[4] = {p.x, p.y, p.z, p.w};
                #pragma unroll
                for (int j = 0; j < 4; j++) {
                    sel[u * 8 + j * 2 + 0] += w * bf_lo(vs[j]);
                    sel[u * 8 + j * 2 + 1] += w * bf_hi(vs[j]);
                }
            }
        }
    }
    #pragma unroll
    for (int u = 0; u < 4; u++)
        *(float4*)&Ss[node_l][kc + u * 4] =
            make_float4(sel[u * 4], sel[u * 4 + 1], sel[u * 4 + 2], sel[u * 4 + 3]);
    __syncthreads();

    const int c0 = (tid & 7) * 5;
    float z[5];
    #pragma unroll
    for (int i = 0; i < 5; i++) z[i] = bs[c0 + i];
    for (int k = 0; k < HIDDEN; k += 4) {
        float4 s4 = *(const float4*)&Ss[node_l][k];
        #pragma unroll
        for (int i = 0; i < 5; i++) {
            float4 w4 = *(const float4*)&Wt[c0 + i][k];
            z[i] += s4.x * w4.x + s4.y * w4.y + s4.z * w4.z + s4.w * w4.w;
        }
    }
    float m = z[0];
    #pragma unroll
    for (int i = 1; i < 5; i++) m = fmaxf(m, z[i]);
    #pragma unroll
    for (int off = 1; off < 8; off <<= 1) m = fmaxf(m, __shfl_xor(m, off));
    float s = 0.f;
    #pragma unroll
    for (int i = 0; i < 5; i++) s += expf(z[i] - m);
    #pragma unroll
    for (int off = 1; off < 8; off <<= 1) s += __shfl_xor(s, off);
    float lg = m + logf(s);
    if (ng < N) {
        #pragma unroll
        for (int i = 0; i < 5; i++)
            out[(size_t)ng * NCLS + c0 + i] = z[i] - lg;
    }
}

// ---------------- launch ----------------

extern "C" void kernel_launch(void* const* d_in, const int* in_sizes, int n_in,
                              void* d_out, int out_size, void* d_ws, size_t ws_size,
                              hipStream_t stream) {
    const float* x      = (const float*)d_in[0];
    const int*   ei     = (const int*)d_in[1];
    const float* W_pre  = (const float*)d_in[2];
    const float* b_pre  = (const float*)d_in[3];
    const float* W_dep  = (const float*)d_in[4];
    const float* b_dep  = (const float*)d_in[5];
    const float* W_aggr = (const float*)d_in[6];
    const float* b_aggr = (const float*)d_in[7];
    const float* W_conv = (const float*)d_in[8];
    const float* b_conv = (const float*)d_in[9];
    const float* W_post = (const float*)d_in[10];
    const float* b_post = (const float*)d_in[11];

    const int N = in_sizes[0] / HIDDEN;
    const int E = in_sizes[1] / 2;
    const int nbuckets = (N + 255) >> 8;

    char* ws = (char*)d_ws;
    size_t off = 0;
    auto alloc = [&](size_t bytes) -> void* {
        void* p = ws + off;
        off += (bytes + 255) & ~(size_t)255;
        return p;
    };
    const size_t hstride = (size_t)N * HIDDEN;
    unsigned short* h_all  = (unsigned short*)alloc(5 * hstride * 2);  // h_0..h_4
    unsigned short* ht     = (unsigned short*)alloc(hstride * 2);
    float* cp       = (float*)alloc((size_t)N * 4);
    float* wsel     = (float*)alloc((size_t)4 * N * 4);
    float* degf     = (float*)alloc((size_t)N * 4);
    float* ctrl     = (float*)alloc((size_t)N * 8 * 4);
    unsigned short* WpreT = (unsigned short*)alloc(128 * 128 * 2);
    unsigned short* WT    = (unsigned short*)alloc(4 * 144 * 128 * 2);
    int*   deg_i    = (int*)alloc((size_t)N * 4);
    int*   row_start= (int*)alloc((size_t)N * 4);
    int*   bucket_cnt    = (int*)alloc(BMAX * 4);
    int*   bucket_base   = (int*)alloc(BMAX * 4);
    int*   bucket_cursor = (int*)alloc(BMAX * 4);
    int*   csr_off  = (int*)alloc((size_t)E * 4);
    unsigned* binned = (unsigned*)alloc((size_t)E * 4);

    hipMemsetAsync(bucket_cnt, 0, BMAX * 4, stream);

    int ebb = (E + 4095) / 4096;
    k_bcount<<<ebb, 256, 0, stream>>>(ei, E, bucket_cnt);
    k_bscan<<<1, 256, 0, stream>>>(bucket_cnt, nbuckets, bucket_base, bucket_cursor);
    k_bin<<<ebb, 256, 0, stream>>>(ei, E, bucket_cursor, binned);
    k_scatter<<<nbuckets, 256, 0, stream>>>(binned, bucket_base, bucket_cnt,
                                            row_start, deg_i, degf, csr_off, N);

    k_wt<<<(16384 + 255) / 256, 256, 0, stream>>>(W_pre, WpreT, 16384);
    k_wtc<<<(4 * 18432 + 255) / 256, 256, 0, stream>>>(W_conv, W_dep, W_aggr, WT, 4 * 18432);

    int gblk = (N + 127) / 128;
    k_gemm_mfma<true, false><<<gblk, 256, 0, stream>>>(x, WpreT, b_pre, h_all,
                                                       nullptr, N, 1);

    int nb4 = (N + 3) / 4;
    for (int d = 0; d < 4; d++) {
        unsigned short* h_d  = h_all + (size_t)d * hstride;
        unsigned short* h_n  = h_all + (size_t)(d + 1) * hstride;
        k_gemm_mfma<false, true><<<gblk, 256, 0, stream>>>(h_d, WT + (size_t)d * 18432,
                                                           b_conv + (size_t)d * HIDDEN,
                                                           ht, ctrl, N, 0);
        k_depth<<<nb4, 256, 0, stream>>>(ht, h_n, cp, wsel + (size_t)d * N, ctrl,
                                         degf, deg_i, row_start, csr_off,
                                         b_dep, b_aggr, N, d == 0 ? 1 : 0);
    }
    k_post<<<(N + 31) / 32, 256, 0, stream>>>(h_all, hstride, wsel, N,
                                              W_post, b_post, (float*)d_out);
}

// Round 10
// 583.445 us; speedup vs baseline: 2.2794x; 1.0192x over previous
//
#include <hip/hip_runtime.h>
#include <math.h>

#define HIDDEN 128
#define NCLS 40
#define BMAX 1024   // max buckets (256 nodes/bucket -> supports N <= 262144)

typedef __attribute__((ext_vector_type(8))) short short8;
typedef __attribute__((ext_vector_type(4))) float f32x4;

__device__ __forceinline__ unsigned short f2bf(float f) {
    unsigned u = __float_as_uint(f);
    unsigned r = u + 0x7FFFu + ((u >> 16) & 1u);   // RNE
    return (unsigned short)(r >> 16);
}
__device__ __forceinline__ float bf_lo(unsigned u) { return __uint_as_float(u << 16); }
__device__ __forceinline__ float bf_hi(unsigned u) { return __uint_as_float(u & 0xFFFF0000u); }

// ---------------- weight prep (merged): WpreT + WT ----------------
// i < 16384: WpreT[n][k] = W_pre[k][n]
// else: WT[d][n][k], n in [0,144): 0-127 W_conv[d][k][n]; 128-129 W_depth; 130-132 W_aggr.
__global__ void k_wprep(const float* __restrict__ Wp, const float* __restrict__ Wc,
                        const float* __restrict__ Wd, const float* __restrict__ Wa,
                        unsigned short* __restrict__ WpreT, unsigned short* __restrict__ WT) {
    int i = blockIdx.x * 256 + threadIdx.x;
    if (i < 16384) {
        int n = i >> 7, k = i & 127;
        WpreT[i] = f2bf(Wp[k * 128 + n]);
    } else if (i < 16384 + 4 * 18432) {
        int j = i - 16384;
        int d = j / 18432;
        int rem = j % 18432;
        int n = rem >> 7, k = rem & 127;
        float v = 0.f;
        if (n < 128)      v = Wc[d * 16384 + k * 128 + n];
        else if (n < 130) v = Wd[k * 2 + (n - 128)];
        else if (n < 133) v = Wa[k * 3 + (n - 130)];
        WT[j] = f2bf(v);
    }
}

// ---------------- CSR build (histogram-free: bucket counts -> bin -> scatter) ----------

__launch_bounds__(256)
__global__ void k_bcount(const int* __restrict__ ei, int E, int* __restrict__ bucket_cnt) {
    __shared__ int hist[BMAX];
    const int tid = threadIdx.x;
    for (int i = tid; i < BMAX; i += 256) hist[i] = 0;
    __syncthreads();
    const int e0 = blockIdx.x * 4096;
    #pragma unroll
    for (int i = 0; i < 16; i++) {
        int e = e0 + i * 256 + tid;
        if (e < E) atomicAdd(&hist[ei[E + e] >> 8], 1);
    }
    __syncthreads();
    for (int i = tid; i < BMAX; i += 256) {
        int v = hist[i];
        if (v > 0) atomicAdd(&bucket_cnt[i], v);
    }
}

__global__ void k_bscan(const int* __restrict__ bucket_cnt, int nb,
                        int* __restrict__ bucket_base, int* __restrict__ bucket_cursor) {
    __shared__ int sd[256];
    const int tid = threadIdx.x;
    int v[4];
    int sum = 0;
    #pragma unroll
    for (int j = 0; j < 4; j++) {
        int b = tid * 4 + j;
        v[j] = (b < nb) ? bucket_cnt[b] : 0;
        sum += v[j];
    }
    sd[tid] = sum;
    __syncthreads();
    #pragma unroll
    for (int off = 1; off < 256; off <<= 1) {
        int t = (tid >= off) ? sd[tid - off] : 0;
        __syncthreads();
        sd[tid] += t;
        __syncthreads();
    }
    int base = sd[tid] - sum;   // exclusive
    #pragma unroll
    for (int j = 0; j < 4; j++) {
        int b = tid * 4 + j;
        if (b < nb) {
            bucket_base[b] = base;
            bucket_cursor[b] = base;
            base += v[j];
        }
    }
}

// bin edges into bucket-grouped runs of packed (dstlocal<<24 | src). Needs N < 2^24.
__launch_bounds__(256)
__global__ void k_bin(const int* __restrict__ ei, int E,
                      int* __restrict__ bucket_cursor, unsigned* __restrict__ binned) {
    __shared__ int hist[BMAX];
    __shared__ int rankc[BMAX];
    __shared__ int lbase[BMAX];
    const int tid = threadIdx.x;
    const int e0 = blockIdx.x * 4096;
    for (int i = tid; i < BMAX; i += 256) { hist[i] = 0; rankc[i] = 0; }
    __syncthreads();
    int bkt[16];
    unsigned pk[16];
    #pragma unroll
    for (int i = 0; i < 16; i++) {
        int e = e0 + i * 256 + tid;
        if (e < E) {
            int s = ei[e];
            int d = ei[E + e];
            bkt[i] = d >> 8;
            pk[i] = ((unsigned)(d & 255) << 24) | (unsigned)s;
            atomicAdd(&hist[bkt[i]], 1);
        } else bkt[i] = -1;
    }
    __syncthreads();
    for (int i = tid; i < BMAX; i += 256)
        if (hist[i] > 0) lbase[i] = atomicAdd(&bucket_cursor[i], hist[i]);
    __syncthreads();
    #pragma unroll
    for (int i = 0; i < 16; i++) {
        if (bkt[i] >= 0) {
            int r = atomicAdd(&rankc[bkt[i]], 1);
            binned[lbase[bkt[i]] + r] = pk[i];
        }
    }
}

// one block per bucket: derive degrees, write row_start/deg/degf coalesced, scatter
// csr as BYTE row offsets (src*256) for cheap gather addressing in k_depth.
__launch_bounds__(256)
__global__ void k_scatter(const unsigned* __restrict__ binned,
                          const int* __restrict__ bucket_base,
                          const int* __restrict__ bucket_cnt,
                          int* __restrict__ row_start, int* __restrict__ deg_i,
                          float* __restrict__ degf,
                          int* __restrict__ csr_off, int N) {
    __shared__ int hist[256];
    __shared__ int rs[256];
    __shared__ int cur[256];
    const int tid = threadIdx.x;
    hist[tid] = 0;
    __syncthreads();
    const int base = bucket_base[blockIdx.x];
    const int cnt = bucket_cnt[blockIdx.x];
    for (int i = tid; i < cnt; i += 256)
        atomicAdd(&hist[binned[base + i] >> 24], 1);
    __syncthreads();
    int v = hist[tid];
    rs[tid] = v;
    __syncthreads();
    #pragma unroll
    for (int off = 1; off < 256; off <<= 1) {
        int t = (tid >= off) ? rs[tid - off] : 0;
        __syncthreads();
        rs[tid] += t;
        __syncthreads();
    }
    int gstart = base + rs[tid] - v;
    int n = (blockIdx.x << 8) + tid;
    if (n < N) {
        row_start[n] = gstart;
        deg_i[n] = v;
        degf[n] = fmaxf((float)v, 1.0f);
    }
    __syncthreads();
    rs[tid] = gstart;
    cur[tid] = 0;
    __syncthreads();
    for (int i = tid; i < cnt; i += 256) {
        unsigned p = binned[base + i];
        int dl = (int)(p >> 24);
        int r = atomicAdd(&cur[dl], 1);
        csr_off[rs[dl] + r] = (int)((p & 0xFFFFFFu) << 8);   // src * 256 bytes
    }
}

// ---------------- bf16 MFMA GEMM, A streamed from global, A read ONCE per block ----
// Wave w owns rows [wv*32, wv*32+32) x ALL 128 cols -> acc[2][8]. Full 144x128 W in
// LDS (stride 132 shorts, conflict-free b128 reads). Operands swapped (W first):
// D row = feature (q*4+reg), D col = node (lane&15) -> packed ushort4 stores.

template <bool AF32, bool CTRL>
__launch_bounds__(256)
__global__ void k_gemm_mfma(const void* __restrict__ Ain,
                            const unsigned short* __restrict__ Wt,
                            const float* __restrict__ bias,
                            unsigned short* __restrict__ Cb,
                            float* __restrict__ ctrl,
                            int M, int do_relu) {
    __shared__ unsigned short Ws[144 * 132];
    const int tid = threadIdx.x;
    const int lane = tid & 63;
    const int wv = tid >> 6;
    const int row_blk = blockIdx.x * 128;
    const int rows0 = wv * 32;
    const int l15 = lane & 15;
    const int q = lane >> 4;
    const int RWS = CTRL ? 144 : 128;

    // stage all K=128 of W once: 16 x 16B chunks per row
    for (int c = tid; c < RWS * 16; c += 256) {
        int r = c >> 4, ch = c & 15;
        *(uint4*)&Ws[r * 132 + ch * 8] = *(const uint4*)(Wt + (size_t)r * HIDDEN + ch * 8);
    }
    __syncthreads();

    f32x4 acc[2][8] = {};
    f32x4 acc5[2] = {};
    for (int k0 = 0; k0 < 128; k0 += 32) {
        short8 af[2];
        #pragma unroll
        for (int mi = 0; mi < 2; mi++) {
            int ar = row_blk + rows0 + mi * 16 + l15;
            if (AF32) {
                const float* A = (const float*)Ain;
                float4 v0 = make_float4(0.f, 0.f, 0.f, 0.f);
                float4 v1 = make_float4(0.f, 0.f, 0.f, 0.f);
                if (ar < M) {
                    v0 = *(const float4*)(A + (size_t)ar * HIDDEN + k0 + q * 8);
                    v1 = *(const float4*)(A + (size_t)ar * HIDDEN + k0 + q * 8 + 4);
                }
                short8 t;
                t[0] = (short)f2bf(v0.x); t[1] = (short)f2bf(v0.y);
                t[2] = (short)f2bf(v0.z); t[3] = (short)f2bf(v0.w);
                t[4] = (short)f2bf(v1.x); t[5] = (short)f2bf(v1.y);
                t[6] = (short)f2bf(v1.z); t[7] = (short)f2bf(v1.w);
                af[mi] = t;
            } else {
                const unsigned short* A = (const unsigned short*)Ain;
                short8 t = {};
                if (ar < M) t = *(const short8*)(A + (size_t)ar * HIDDEN + k0 + q * 8);
                af[mi] = t;
            }
        }
        #pragma unroll
        for (int ni = 0; ni < 8; ni++) {
            short8 bw = *(const short8*)&Ws[(ni * 16 + l15) * 132 + k0 + q * 8];
            #pragma unroll
            for (int mi = 0; mi < 2; mi++)
                acc[mi][ni] = __builtin_amdgcn_mfma_f32_16x16x32_bf16(
                    bw, af[mi], acc[mi][ni], 0, 0, 0);   // swapped: W first, A second
        }
        if (CTRL) {
            short8 bc = *(const short8*)&Ws[(128 + l15) * 132 + k0 + q * 8];
            #pragma unroll
            for (int mi = 0; mi < 2; mi++)
                acc5[mi] = __builtin_amdgcn_mfma_f32_16x16x32_bf16(
                    bc, af[mi], acc5[mi], 0, 0, 0);
        }
    }
    // epilogue: acc[mi][ni] reg r -> feature ni*16+q*4+r of node rows0+mi*16+l15
    #pragma unroll
    for (int mi = 0; mi < 2; mi++) {
        int node = row_blk + rows0 + mi * 16 + l15;
        if (node < M) {
            #pragma unroll
            for (int ni = 0; ni < 8; ni++) {
                int fb = ni * 16 + q * 4;
                float4 bv = *(const float4*)&bias[fb];
                float o0 = acc[mi][ni][0] + bv.x;
                float o1 = acc[mi][ni][1] + bv.y;
                float o2 = acc[mi][ni][2] + bv.z;
                float o3 = acc[mi][ni][3] + bv.w;
                if (do_relu) {
                    o0 = fmaxf(o0, 0.f); o1 = fmaxf(o1, 0.f);
                    o2 = fmaxf(o2, 0.f); o3 = fmaxf(o3, 0.f);
                }
                ushort4 ov;
                ov.x = f2bf(o0); ov.y = f2bf(o1); ov.z = f2bf(o2); ov.w = f2bf(o3);
                *(ushort4*)(Cb + (size_t)node * HIDDEN + fb) = ov;
            }
            if (CTRL) {
                if (q == 0) {
                    *(float4*)(ctrl + (size_t)node * 8) =
                        make_float4(acc5[mi][0], acc5[mi][1], acc5[mi][2], acc5[mi][3]);
                } else if (q == 1) {
                    ctrl[(size_t)node * 8 + 4] = acc5[mi][0];
                }
            }
        }
    }
}

// ---------------- fused depth step ----------------
// one wave per node; each lane owns 4 features (8B uint2 gather), 2 edges/iter via
// half-waves, 8x GPAIR unroll -> 16 edges / 16 loads in flight per wave.

__launch_bounds__(256)
__global__ void k_depth(const unsigned short* __restrict__ ht,
                        unsigned short* __restrict__ h_out,
                        float* __restrict__ cp, float* __restrict__ wsel,
                        const float* __restrict__ ctrl,
                        const float* __restrict__ degf, const int* __restrict__ deg_i,
                        const int* __restrict__ row_start, const int* __restrict__ csr_off,
                        const float* __restrict__ bd, const float* __restrict__ ba,
                        int N, int first) {
    const int lane = threadIdx.x & 63;
    const int wave = threadIdx.x >> 6;
    const int node = blockIdx.x * 4 + wave;
    if (node >= N) return;
    const int nodeu = __builtin_amdgcn_readfirstlane(node);
    const int half = lane >> 5;
    const int fb = (lane & 31) * 4;      // feature base (4 features/lane)
    const int fob = fb * 2;              // byte offset within row
    const char* htb = (const char*)ht;

    // controller softmaxes from precomputed logits
    float4 c4 = *(const float4*)(ctrl + (size_t)nodeu * 8);
    float cl4 = ctrl[(size_t)nodeu * 8 + 4];
    float d0 = c4.x + bd[0], d1 = c4.y + bd[1];
    float a0 = c4.z + ba[0], a1 = c4.w + ba[1], a2 = cl4 + ba[2];
    float m2 = fmaxf(d0, d1);
    float e0 = __expf(d0 - m2), e1 = __expf(d1 - m2);
    float inv2 = 1.f / (e0 + e1);
    float sp0 = e0 * inv2, sp1 = e1 * inv2;
    float m3 = fmaxf(fmaxf(a0, a1), a2);
    float f0 = __expf(a0 - m3), f1 = __expf(a1 - m3), f2 = __expf(a2 - m3);
    float inv3 = 1.f / (f0 + f1 + f2);
    float ap0 = f0 * inv3, ap1 = f1 * inv3, ap2 = f2 * inv3;

    const int cnt = deg_i[nodeu];
    const int start = row_start[nodeu];
    const float invd = 1.0f / degf[nodeu];

    float s0 = 0.f, s1 = 0.f, s2 = 0.f, s3 = 0.f;
    float x0m = -3.4e38f, x1m = -3.4e38f, x2m = -3.4e38f, x3m = -3.4e38f;

    for (int eb = 0; eb < cnt; eb += 64) {
        int idx = eb + lane;
        int soff = (idx < cnt) ? csr_off[start + idx] : 0;
        int lim = min(64, cnt - eb);
        int lim2 = lim & ~1;
        int j = 0;
        #define GPAIR(JJ)                                                     \
        {                                                                     \
            int o = __shfl(soff, (JJ) + half);                                \
            uint2 u = *(const uint2*)(htb + (unsigned)(o + fob));             \
            float px0 = bf_lo(u.x), px1 = bf_hi(u.x);                         \
            float px2 = bf_lo(u.y), px3 = bf_hi(u.y);                         \
            s0 += px0; s1 += px1; s2 += px2; s3 += px3;                       \
            x0m = fmaxf(x0m, px0); x1m = fmaxf(x1m, px1);                     \
            x2m = fmaxf(x2m, px2); x3m = fmaxf(x3m, px3);                     \
        }
        for (; j + 16 <= lim2; j += 16) {
            GPAIR(j) GPAIR(j + 2) GPAIR(j + 4) GPAIR(j + 6)
            GPAIR(j + 8) GPAIR(j + 10) GPAIR(j + 12) GPAIR(j + 14)
        }
        for (; j + 4 <= lim2; j += 4) { GPAIR(j) GPAIR(j + 2) }
        for (; j < lim2; j += 2) GPAIR(j)
        #undef GPAIR
        if (lim & 1) {
            int o = __shfl(soff, lim - 1);
            if (half == 0) {
                uint2 u = *(const uint2*)(htb + (unsigned)(o + fob));
                float px0 = bf_lo(u.x), px1 = bf_hi(u.x);
                float px2 = bf_lo(u.y), px3 = bf_hi(u.y);
                s0 += px0; s1 += px1; s2 += px2; s3 += px3;
                x0m = fmaxf(x0m, px0); x1m = fmaxf(x1m, px1);
                x2m = fmaxf(x2m, px2); x3m = fmaxf(x3m, px3);
            }
        }
    }
    // combine halves
    s0 += __shfl_xor(s0, 32); s1 += __shfl_xor(s1, 32);
    s2 += __shfl_xor(s2, 32); s3 += __shfl_xor(s3, 32);
    x0m = fmaxf(x0m, __shfl_xor(x0m, 32)); x1m = fmaxf(x1m, __shfl_xor(x1m, 32));
    x2m = fmaxf(x2m, __shfl_xor(x2m, 32)); x3m = fmaxf(x3m, __shfl_xor(x3m, 32));

    if (cnt == 0) { x0m = 0.f; x1m = 0.f; x2m = 0.f; x3m = 0.f; }

    if (half == 0) {
        uint2 su = *(const uint2*)(htb + (unsigned)(nodeu * 256 + fob));
        float h0 = ap0 * (s0 * invd) + ap1 * x0m + ap2 * bf_lo(su.x);
        float h1 = ap0 * (s1 * invd) + ap1 * x1m + ap2 * bf_hi(su.x);
        float h2 = ap0 * (s2 * invd) + ap1 * x2m + ap2 * bf_lo(su.y);
        float h3 = ap0 * (s3 * invd) + ap1 * x3m + ap2 * bf_hi(su.y);
        h0 = fmaxf(h0, 0.f); h1 = fmaxf(h1, 0.f);
        h2 = fmaxf(h2, 0.f); h3 = fmaxf(h3, 0.f);
        ushort4 ho;
        ho.x = f2bf(h0); ho.y = f2bf(h1); ho.z = f2bf(h2); ho.w = f2bf(h3);
        *(ushort4*)(h_out + (size_t)nodeu * HIDDEN + fb) = ho;
    }
    if (lane == 0) {
        float cpv = first ? 1.0f : cp[nodeu];
        wsel[nodeu] = cpv * sp1;
        cp[nodeu] = cpv * sp0;
    }
}

// ---------------- post: sel = sum_d w_d * h_{d+1}; logits; log_softmax ----------------

__launch_bounds__(256)
__global__ void k_post(const unsigned short* __restrict__ h_all, size_t hstride,
                       const float* __restrict__ wsel, int N,
                       const float* __restrict__ Wp, const float* __restrict__ bp,
                       float* __restrict__ out) {
    __shared__ float Ss[32][132];
    __shared__ float Wt[NCLS][132];
    __shared__ float bs[NCLS];
    const int tid = threadIdx.x;
    const int n0 = blockIdx.x * 32;

    for (int i = tid; i < (HIDDEN * NCLS) / 4; i += 256) {
        float4 v = *(const float4*)&Wp[i * 4];
        int f = i * 4;
        int k = f / NCLS, c = f % NCLS;
        float e[4] = {v.x, v.y, v.z, v.w};
        #pragma unroll
        for (int j = 0; j < 4; j++) {
            int cc = c + j, kk = k;
            if (cc >= NCLS) { cc -= NCLS; kk++; }
            Wt[cc][kk] = e[j];
        }
    }
    if (tid < NCLS) bs[tid] = bp[tid];

    const int node_l = tid >> 3;
    const int kc = (tid & 7) * 16;
    const int ng = n0 + node_l;
    float sel[16];
    #pragma unroll
    for (int i = 0; i < 16; i++) sel[i] = 0.f;
    if (ng < N) {
        #pragma unroll
        for (int d = 0; d < 4; d++) {
            float w = wsel[(size_t)d * N + ng];
            const unsigned short* hrow = h_all + (size_t)(d + 1) * hstride + (size_t)ng * HIDDEN;
            #pragma unroll
            for (int u = 0; u < 2; u++) {
                uint4 p = *(const uint4*)(hrow + kc + u * 8);
                unsigned vs[4] = {p.x, p.y, p.z, p.w};
                #pragma unroll
                for (int j = 0; j < 4; j++) {
                    sel[u * 8 + j * 2 + 0] += w * bf_lo(vs[j]);
                    sel[u * 8 + j * 2 + 1] += w * bf_hi(vs[j]);
                }
            }
        }
    }
    #pragma unroll
    for (int u = 0; u < 4; u++)
        *(float4*)&Ss[node_l][kc + u * 4] =
            make_float4(sel[u * 4], sel[u * 4 + 1], sel[u * 4 + 2], sel[u * 4 + 3]);
    __syncthreads();

    const int c0 = (tid & 7) * 5;
    float z[5];
    #pragma unroll
    for (int i = 0; i < 5; i++) z[i] = bs[c0 + i];
    for (int k = 0; k < HIDDEN; k += 4) {
        float4 s4 = *(const float4*)&Ss[node_l][k];
        #pragma unroll
        for (int i = 0; i < 5; i++) {
            float4 w4 = *(const float4*)&Wt[c0 + i][k];
            z[i] += s4.x * w4.x + s4.y * w4.y + s4.z * w4.z + s4.w * w4.w;
        }
    }
    float m = z[0];
    #pragma unroll
    for (int i = 1; i < 5; i++) m = fmaxf(m, z[i]);
    #pragma unroll
    for (int off = 1; off < 8; off <<= 1) m = fmaxf(m, __shfl_xor(m, off));
    float s = 0.f;
    #pragma unroll
    for (int i = 0; i < 5; i++) s += expf(z[i] - m);
    #pragma unroll
    for (int off = 1; off < 8; off <<= 1) s += __shfl_xor(s, off);
    float lg = m + logf(s);
    if (ng < N) {
        #pragma unroll
        for (int i = 0; i < 5; i++)
            out[(size_t)ng * NCLS + c0 + i] = z[i] - lg;
    }
}

// ---------------- launch ----------------

extern "C" void kernel_launch(void* const* d_in, const int* in_sizes, int n_in,
                              void* d_out, int out_size, void* d_ws, size_t ws_size,
                              hipStream_t stream) {
    const float* x      = (const float*)d_in[0];
    const int*   ei     = (const int*)d_in[1];
    const float* W_pre  = (const float*)d_in[2];
    const float* b_pre  = (const float*)d_in[3];
    const float* W_dep  = (const float*)d_in[4];
    const float* b_dep  = (const float*)d_in[5];
    const float* W_aggr = (const float*)d_in[6];
    const float* b_aggr = (const float*)d_in[7];
    const float* W_conv = (const float*)d_in[8];
    const float* b_conv = (const float*)d_in[9];
    const float* W_post = (const float*)d_in[10];
    const float* b_post = (const float*)d_in[11];

    const int N = in_sizes[0] / HIDDEN;
    const int E = in_sizes[1] / 2;
    const int nbuckets = (N + 255) >> 8;

    char* ws = (char*)d_ws;
    size_t off = 0;
    auto alloc = [&](size_t bytes) -> void* {
        void* p = ws + off;
        off += (bytes + 255) & ~(size_t)255;
        return p;
    };
    const size_t hstride = (size_t)N * HIDDEN;
    unsigned short* h_all  = (unsigned short*)alloc(5 * hstride * 2);  // h_0..h_4
    unsigned short* ht     = (unsigned short*)alloc(hstride * 2);
    float* cp       = (float*)alloc((size_t)N * 4);
    float* wsel     = (float*)alloc((size_t)4 * N * 4);
    float* degf     = (float*)alloc((size_t)N * 4);
    float* ctrl     = (float*)alloc((size_t)N * 8 * 4);
    unsigned short* WpreT = (unsigned short*)alloc(128 * 128 * 2);
    unsigned short* WT    = (unsigned short*)alloc(4 * 144 * 128 * 2);
    int*   deg_i    = (int*)alloc((size_t)N * 4);
    int*   row_start= (int*)alloc((size_t)N * 4);
    int*   bucket_cnt    = (int*)alloc(BMAX * 4);
    int*   bucket_base   = (int*)alloc(BMAX * 4);
    int*   bucket_cursor = (int*)alloc(BMAX * 4);
    int*   csr_off  = (int*)alloc((size_t)E * 4);
    unsigned* binned = (unsigned*)alloc((size_t)E * 4);

    hipMemsetAsync(bucket_cnt, 0, BMAX * 4, stream);

    int ebb = (E + 4095) / 4096;
    k_bcount<<<ebb, 256, 0, stream>>>(ei, E, bucket_cnt);
    k_bscan<<<1, 256, 0, stream>>>(bucket_cnt, nbuckets, bucket_base, bucket_cursor);
    k_bin<<<ebb, 256, 0, stream>>>(ei, E, bucket_cursor, binned);
    k_scatter<<<nbuckets, 256, 0, stream>>>(binned, bucket_base, bucket_cnt,
                                            row_start, deg_i, degf, csr_off, N);

    int wtot = 16384 + 4 * 18432;
    k_wprep<<<(wtot + 255) / 256, 256, 0, stream>>>(W_pre, W_conv, W_dep, W_aggr,
                                                    WpreT, WT);

    int gblk = (N + 127) / 128;
    k_gemm_mfma<true, false><<<gblk, 256, 0, stream>>>(x, WpreT, b_pre, h_all,
                                                       nullptr, N, 1);

    int nb4 = (N + 3) / 4;
    for (int d = 0; d < 4; d++) {
        unsigned short* h_d  = h_all + (size_t)d * hstride;
        unsigned short* h_n  = h_all + (size_t)(d + 1) * hstride;
        k_gemm_mfma<false, true><<<gblk, 256, 0, stream>>>(h_d, WT + (size_t)d * 18432,
                                                           b_conv + (size_t)d * HIDDEN,
                                                           ht, ctrl, N, 0);
        k_depth<<<nb4, 256, 0, stream>>>(ht, h_n, cp, wsel + (size_t)d * N, ctrl,
                                         degf, deg_i, row_start, csr_off,
                                         b_dep, b_aggr, N, d == 0 ? 1 : 0);
    }
    k_post<<<(N + 31) / 32, 256, 0, stream>>>(h_all, hstride, wsel, N,
                                              W_post, b_post, (float*)d_out);
}

// Round 11
// 552.286 us; speedup vs baseline: 2.4080x; 1.0564x over previous
//
#include <hip/hip_runtime.h>
#include <math.h>

#define HIDDEN 128
#define NCLS 40
#define BMAX 1024   // max buckets (256 nodes/bucket -> supports N <= 262144)

typedef __attribute__((ext_vector_type(8))) short short8;
typedef __attribute__((ext_vector_type(4))) float f32x4;
typedef __attribute__((ext_vector_type(2))) float f32x2;

__device__ __forceinline__ unsigned short f2bf(float f) {
    unsigned u = __float_as_uint(f);
    unsigned r = u + 0x7FFFu + ((u >> 16) & 1u);   // RNE
    return (unsigned short)(r >> 16);
}
__device__ __forceinline__ float bf_lo(unsigned u) { return __uint_as_float(u << 16); }
__device__ __forceinline__ float bf_hi(unsigned u) { return __uint_as_float(u & 0xFFFF0000u); }

// ---------------- weight prep (merged): WpreT + WT ----------------
__global__ void k_wprep(const float* __restrict__ Wp, const float* __restrict__ Wc,
                        const float* __restrict__ Wd, const float* __restrict__ Wa,
                        unsigned short* __restrict__ WpreT, unsigned short* __restrict__ WT) {
    int i = blockIdx.x * 256 + threadIdx.x;
    if (i < 16384) {
        int n = i >> 7, k = i & 127;
        WpreT[i] = f2bf(Wp[k * 128 + n]);
    } else if (i < 16384 + 4 * 18432) {
        int j = i - 16384;
        int d = j / 18432;
        int rem = j % 18432;
        int n = rem >> 7, k = rem & 127;
        float v = 0.f;
        if (n < 128)      v = Wc[d * 16384 + k * 128 + n];
        else if (n < 130) v = Wd[k * 2 + (n - 128)];
        else if (n < 133) v = Wa[k * 3 + (n - 130)];
        WT[j] = f2bf(v);
    }
}

// ---------------- CSR build (histogram-free: bucket counts -> bin -> scatter) ----------

__launch_bounds__(256)
__global__ void k_bcount(const int* __restrict__ ei, int E, int* __restrict__ bucket_cnt) {
    __shared__ int hist[BMAX];
    const int tid = threadIdx.x;
    for (int i = tid; i < BMAX; i += 256) hist[i] = 0;
    __syncthreads();
    const int e0 = blockIdx.x * 4096;
    #pragma unroll
    for (int i = 0; i < 16; i++) {
        int e = e0 + i * 256 + tid;
        if (e < E) atomicAdd(&hist[ei[E + e] >> 8], 1);
    }
    __syncthreads();
    for (int i = tid; i < BMAX; i += 256) {
        int v = hist[i];
        if (v > 0) atomicAdd(&bucket_cnt[i], v);
    }
}

__global__ void k_bscan(const int* __restrict__ bucket_cnt, int nb,
                        int* __restrict__ bucket_base, int* __restrict__ bucket_cursor) {
    __shared__ int sd[256];
    const int tid = threadIdx.x;
    int v[4];
    int sum = 0;
    #pragma unroll
    for (int j = 0; j < 4; j++) {
        int b = tid * 4 + j;
        v[j] = (b < nb) ? bucket_cnt[b] : 0;
        sum += v[j];
    }
    sd[tid] = sum;
    __syncthreads();
    #pragma unroll
    for (int off = 1; off < 256; off <<= 1) {
        int t = (tid >= off) ? sd[tid - off] : 0;
        __syncthreads();
        sd[tid] += t;
        __syncthreads();
    }
    int base = sd[tid] - sum;   // exclusive
    #pragma unroll
    for (int j = 0; j < 4; j++) {
        int b = tid * 4 + j;
        if (b < nb) {
            bucket_base[b] = base;
            bucket_cursor[b] = base;
            base += v[j];
        }
    }
}

// bin edges into bucket-grouped runs of packed (dstlocal<<24 | src). Needs N < 2^24.
__launch_bounds__(256)
__global__ void k_bin(const int* __restrict__ ei, int E,
                      int* __restrict__ bucket_cursor, unsigned* __restrict__ binned) {
    __shared__ int hist[BMAX];
    __shared__ int rankc[BMAX];
    __shared__ int lbase[BMAX];
    const int tid = threadIdx.x;
    const int e0 = blockIdx.x * 4096;
    for (int i = tid; i < BMAX; i += 256) { hist[i] = 0; rankc[i] = 0; }
    __syncthreads();
    int bkt[16];
    unsigned pk[16];
    #pragma unroll
    for (int i = 0; i < 16; i++) {
        int e = e0 + i * 256 + tid;
        if (e < E) {
            int s = ei[e];
            int d = ei[E + e];
            bkt[i] = d >> 8;
            pk[i] = ((unsigned)(d & 255) << 24) | (unsigned)s;
            atomicAdd(&hist[bkt[i]], 1);
        } else bkt[i] = -1;
    }
    __syncthreads();
    for (int i = tid; i < BMAX; i += 256)
        if (hist[i] > 0) lbase[i] = atomicAdd(&bucket_cursor[i], hist[i]);
    __syncthreads();
    #pragma unroll
    for (int i = 0; i < 16; i++) {
        if (bkt[i] >= 0) {
            int r = atomicAdd(&rankc[bkt[i]], 1);
            binned[lbase[bkt[i]] + r] = pk[i];
        }
    }
}

// one block per bucket: derive degrees, write row_start/deg/degf coalesced, scatter
// csr as fp8-row BYTE offsets (src*128) for cheap gather addressing in k_depth.
__launch_bounds__(256)
__global__ void k_scatter(const unsigned* __restrict__ binned,
                          const int* __restrict__ bucket_base,
                          const int* __restrict__ bucket_cnt,
                          int* __restrict__ row_start, int* __restrict__ deg_i,
                          float* __restrict__ degf,
                          int* __restrict__ csr_off, int N) {
    __shared__ int hist[256];
    __shared__ int rs[256];
    __shared__ int cur[256];
    const int tid = threadIdx.x;
    hist[tid] = 0;
    __syncthreads();
    const int base = bucket_base[blockIdx.x];
    const int cnt = bucket_cnt[blockIdx.x];
    for (int i = tid; i < cnt; i += 256)
        atomicAdd(&hist[binned[base + i] >> 24], 1);
    __syncthreads();
    int v = hist[tid];
    rs[tid] = v;
    __syncthreads();
    #pragma unroll
    for (int off = 1; off < 256; off <<= 1) {
        int t = (tid >= off) ? rs[tid - off] : 0;
        __syncthreads();
        rs[tid] += t;
        __syncthreads();
    }
    int gstart = base + rs[tid] - v;
    int n = (blockIdx.x << 8) + tid;
    if (n < N) {
        row_start[n] = gstart;
        deg_i[n] = v;
        degf[n] = fmaxf((float)v, 1.0f);
    }
    __syncthreads();
    rs[tid] = gstart;
    cur[tid] = 0;
    __syncthreads();
    for (int i = tid; i < cnt; i += 256) {
        unsigned p = binned[base + i];
        int dl = (int)(p >> 24);
        int r = atomicAdd(&cur[dl], 1);
        csr_off[rs[dl] + r] = (int)((p & 0xFFFFFFu) << 7);   // src * 128 bytes (fp8 row)
    }
}

// ---------------- bf16 MFMA GEMM, A streamed from global, A read ONCE per block ----
// Wave w owns rows [wv*32, wv*32+32) x ALL 128 cols -> acc[2][8]. Full 144x128 W in
// LDS (stride 132 shorts). Operands swapped (W first): D row = feature (q*4+reg),
// D col = node (lane&15) -> packed ushort4 stores. CTRL also writes fp8 copy (C8)
// of the output row for the gather in k_depth, + controller logits.

template <bool AF32, bool CTRL>
__launch_bounds__(256)
__global__ void k_gemm_mfma(const void* __restrict__ Ain,
                            const unsigned short* __restrict__ Wt,
                            const float* __restrict__ bias,
                            unsigned short* __restrict__ Cb,
                            unsigned char* __restrict__ C8,
                            float* __restrict__ ctrl,
                            int M, int do_relu) {
    __shared__ unsigned short Ws[144 * 132];
    const int tid = threadIdx.x;
    const int lane = tid & 63;
    const int wv = tid >> 6;
    const int row_blk = blockIdx.x * 128;
    const int rows0 = wv * 32;
    const int l15 = lane & 15;
    const int q = lane >> 4;
    const int RWS = CTRL ? 144 : 128;

    for (int c = tid; c < RWS * 16; c += 256) {
        int r = c >> 4, ch = c & 15;
        *(uint4*)&Ws[r * 132 + ch * 8] = *(const uint4*)(Wt + (size_t)r * HIDDEN + ch * 8);
    }
    __syncthreads();

    f32x4 acc[2][8] = {};
    f32x4 acc5[2] = {};
    for (int k0 = 0; k0 < 128; k0 += 32) {
        short8 af[2];
        #pragma unroll
        for (int mi = 0; mi < 2; mi++) {
            int ar = row_blk + rows0 + mi * 16 + l15;
            if (AF32) {
                const float* A = (const float*)Ain;
                float4 v0 = make_float4(0.f, 0.f, 0.f, 0.f);
                float4 v1 = make_float4(0.f, 0.f, 0.f, 0.f);
                if (ar < M) {
                    v0 = *(const float4*)(A + (size_t)ar * HIDDEN + k0 + q * 8);
                    v1 = *(const float4*)(A + (size_t)ar * HIDDEN + k0 + q * 8 + 4);
                }
                short8 t;
                t[0] = (short)f2bf(v0.x); t[1] = (short)f2bf(v0.y);
                t[2] = (short)f2bf(v0.z); t[3] = (short)f2bf(v0.w);
                t[4] = (short)f2bf(v1.x); t[5] = (short)f2bf(v1.y);
                t[6] = (short)f2bf(v1.z); t[7] = (short)f2bf(v1.w);
                af[mi] = t;
            } else {
                const unsigned short* A = (const unsigned short*)Ain;
                short8 t = {};
                if (ar < M) t = *(const short8*)(A + (size_t)ar * HIDDEN + k0 + q * 8);
                af[mi] = t;
            }
        }
        #pragma unroll
        for (int ni = 0; ni < 8; ni++) {
            short8 bw = *(const short8*)&Ws[(ni * 16 + l15) * 132 + k0 + q * 8];
            #pragma unroll
            for (int mi = 0; mi < 2; mi++)
                acc[mi][ni] = __builtin_amdgcn_mfma_f32_16x16x32_bf16(
                    bw, af[mi], acc[mi][ni], 0, 0, 0);
        }
        if (CTRL) {
            short8 bc = *(const short8*)&Ws[(128 + l15) * 132 + k0 + q * 8];
            #pragma unroll
            for (int mi = 0; mi < 2; mi++)
                acc5[mi] = __builtin_amdgcn_mfma_f32_16x16x32_bf16(
                    bc, af[mi], acc5[mi], 0, 0, 0);
        }
    }
    #pragma unroll
    for (int mi = 0; mi < 2; mi++) {
        int node = row_blk + rows0 + mi * 16 + l15;
        if (node < M) {
            #pragma unroll
            for (int ni = 0; ni < 8; ni++) {
                int fb = ni * 16 + q * 4;
                float4 bv = *(const float4*)&bias[fb];
                float o0 = acc[mi][ni][0] + bv.x;
                float o1 = acc[mi][ni][1] + bv.y;
                float o2 = acc[mi][ni][2] + bv.z;
                float o3 = acc[mi][ni][3] + bv.w;
                if (do_relu) {
                    o0 = fmaxf(o0, 0.f); o1 = fmaxf(o1, 0.f);
                    o2 = fmaxf(o2, 0.f); o3 = fmaxf(o3, 0.f);
                }
                ushort4 ov;
                ov.x = f2bf(o0); ov.y = f2bf(o1); ov.z = f2bf(o2); ov.w = f2bf(o3);
                *(ushort4*)(Cb + (size_t)node * HIDDEN + fb) = ov;
                if (CTRL) {
                    unsigned w8 = 0;
                    w8 = __builtin_amdgcn_cvt_pk_fp8_f32(o0, o1, w8, 0);
                    w8 = __builtin_amdgcn_cvt_pk_fp8_f32(o2, o3, w8, 1);
                    *(unsigned*)(C8 + (size_t)node * HIDDEN + fb) = w8;
                }
            }
            if (CTRL) {
                if (q == 0) {
                    *(float4*)(ctrl + (size_t)node * 8) =
                        make_float4(acc5[mi][0], acc5[mi][1], acc5[mi][2], acc5[mi][3]);
                } else if (q == 1) {
                    ctrl[(size_t)node * 8 + 4] = acc5[mi][0];
                }
            }
        }
    }
}

// ---------------- fused depth step ----------------
// one wave per node; gather reads fp8 rows (4B uint/lane = 4 features), self term
// reads exact bf16 row; 2 edges/iter via half-waves, 8x GPAIR unroll.

__launch_bounds__(256)
__global__ void k_depth(const unsigned char* __restrict__ ht8,
                        const unsigned short* __restrict__ ht,
                        unsigned short* __restrict__ h_out,
                        float* __restrict__ cp, float* __restrict__ wsel,
                        const float* __restrict__ ctrl,
                        const float* __restrict__ degf, const int* __restrict__ deg_i,
                        const int* __restrict__ row_start, const int* __restrict__ csr_off,
                        const float* __restrict__ bd, const float* __restrict__ ba,
                        int N, int first) {
    const int lane = threadIdx.x & 63;
    const int wave = threadIdx.x >> 6;
    const int node = blockIdx.x * 4 + wave;
    if (node >= N) return;
    const int nodeu = __builtin_amdgcn_readfirstlane(node);
    const int half = lane >> 5;
    const int fb = (lane & 31) * 4;      // feature base (4 features/lane)
    const int f8 = fb;                   // fp8 byte offset within row
    const char* htb = (const char*)ht;

    // controller softmaxes from precomputed logits
    float4 c4 = *(const float4*)(ctrl + (size_t)nodeu * 8);
    float cl4 = ctrl[(size_t)nodeu * 8 + 4];
    float d0 = c4.x + bd[0], d1 = c4.y + bd[1];
    float a0 = c4.z + ba[0], a1 = c4.w + ba[1], a2 = cl4 + ba[2];
    float m2 = fmaxf(d0, d1);
    float e0 = __expf(d0 - m2), e1 = __expf(d1 - m2);
    float inv2 = 1.f / (e0 + e1);
    float sp0 = e0 * inv2, sp1 = e1 * inv2;
    float m3 = fmaxf(fmaxf(a0, a1), a2);
    float f0 = __expf(a0 - m3), f1 = __expf(a1 - m3), f2 = __expf(a2 - m3);
    float inv3 = 1.f / (f0 + f1 + f2);
    float ap0 = f0 * inv3, ap1 = f1 * inv3, ap2 = f2 * inv3;

    const int cnt = deg_i[nodeu];
    const int start = row_start[nodeu];
    const float invd = 1.0f / degf[nodeu];

    float s0 = 0.f, s1 = 0.f, s2 = 0.f, s3 = 0.f;
    float x0m = -3.4e38f, x1m = -3.4e38f, x2m = -3.4e38f, x3m = -3.4e38f;

    for (int eb = 0; eb < cnt; eb += 64) {
        int idx = eb + lane;
        int soff = (idx < cnt) ? csr_off[start + idx] : 0;   // src*128 (fp8 row bytes)
        int lim = min(64, cnt - eb);
        int lim2 = lim & ~1;
        int j = 0;
        #define GPAIR(JJ)                                                     \
        {                                                                     \
            int o = __shfl(soff, (JJ) + half);                                \
            unsigned u = *(const unsigned*)(ht8 + (unsigned)(o + f8));        \
            f32x2 plo = __builtin_amdgcn_cvt_pk_f32_fp8(u, 0);                \
            f32x2 phi = __builtin_amdgcn_cvt_pk_f32_fp8(u, 1);                \
            s0 += plo.x; s1 += plo.y; s2 += phi.x; s3 += phi.y;               \
            x0m = fmaxf(x0m, plo.x); x1m = fmaxf(x1m, plo.y);                 \
            x2m = fmaxf(x2m, phi.x); x3m = fmaxf(x3m, phi.y);                 \
        }
        for (; j + 16 <= lim2; j += 16) {
            GPAIR(j) GPAIR(j + 2) GPAIR(j + 4) GPAIR(j + 6)
            GPAIR(j + 8) GPAIR(j + 10) GPAIR(j + 12) GPAIR(j + 14)
        }
        for (; j + 4 <= lim2; j += 4) { GPAIR(j) GPAIR(j + 2) }
        for (; j < lim2; j += 2) GPAIR(j)
        #undef GPAIR
        if (lim & 1) {
            int o = __shfl(soff, lim - 1);
            if (half == 0) {
                unsigned u = *(const unsigned*)(ht8 + (unsigned)(o + f8));
                f32x2 plo = __builtin_amdgcn_cvt_pk_f32_fp8(u, 0);
                f32x2 phi = __builtin_amdgcn_cvt_pk_f32_fp8(u, 1);
                s0 += plo.x; s1 += plo.y; s2 += phi.x; s3 += phi.y;
                x0m = fmaxf(x0m, plo.x); x1m = fmaxf(x1m, plo.y);
                x2m = fmaxf(x2m, phi.x); x3m = fmaxf(x3m, phi.y);
            }
        }
    }
    // combine halves
    s0 += __shfl_xor(s0, 32); s1 += __shfl_xor(s1, 32);
    s2 += __shfl_xor(s2, 32); s3 += __shfl_xor(s3, 32);
    x0m = fmaxf(x0m, __shfl_xor(x0m, 32)); x1m = fmaxf(x1m, __shfl_xor(x1m, 32));
    x2m = fmaxf(x2m, __shfl_xor(x2m, 32)); x3m = fmaxf(x3m, __shfl_xor(x3m, 32));

    if (cnt == 0) { x0m = 0.f; x1m = 0.f; x2m = 0.f; x3m = 0.f; }

    if (half == 0) {
        uint2 su = *(const uint2*)(htb + (unsigned)(nodeu * 256 + fb * 2));  // exact bf16 self
        float h0 = ap0 * (s0 * invd) + ap1 * x0m + ap2 * bf_lo(su.x);
        float h1 = ap0 * (s1 * invd) + ap1 * x1m + ap2 * bf_hi(su.x);
        float h2 = ap0 * (s2 * invd) + ap1 * x2m + ap2 * bf_lo(su.y);
        float h3 = ap0 * (s3 * invd) + ap1 * x3m + ap2 * bf_hi(su.y);
        h0 = fmaxf(h0, 0.f); h1 = fmaxf(h1, 0.f);
        h2 = fmaxf(h2, 0.f); h3 = fmaxf(h3, 0.f);
        ushort4 ho;
        ho.x = f2bf(h0); ho.y = f2bf(h1); ho.z = f2bf(h2); ho.w = f2bf(h3);
        *(ushort4*)(h_out + (size_t)nodeu * HIDDEN + fb) = ho;
    }
    if (lane == 0) {
        float cpv = first ? 1.0f : cp[nodeu];
        wsel[nodeu] = cpv * sp1;
        cp[nodeu] = cpv * sp0;
    }
}

// ---------------- post: sel = sum_d w_d * h_{d+1}; logits; log_softmax ----------------

__launch_bounds__(256)
__global__ void k_post(const unsigned short* __restrict__ h_all, size_t hstride,
                       const float* __restrict__ wsel, int N,
                       const float* __restrict__ Wp, const float* __restrict__ bp,
                       float* __restrict__ out) {
    __shared__ float Ss[32][132];
    __shared__ float Wt[NCLS][132];
    __shared__ float bs[NCLS];
    const int tid = threadIdx.x;
    const int n0 = blockIdx.x * 32;

    for (int i = tid; i < (HIDDEN * NCLS) / 4; i += 256) {
        float4 v = *(const float4*)&Wp[i * 4];
        int f = i * 4;
        int k = f / NCLS, c = f % NCLS;
        float e[4] = {v.x, v.y, v.z, v.w};
        #pragma unroll
        for (int j = 0; j < 4; j++) {
            int cc = c + j, kk = k;
            if (cc >= NCLS) { cc -= NCLS; kk++; }
            Wt[cc][kk] = e[j];
        }
    }
    if (tid < NCLS) bs[tid] = bp[tid];

    const int node_l = tid >> 3;
    const int kc = (tid & 7) * 16;
    const int ng = n0 + node_l;
    float sel[16];
    #pragma unroll
    for (int i = 0; i < 16; i++) sel[i] = 0.f;
    if (ng < N) {
        #pragma unroll
        for (int d = 0; d < 4; d++) {
            float w = wsel[(size_t)d * N + ng];
            const unsigned short* hrow = h_all + (size_t)(d + 1) * hstride + (size_t)ng * HIDDEN;
            #pragma unroll
            for (int u = 0; u < 2; u++) {
                uint4 p = *(const uint4*)(hrow + kc + u * 8);
                unsigned vs[4] = {p.x, p.y, p.z, p.w};
                #pragma unroll
                for (int j = 0; j < 4; j++) {
                    sel[u * 8 + j * 2 + 0] += w * bf_lo(vs[j]);
                    sel[u * 8 + j * 2 + 1] += w * bf_hi(vs[j]);
                }
            }
        }
    }
    #pragma unroll
    for (int u = 0; u < 4; u++)
        *(float4*)&Ss[node_l][kc + u * 4] =
            make_float4(sel[u * 4], sel[u * 4 + 1], sel[u * 4 + 2], sel[u * 4 + 3]);
    __syncthreads();

    const int c0 = (tid & 7) * 5;
    float z[5];
    #pragma unroll
    for (int i = 0; i < 5; i++) z[i] = bs[c0 + i];
    for (int k = 0; k < HIDDEN; k += 4) {
        float4 s4 = *(const float4*)&Ss[node_l][k];
        #pragma unroll
        for (int i = 0; i < 5; i++) {
            float4 w4 = *(const float4*)&Wt[c0 + i][k];
            z[i] += s4.x * w4.x + s4.y * w4.y + s4.z * w4.z + s4.w * w4.w;
        }
    }
    float m = z[0];
    #pragma unroll
    for (int i = 1; i < 5; i++) m = fmaxf(m, z[i]);
    #pragma unroll
    for (int off = 1; off < 8; off <<= 1) m = fmaxf(m, __shfl_xor(m, off));
    float s = 0.f;
    #pragma unroll
    for (int i = 0; i < 5; i++) s += expf(z[i] - m);
    #pragma unroll
    for (int off = 1; off < 8; off <<= 1) s += __shfl_xor(s, off);
    float lg = m + logf(s);
    if (ng < N) {
        #pragma unroll
        for (int i = 0; i < 5; i++)
            out[(size_t)ng * NCLS + c0 + i] = z[i] - lg;
    }
}

// ---------------- launch ----------------

extern "C" void kernel_launch(void* const* d_in, const int* in_sizes, int n_in,
                              void* d_out, int out_size, void* d_ws, size_t ws_size,
                              hipStream_t stream) {
    const float* x      = (const float*)d_in[0];
    const int*   ei     = (const int*)d_in[1];
    const float* W_pre  = (const float*)d_in[2];
    const float* b_pre  = (const float*)d_in[3];
    const float* W_dep  = (const float*)d_in[4];
    const float* b_dep  = (const float*)d_in[5];
    const float* W_aggr = (const float*)d_in[6];
    const float* b_aggr = (const float*)d_in[7];
    const float* W_conv = (const float*)d_in[8];
    const float* b_conv = (const float*)d_in[9];
    const float* W_post = (const float*)d_in[10];
    const float* b_post = (const float*)d_in[11];

    const int N = in_sizes[0] / HIDDEN;
    const int E = in_sizes[1] / 2;
    const int nbuckets = (N + 255) >> 8;

    char* ws = (char*)d_ws;
    size_t off = 0;
    auto alloc = [&](size_t bytes) -> void* {
        void* p = ws + off;
        off += (bytes + 255) & ~(size_t)255;
        return p;
    };
    const size_t hstride = (size_t)N * HIDDEN;
    unsigned short* h_all  = (unsigned short*)alloc(5 * hstride * 2);  // h_0..h_4
    unsigned short* ht     = (unsigned short*)alloc(hstride * 2);
    unsigned char*  ht8    = (unsigned char*)alloc(hstride);           // fp8 gather copy
    float* cp       = (float*)alloc((size_t)N * 4);
    float* wsel     = (float*)alloc((size_t)4 * N * 4);
    float* degf     = (float*)alloc((size_t)N * 4);
    float* ctrl     = (float*)alloc((size_t)N * 8 * 4);
    unsigned short* WpreT = (unsigned short*)alloc(128 * 128 * 2);
    unsigned short* WT    = (unsigned short*)alloc(4 * 144 * 128 * 2);
    int*   deg_i    = (int*)alloc((size_t)N * 4);
    int*   row_start= (int*)alloc((size_t)N * 4);
    int*   bucket_cnt    = (int*)alloc(BMAX * 4);
    int*   bucket_base   = (int*)alloc(BMAX * 4);
    int*   bucket_cursor = (int*)alloc(BMAX * 4);
    int*   csr_off  = (int*)alloc((size_t)E * 4);
    unsigned* binned = (unsigned*)alloc((size_t)E * 4);

    hipMemsetAsync(bucket_cnt, 0, BMAX * 4, stream);

    int ebb = (E + 4095) / 4096;
    k_bcount<<<ebb, 256, 0, stream>>>(ei, E, bucket_cnt);
    k_bscan<<<1, 256, 0, stream>>>(bucket_cnt, nbuckets, bucket_base, bucket_cursor);
    k_bin<<<ebb, 256, 0, stream>>>(ei, E, bucket_cursor, binned);
    k_scatter<<<nbuckets, 256, 0, stream>>>(binned, bucket_base, bucket_cnt,
                                            row_start, deg_i, degf, csr_off, N);

    int wtot = 16384 + 4 * 18432;
    k_wprep<<<(wtot + 255) / 256, 256, 0, stream>>>(W_pre, W_conv, W_dep, W_aggr,
                                                    WpreT, WT);

    int gblk = (N + 127) / 128;
    k_gemm_mfma<true, false><<<gblk, 256, 0, stream>>>(x, WpreT, b_pre, h_all,
                                                       nullptr, nullptr, N, 1);

    int nb4 = (N + 3) / 4;
    for (int d = 0; d < 4; d++) {
        unsigned short* h_d  = h_all + (size_t)d * hstride;
        unsigned short* h_n  = h_all + (size_t)(d + 1) * hstride;
        k_gemm_mfma<false, true><<<gblk, 256, 0, stream>>>(h_d, WT + (size_t)d * 18432,
                                                           b_conv + (size_t)d * HIDDEN,
                                                           ht, ht8, ctrl, N, 0);
        k_depth<<<nb4, 256, 0, stream>>>(ht8, ht, h_n, cp, wsel + (size_t)d * N, ctrl,
                                         degf, deg_i, row_start, csr_off,
                                         b_dep, b_aggr, N, d == 0 ? 1 : 0);
    }
    k_post<<<(N + 31) / 32, 256, 0, stream>>>(h_all, hstride, wsel, N,
                                              W_post, b_post, (float*)d_out);
}